// Round 5
// baseline (554.731 us; speedup 1.0000x reference)
//
#include <hip/hip_runtime.h>

#define Bb 8
#define Ss 2048
#define Ee 1024
#define Dd 1024

typedef __attribute__((ext_vector_type(8))) __bf16 bf16x8;
typedef __attribute__((ext_vector_type(4))) float f32x4;
typedef unsigned short u16;

__device__ __forceinline__ u16 f2bf(float x) {
  unsigned u = __float_as_uint(x);
  return (u16)((u + 0x7fffu + ((u >> 16) & 1u)) >> 16);
}
__device__ __forceinline__ float bf2f(u16 h) {
  return __uint_as_float(((unsigned)h) << 16);
}

__device__ __forceinline__ void gload16(const void* g, void* l) {
  __builtin_amdgcn_global_load_lds(
      (__attribute__((address_space(1))) void*)const_cast<void*>(g),
      (__attribute__((address_space(3))) void*)l, 16, 0, 0);
}

#define MFMA_BF16 __builtin_amdgcn_mfma_f32_16x16x32_bf16

// ---------------- fp32 -> bf16 hi/lo split (vectorized x4) ----------------
__global__ __launch_bounds__(256) void k_split4(const float* __restrict__ in,
                                                u16* __restrict__ hi,
                                                u16* __restrict__ lo,
                                                long long n4) {
  long long i = (long long)blockIdx.x * 256 + threadIdx.x;
  if (i >= n4) return;
  float4 v = ((const float4*)in)[i];
  float xs[4] = {v.x, v.y, v.z, v.w};
  u16 hh[4], ll[4];
#pragma unroll
  for (int j = 0; j < 4; ++j) {
    hh[j] = f2bf(xs[j]);
    ll[j] = f2bf(xs[j] - bf2f(hh[j]));
  }
  ushort4 h, l;
  h.x = hh[0]; h.y = hh[1]; h.z = hh[2]; h.w = hh[3];
  l.x = ll[0]; l.y = ll[1]; l.z = ll[2]; l.w = ll[3];
  ((ushort4*)hi)[i] = h;
  ((ushort4*)lo)[i] = l;
}

// ---------------- W [E,D] fp32 -> W^T [D,E] bf16 hi(/lo) ----------------
__global__ __launch_bounds__(256) void k_wt_split(const float* __restrict__ W,
                                                  u16* __restrict__ hi,
                                                  u16* __restrict__ lo) {
  __shared__ float t[32][33];
  const int tx = threadIdx.x & 31;
  const int ty = threadIdx.x >> 5;  // 0..7
  const int e0 = blockIdx.y * 32, d0 = blockIdx.x * 32;
#pragma unroll
  for (int r = ty; r < 32; r += 8)
    t[r][tx] = W[(long long)(e0 + r) * Dd + d0 + tx];
  __syncthreads();
#pragma unroll
  for (int r = ty; r < 32; r += 8) {
    float x = t[tx][r];  // = W[e0+tx][d0+r]
    long long o = (long long)(d0 + r) * Ee + e0 + tx;
    u16 h = f2bf(x);
    hi[o] = h;
    if (lo) lo[o] = f2bf(x - bf2f(h));
  }
}

// ========== m201-geometry 256x256 split-precision BT GEMM (proj) ==========
// hi/lo folded into a virtual doubled-K "A-hat" matrix at 16B-chunk
// granularity: LDS tile = 256 rows x 128B (8 chunks), chunk c_l = 2*oct + s
// (s: 0=hi,1=lo), stored at phys chunk c_l ^ (row&7) [conflict-free reads:
// 8-lane groups hit 8 distinct chunks].  Storage stays plain hi/lo row-major;
// the inverse swizzle is applied on the per-lane gload SOURCE address only
// (LDS dest linear).  2 mats x 32KB x dbuf = 128 KiB.  Per A-hat tile
// (K=32 real): 4 phases x {ds-reads; stage 1 half-tile; BAR; setprio 24-MFMA
// (pass-major) setprio; BAR}.  Sound counted gate per tile: issue next h0,
// vmcnt(2), BAR (all current-tile loads are the oldest 8 outstanding).
__global__ __launch_bounds__(512, 2) void k_proj256(
    const u16* __restrict__ Ah, const u16* __restrict__ Al,
    const u16* __restrict__ Bh, const u16* __restrict__ Bl,
    u16* __restrict__ Ch, u16* __restrict__ Cl,
    int nbx, int N, int K) {
  const int nwg = gridDim.x;
  const int f = blockIdx.x;
  const int wgid = (f & 7) * (nwg >> 3) + (f >> 3);  // XCD chunk swizzle
  const int bx = wgid % nbx;
  const int by = wgid / nbx;

  // lds bytes: buf*65536 + mat*32768 + row*128 + chunk*16
  __shared__ __align__(16) u16 lds[2][2][16384];

  const int tid = threadIdx.x;
  const int lane = tid & 63;
  const int w = tid >> 6;  // 0..7
  const int wr = w >> 2;   // 0..1  (M half)
  const int wc = w & 3;    // 0..3  (N quarter)

  const u16* srcHi[2] = {Ah, Bh};
  const u16* srcLo[2] = {Al, Bl};
  const long long row0[2] = {(long long)by * 256, (long long)bx * 256};

  // ---- staging source pointers (8 per thread; all indices compile-time) ---
  const int l7 = lane & 7;
  const int l3 = lane >> 3;  // 0..7
  const int cl = l7 ^ l3;    // logical chunk this thread covers
  const int s_sel = cl & 1;  // 0=hi 1=lo
  const int oct = cl >> 1;   // real-K octet within the 32-col group
  const u16* gp[8];
#pragma unroll
  for (int hh = 0; hh < 4; ++hh) {
    const int mat = hh >> 1, hf = hh & 1;
#pragma unroll
    for (int i = 0; i < 2; ++i) {
      const long long grow = row0[mat] + hf * 128 + w * 16 + i * 8 + l3;
      gp[hh * 2 + i] =
          (s_sel ? srcLo[mat] : srcHi[mat]) + grow * (long long)K + oct * 8;
    }
  }

  // ---- swizzled read offsets (hi / lo fragment of a 16-row block) ----
  const int rdH = (lane & 15) * 128 + (((lane >> 4) * 2) ^ l7) * 16;
  const int rdL = (lane & 15) * 128 + (((lane >> 4) * 2 + 1) ^ l7) * 16;

  const int AR = wr * 128;
  const int BR = wc * 64;
  const int nt = K / 32;

#define STAGE_H(DSTC, HH)                                                   \
  do {                                                                      \
    char* _d = (char*)lds + (DSTC)*65536 + ((HH) >> 1) * 32768 +            \
               ((HH)&1) * 16384 + w * 2048;                                 \
    gload16(gp[(HH)*2], _d);                                                \
    gp[(HH)*2] += 32;                                                       \
    gload16(gp[(HH)*2 + 1], _d + 1024);                                     \
    gp[(HH)*2 + 1] += 32;                                                   \
  } while (0)

#define RDA(MB)                                                             \
  _Pragma("unroll") for (int m = 0; m < 4; ++m) {                           \
    const char* _a = (const char*)lds + cur * 65536 +                       \
                     (AR + (MB)*64 + m * 16) * 128;                         \
    aH[m] = *(const bf16x8*)(_a + rdH);                                     \
    aL[m] = *(const bf16x8*)(_a + rdL);                                     \
  }

#define RDB(NB)                                                             \
  _Pragma("unroll") for (int nn = 0; nn < 2; ++nn) {                        \
    const char* _b = (const char*)lds + cur * 65536 + 32768 +               \
                     (BR + ((NB)*2 + nn) * 16) * 128;                       \
    bH[nn] = *(const bf16x8*)(_b + rdH);                                    \
    bL[nn] = *(const bf16x8*)(_b + rdL);                                    \
  }

#define CLUSTER(MB, NB)                                                     \
  __builtin_amdgcn_s_setprio(1);                                            \
  _Pragma("unroll") for (int m = 0; m < 4; ++m)                             \
      _Pragma("unroll") for (int nn = 0; nn < 2; ++nn)                      \
          acc[(MB)*4 + m][(NB)*2 + nn] = MFMA_BF16(                         \
              aH[m], bL[nn], acc[(MB)*4 + m][(NB)*2 + nn], 0, 0, 0);        \
  _Pragma("unroll") for (int m = 0; m < 4; ++m)                             \
      _Pragma("unroll") for (int nn = 0; nn < 2; ++nn)                      \
          acc[(MB)*4 + m][(NB)*2 + nn] = MFMA_BF16(                         \
              aL[m], bH[nn], acc[(MB)*4 + m][(NB)*2 + nn], 0, 0, 0);        \
  _Pragma("unroll") for (int m = 0; m < 4; ++m)                             \
      _Pragma("unroll") for (int nn = 0; nn < 2; ++nn)                      \
          acc[(MB)*4 + m][(NB)*2 + nn] = MFMA_BF16(                         \
              aH[m], bH[nn], acc[(MB)*4 + m][(NB)*2 + nn], 0, 0, 0);        \
  __builtin_amdgcn_s_setprio(0);

#define BAR __builtin_amdgcn_s_barrier()

  f32x4 acc[8][4];
#pragma unroll
  for (int m = 0; m < 8; ++m)
#pragma unroll
    for (int n = 0; n < 4; ++n) acc[m][n] = f32x4{0.f, 0.f, 0.f, 0.f};

  bf16x8 aH[4], aL[4], bH[2], bL[2];

  // prologue: stage tile 0 (4 half-tiles) into buf 0
  STAGE_H(0, 0);
  STAGE_H(0, 1);
  STAGE_H(0, 2);
  STAGE_H(0, 3);

  for (int kt = 0; kt < nt; ++kt) {
    const int cur = kt & 1;
    const bool more = (kt + 1 < nt);

    // ---- gate: issue next tile's A.h0, counted wait, sync ----
    if (more) {
      STAGE_H(cur ^ 1, 0);
      asm volatile("s_waitcnt vmcnt(2)" ::: "memory");
    } else {
      asm volatile("s_waitcnt vmcnt(0)" ::: "memory");
    }
    BAR;
    __builtin_amdgcn_sched_barrier(0);

    // P0: read a(mb0)+b(n01); stage A.h1; MFMA (mb0, n01)
    RDA(0); RDB(0);
    if (more) STAGE_H(cur ^ 1, 1);
    BAR; CLUSTER(0, 0); BAR;
    // P1: read a(mb1); stage B.h0; MFMA (mb1, n01)
    RDA(1);
    if (more) STAGE_H(cur ^ 1, 2);
    BAR; CLUSTER(1, 0); BAR;
    // P2: read b(n23); stage B.h1; MFMA (mb1, n23)
    RDB(1);
    if (more) STAGE_H(cur ^ 1, 3);
    BAR; CLUSTER(1, 1); BAR;
    // P3: re-read a(mb0); MFMA (mb0, n23)
    RDA(0);
    BAR; CLUSTER(0, 1); BAR;
  }

  // epilogue: C/D map col=lane&15, row=(lane>>4)*4+reg; acc ai -> row off
  // (ai>>2)*64 + (ai&3)*16
  const int cr = (lane >> 4) << 2;
  const int cc = lane & 15;
#pragma unroll
  for (int m = 0; m < 8; ++m)
#pragma unroll
    for (int n = 0; n < 4; ++n)
#pragma unroll
      for (int r = 0; r < 4; ++r) {
        const long long row =
            (long long)by * 256 + wr * 128 + (m >> 2) * 64 + (m & 3) * 16 + cr + r;
        const long long col = (long long)bx * 256 + wc * 64 + n * 16 + cc;
        const long long idx = row * N + col;
        const float v = acc[m][n][r];
        u16 h = f2bf(v);
        Ch[idx] = h;
        Cl[idx] = f2bf(v - bf2f(h));
      }
#undef STAGE_H
#undef RDA
#undef RDB
#undef CLUSTER
#undef BAR
}

// ============ deep-prefetch 128x128 energy GEMM (4 waves, 2 blk/CU) =======
__global__ __launch_bounds__(256, 2) void k_energy128(
    const u16* __restrict__ qh, const u16* __restrict__ ql,
    const u16* __restrict__ kh, const u16* __restrict__ kl,
    float* __restrict__ attn) {
  const int nwg = gridDim.x;  // 1088
  const int f = blockIdx.x;
  const int wgid = (f & 7) * (nwg >> 3) + (f >> 3);
  const int bz = wgid / 136;
  const int t = wgid % 136;
  int by = 0, c = 0;
  while (c + by + 1 <= t) { c += by + 1; ++by; }  // <=16 iters
  const int bx = t - c;

  __shared__ __align__(16) u16 lds[2][4][4096];  // 64 KiB -> 2 blocks/CU

  const int tid = threadIdx.x;
  const int lane = tid & 63;
  const int w = tid >> 6;  // 0..3
  const int wr = w >> 1;   // 0..1
  const int wc = w & 1;    // 0..1

  const long long sQ = (long long)bz * Ss * Dd;
  const u16* srcBase[4] = {qh + sQ, ql + sQ, kh + sQ, kl + sQ};
  const long long row0[2] = {(long long)by * 128, (long long)bx * 128};

  const int rL = tid >> 2;  // 0..63
  const int colOff = ((tid & 3) ^ ((tid >> 3) & 3)) * 8;
  const int rdOff = (lane & 15) * 64 + ((((lane >> 4) & 3) ^ ((lane >> 1) & 3)) << 4);

  const int AR = wr * 64;
  const int BR = wc * 64;
  const int nt = Dd / 32;  // 32

#define STAGE8E(buf, kt)                                                \
  {                                                                     \
    _Pragma("unroll") for (int u = 0; u < 8; ++u) {                     \
      const int mat = u >> 1, half = u & 1;                             \
      const long long grow = row0[mat >> 1] + half * 64 + rL;           \
      gload16(srcBase[mat] + grow * Dd + (kt)*32 + colOff,              \
              (char*)&lds[buf][mat][0] + half * 4096 + w * 1024);       \
    }                                                                   \
  }
#define LDFRAGE(buf, mat, R) \
  (*(const bf16x8*)((const char*)&lds[buf][mat][0] + (R)*64 + rdOff))

  f32x4 acc[4][4];
#pragma unroll
  for (int m = 0; m < 4; ++m)
#pragma unroll
    for (int n = 0; n < 4; ++n) acc[m][n] = f32x4{0.f, 0.f, 0.f, 0.f};

  bf16x8 a_h[4], a_l[4], b_h[4], b_l[4];

  STAGE8E(0, 0);

  for (int kt = 0; kt < nt; ++kt) {
    const int cur = kt & 1;
    const bool more = (kt + 1 < nt);

    if (more) {
      STAGE8E(cur ^ 1, kt + 1);
      asm volatile("s_waitcnt vmcnt(8)" ::: "memory");
    } else {
      asm volatile("s_waitcnt vmcnt(0)" ::: "memory");
    }
    __builtin_amdgcn_s_barrier();  // data ready

#pragma unroll
    for (int m = 0; m < 4; ++m) {
      a_h[m] = LDFRAGE(cur, 0, AR + m * 16);
      a_l[m] = LDFRAGE(cur, 1, AR + m * 16);
    }
#pragma unroll
    for (int n = 0; n < 2; ++n) {
      b_h[n] = LDFRAGE(cur, 2, BR + n * 16);
      b_l[n] = LDFRAGE(cur, 3, BR + n * 16);
    }
    __builtin_amdgcn_s_barrier();
    __builtin_amdgcn_s_setprio(1);
#pragma unroll
    for (int m = 0; m < 4; ++m)
#pragma unroll
      for (int n = 0; n < 2; ++n) {
        acc[m][n] = MFMA_BF16(a_h[m], b_l[n], acc[m][n], 0, 0, 0);
        acc[m][n] = MFMA_BF16(a_l[m], b_h[n], acc[m][n], 0, 0, 0);
        acc[m][n] = MFMA_BF16(a_h[m], b_h[n], acc[m][n], 0, 0, 0);
      }
    __builtin_amdgcn_s_setprio(0);
    __builtin_amdgcn_s_barrier();

#pragma unroll
    for (int n = 2; n < 4; ++n) {
      b_h[n] = LDFRAGE(cur, 2, BR + n * 16);
      b_l[n] = LDFRAGE(cur, 3, BR + n * 16);
    }
    __builtin_amdgcn_s_barrier();
    __builtin_amdgcn_s_setprio(1);
#pragma unroll
    for (int m = 0; m < 4; ++m)
#pragma unroll
      for (int n = 2; n < 4; ++n) {
        acc[m][n] = MFMA_BF16(a_h[m], b_l[n], acc[m][n], 0, 0, 0);
        acc[m][n] = MFMA_BF16(a_l[m], b_h[n], acc[m][n], 0, 0, 0);
        acc[m][n] = MFMA_BF16(a_h[m], b_h[n], acc[m][n], 0, 0, 0);
      }
    __builtin_amdgcn_s_setprio(0);
    __builtin_amdgcn_s_barrier();
  }

  const int cr = (lane >> 4) << 2;
  const int cc = lane & 15;
#pragma unroll
  for (int m = 0; m < 4; ++m)
#pragma unroll
    for (int n = 0; n < 4; ++n)
#pragma unroll
      for (int r = 0; r < 4; ++r) {
        const long long row = (long long)by * 128 + wr * 64 + m * 16 + cr + r;
        const long long col = (long long)bx * 128 + wc * 64 + n * 16 + cc;
        attn[(long long)bz * Ss * Ss + row * Ss + col] = acc[m][n][r];
      }
#undef STAGE8E
#undef LDFRAGE
}

// ---------------- 128x128-tile BT-layout MFMA GEMM (NPASS=1) --------------
template <int EPI, bool TRIK>
__global__ __launch_bounds__(256) void k_gemm_bt(
    const u16* __restrict__ Ah, const u16* __restrict__ Bh,
    float* __restrict__ Cf, u16* __restrict__ Ch,
    int M, int N, int K, long long strA, long long strB, long long strC) {
  const int bx = blockIdx.x, by = blockIdx.y, bz = blockIdx.z;

  const int tid = threadIdx.x;
  const int lane = tid & 63;
  const int w = tid >> 6;
  const int wr = w >> 1, wc = w & 1;

  const u16* pAh = Ah + (long long)bz * strA;
  const u16* pBh = Bh + (long long)bz * strB;

  __shared__ __align__(16) u16 lds[2 * 128 * 32];
  char* ldsc = (char*)lds;

  const int srow = tid >> 2;
  const int scol = (tid & 3) * 8;
  const long long arow = (long long)by * 128 + srow;
  const long long brow = (long long)bx * 128 + srow;

  int ktEnd = K / 32;
  if (TRIK) {
    int lim = ((by + 1) * 128) / 32;
    if (lim < ktEnd) ktEnd = lim;
  }

  f32x4 acc[4][4];
#pragma unroll
  for (int i = 0; i < 4; ++i)
#pragma unroll
    for (int j = 0; j < 4; ++j) acc[i][j] = f32x4{0.f, 0.f, 0.f, 0.f};

  for (int kt = 0; kt < ktEnd; ++kt) {
    const int k0 = kt * 32 + scol;
    __syncthreads();
    gload16(pAh + arow * K + k0, ldsc + 0 * 4096 + w * 1024);
    gload16(pAh + (arow + 64) * K + k0, ldsc + 1 * 4096 + w * 1024);
    gload16(pBh + brow * K + k0, ldsc + 8192 + 0 * 4096 + w * 1024);
    gload16(pBh + (brow + 64) * K + k0, ldsc + 8192 + 1 * 4096 + w * 1024);
    __syncthreads();

    const int kk = (lane >> 4) * 8;
    const int ar = wr * 64 + (lane & 15);
    const int br = wc * 64 + (lane & 15);
    bf16x8 avh[4], bvh[4];
#pragma unroll
    for (int m = 0; m < 4; ++m)
      avh[m] = *(const bf16x8*)(lds + (ar + m * 16) * 32 + kk);
#pragma unroll
    for (int n = 0; n < 4; ++n)
      bvh[n] = *(const bf16x8*)(lds + 128 * 32 + (br + n * 16) * 32 + kk);
#pragma unroll
    for (int m = 0; m < 4; ++m)
#pragma unroll
      for (int n = 0; n < 4; ++n)
        acc[m][n] = MFMA_BF16(avh[m], bvh[n], acc[m][n], 0, 0, 0);
  }

  const int cr = wr * 64 + ((lane >> 4) << 2);
  const int cc = wc * 64 + (lane & 15);
  const long long rb = (long long)by * 128 + cr;
  const long long cb = (long long)bx * 128 + cc;
#pragma unroll
  for (int m = 0; m < 4; ++m)
#pragma unroll
    for (int n = 0; n < 4; ++n)
#pragma unroll
      for (int r = 0; r < 4; ++r) {
        const long long idx =
            (long long)bz * strC + (rb + m * 16 + r) * (long long)N + (cb + n * 16);
        const float v = acc[m][n][r];
        if constexpr (EPI == 0) Cf[idx] = v;
        else Ch[idx] = f2bf(v);
      }
}

// -------- causal+pad masked row softmax (in-place, causal-trimmed) --------
__global__ __launch_bounds__(256) void k_softmax(float* __restrict__ attn,
                                                 u16* __restrict__ attn_bf,
                                                 const int* __restrict__ mask,
                                                 float inv_scale) {
  const int q = blockIdx.x;
  const int b = blockIdx.y;
  const int tid = threadIdx.x;
  float* row = attn + ((long long)b * Ss + q) * Ss;
  u16* rowb = attn_bf + ((long long)b * Ss + q) * Ss;
  const int* mrow = mask + b * Ss;
  const int qup = ((q >> 7) + 1) << 7;  // PV's TRIK reads bf16 cols < qup

  float x[8];
  float m = -3.0e38f;
#pragma unroll
  for (int j = 0; j < 8; ++j) {
    const int k = tid + j * 256;
    float v = -3.0e38f;
    if (k <= q) {
      const float e = row[k];
      v = ((mrow[k] != 0) ? e : -1e20f) * inv_scale;
    }
    x[j] = v;
    m = fmaxf(m, v);
  }
#pragma unroll
  for (int o = 32; o > 0; o >>= 1) m = fmaxf(m, __shfl_xor(m, o));
  __shared__ float redm[4], reds[4];
  const int w = tid >> 6;
  if ((tid & 63) == 0) redm[w] = m;
  __syncthreads();
  m = fmaxf(fmaxf(redm[0], redm[1]), fmaxf(redm[2], redm[3]));
  float s = 0.f;
#pragma unroll
  for (int j = 0; j < 8; ++j) {
    x[j] = __expf(x[j] - m);
    s += x[j];
  }
#pragma unroll
  for (int o = 32; o > 0; o >>= 1) s += __shfl_xor(s, o);
  if ((tid & 63) == 0) reds[w] = s;
  __syncthreads();
  s = reds[0] + reds[1] + reds[2] + reds[3];
  const float inv = 1.0f / s;
#pragma unroll
  for (int j = 0; j < 8; ++j) {
    const int k = tid + j * 256;
    if (k <= q) {
      const float a = x[j] * inv;
      row[k] = a;
      rowb[k] = f2bf(a);
    } else {
      row[k] = 0.0f;          // exact: reference gives exp(-inf)=0 here
      if (k < qup) rowb[k] = 0;
    }
  }
}

extern "C" void kernel_launch(void* const* d_in, const int* in_sizes, int n_in,
                              void* d_out, int out_size, void* d_ws, size_t ws_size,
                              hipStream_t stream) {
  const float* emb = (const float*)d_in[0];
  const int* mask = (const int*)d_in[1];
  const float* Wq = (const float*)d_in[2];
  const float* Wk = (const float*)d_in[3];
  const float* Wv = (const float*)d_in[4];

  float* out = (float*)d_out;                   // [8,2048,1024] fp32
  float* attn = out + (long long)Bb * Ss * Dd;  // [8,2048,2048] fp32

  char* p = (char*)d_ws;
  u16* emb_hi = (u16*)p;
  u16* emb_lo = emb_hi + (long long)Bb * Ss * Ee;
  u16* attn_bf = emb_hi;  // alias: emb dead before softmax
  u16* q_hi = (u16*)(p + 67108864LL);
  u16* q_lo = q_hi + 16777216LL;
  u16* k_hi = q_lo + 16777216LL;
  u16* k_lo = k_hi + 16777216LL;
  u16* v_t = k_lo + 16777216LL;  // [b][D][S] bf16
  u16* Wq_hi = v_t + 16777216LL;
  u16* Wq_lo = Wq_hi + 1048576LL;
  u16* Wk_hi = Wq_lo + 1048576LL;
  u16* Wk_lo = Wk_hi + 1048576LL;
  u16* Wv_hi = Wk_lo + 1048576LL;

  const float inv_scale = 1.0f / (32.0f + 1.1920929e-07f);

  k_split4<<<16384, 256, 0, stream>>>(emb, emb_hi, emb_lo, (long long)Bb * Ss * Ee / 4);
  k_wt_split<<<dim3(32, 32), 256, 0, stream>>>(Wq, Wq_hi, Wq_lo);
  k_wt_split<<<dim3(32, 32), 256, 0, stream>>>(Wk, Wk_hi, Wk_lo);
  k_wt_split<<<dim3(32, 32), 256, 0, stream>>>(Wv, Wv_hi, nullptr);

  // q/k = emb @ W : M=16384, N=1024, K=1024; flat grid 256 (nbx=4)
  k_proj256<<<256, 512, 0, stream>>>(
      emb_hi, emb_lo, Wq_hi, Wq_lo, q_hi, q_lo, 4, 1024, 1024);
  k_proj256<<<256, 512, 0, stream>>>(
      emb_hi, emb_lo, Wk_hi, Wk_lo, k_hi, k_lo, 4, 1024, 1024);
  // v^T per batch: [D,S] = Wv^T[D,E] x emb_b (BT), single-pass bf16
  k_gemm_bt<2, false><<<dim3(16, 8, 8), 256, 0, stream>>>(
      Wv_hi, emb_hi, nullptr, v_t,
      1024, 2048, 1024, 0, (long long)Ss * Ee, (long long)Dd * Ss);
  // energy: 128^2 causal tiles, 4-wave 2-blk/CU deep-prefetch
  k_energy128<<<1088, 256, 0, stream>>>(q_hi, q_lo, k_hi, k_lo, attn);
  // softmax rows in-place + bf16 copy (causal-trimmed)
  k_softmax<<<dim3(Ss, Bb), 256, 0, stream>>>(attn, attn_bf, mask, inv_scale);
  // out per batch: [S,D] = attn_bf @ v (v_t is BT operand), K truncated causally
  k_gemm_bt<0, true><<<dim3(8, 16, 8), 256, 0, stream>>>(
      attn_bf, v_t, out, nullptr,
      2048, 1024, 2048, (long long)Ss * Ss, (long long)Dd * Ss, (long long)Ss * Dd);
}

// Round 6
// 514.525 us; speedup vs baseline: 1.0781x; 1.0781x over previous
//
#include <hip/hip_runtime.h>

#define Bb 8
#define Ss 2048
#define Ee 1024
#define Dd 1024

typedef __attribute__((ext_vector_type(8))) __bf16 bf16x8;
typedef __attribute__((ext_vector_type(4))) float f32x4;
typedef unsigned short u16;

__device__ __forceinline__ u16 f2bf(float x) {
  unsigned u = __float_as_uint(x);
  return (u16)((u + 0x7fffu + ((u >> 16) & 1u)) >> 16);
}
__device__ __forceinline__ float bf2f(u16 h) {
  return __uint_as_float(((unsigned)h) << 16);
}

__device__ __forceinline__ void gload16(const void* g, void* l) {
  __builtin_amdgcn_global_load_lds(
      (__attribute__((address_space(1))) void*)const_cast<void*>(g),
      (__attribute__((address_space(3))) void*)l, 16, 0, 0);
}

#define MFMA_BF16 __builtin_amdgcn_mfma_f32_16x16x32_bf16

// ---------------- fp32 -> bf16 hi/lo split (vectorized x4) ----------------
__global__ __launch_bounds__(256) void k_split4(const float* __restrict__ in,
                                                u16* __restrict__ hi,
                                                u16* __restrict__ lo,
                                                long long n4) {
  long long i = (long long)blockIdx.x * 256 + threadIdx.x;
  if (i >= n4) return;
  float4 v = ((const float4*)in)[i];
  float xs[4] = {v.x, v.y, v.z, v.w};
  u16 hh[4], ll[4];
#pragma unroll
  for (int j = 0; j < 4; ++j) {
    hh[j] = f2bf(xs[j]);
    ll[j] = f2bf(xs[j] - bf2f(hh[j]));
  }
  ushort4 h, l;
  h.x = hh[0]; h.y = hh[1]; h.z = hh[2]; h.w = hh[3];
  l.x = ll[0]; l.y = ll[1]; l.z = ll[2]; l.w = ll[3];
  ((ushort4*)hi)[i] = h;
  ((ushort4*)lo)[i] = l;
}

// ---------------- W [E,D] fp32 -> W^T [D,E] bf16 hi(/lo) ----------------
__global__ __launch_bounds__(256) void k_wt_split(const float* __restrict__ W,
                                                  u16* __restrict__ hi,
                                                  u16* __restrict__ lo) {
  __shared__ float t[32][33];
  const int tx = threadIdx.x & 31;
  const int ty = threadIdx.x >> 5;  // 0..7
  const int e0 = blockIdx.y * 32, d0 = blockIdx.x * 32;
#pragma unroll
  for (int r = ty; r < 32; r += 8)
    t[r][tx] = W[(long long)(e0 + r) * Dd + d0 + tx];
  __syncthreads();
#pragma unroll
  for (int r = ty; r < 32; r += 8) {
    float x = t[tx][r];  // = W[e0+tx][d0+r]
    long long o = (long long)(d0 + r) * Ee + e0 + tx;
    u16 h = f2bf(x);
    hi[o] = h;
    if (lo) lo[o] = f2bf(x - bf2f(h));
  }
}

// ======= fine-interleaved 8-phase 256x256 split-precision BT GEMM =========
// (round-4 kernel, verbatim: 122 us, 0 bank conflicts at M=16384)
// C[M,N] = (Ah+Al)(Bh+Bl)^T (drop Al*Bl).  8 waves (2Mx4N), per-wave 128x64,
// BK=32, dbuf LDS 128KiB.  Chunk-XOR LDS swizzle both sides.
template <int EPI>  // 0 = fp32 store, 1 = split hi/lo bf16 store
__global__ __launch_bounds__(512, 2) void k_gemm256(
    const u16* __restrict__ Ah, const u16* __restrict__ Al,
    const u16* __restrict__ Bh, const u16* __restrict__ Bl,
    float* __restrict__ Cf, u16* __restrict__ Ch, u16* __restrict__ Cl,
    int nbx, int N, int K) {
  const int nwg = gridDim.x;
  const int f = blockIdx.x;
  const int wgid = (f & 7) * (nwg >> 3) + (f >> 3);  // XCD chunk swizzle
  const int bx = wgid % nbx;
  const int by = wgid / nbx;

  __shared__ __align__(16) u16 lds[2][4][8192];

  const int tid = threadIdx.x;
  const int lane = tid & 63;
  const int w = tid >> 6;  // 0..7
  const int wr = w >> 2;   // 0..1
  const int wc = w & 3;    // 0..3

  const u16* srcBase[4] = {Ah, Al, Bh, Bl};
  const long long row0[2] = {(long long)by * 256, (long long)bx * 256};

  const int rL = tid >> 2;  // 0..127
  const int colOff = ((tid & 3) ^ ((tid >> 3) & 3)) * 8;
  const int rdOff = (lane & 15) * 64 + ((((lane >> 4) & 3) ^ ((lane >> 1) & 3)) << 4);

  const int AR = wr * 128;
  const int BR = wc * 64;
  const int nt = K / 32;

  // per-thread staging pointers (advance +32 u16 = 64B per K-tile)
  const u16* gp[8];
#pragma unroll
  for (int u = 0; u < 8; ++u) {
    const int mat = u >> 1, half = u & 1;
    const long long grow = row0[mat >> 1] + half * 128 + rL;
    gp[u] = srcBase[mat] + grow * (long long)K + colOff;
  }

#define GL(U)                                                              \
  do {                                                                     \
    gload16(gp[U], (char*)lds + (cur ^ 1) * 65536 + ((U) >> 1) * 16384 +   \
                       ((U)&1) * 8192 + w * 1024);                         \
    gp[U] += 32;                                                           \
  } while (0)

#define LDFRAG(mat, R) \
  (*(const bf16x8*)((const char*)&lds[cur][mat][0] + (R)*64 + rdOff))

#define RD_A(MH)                                      \
  _Pragma("unroll") for (int m = 0; m < 4; ++m) {     \
    aH[MH][m] = LDFRAG(0, AR + (MH)*64 + m * 16);     \
    aL[MH][m] = LDFRAG(1, AR + (MH)*64 + m * 16);     \
  }

#define RD_B(NI)                      \
  bH = LDFRAG(2, BR + (NI)*16);       \
  bL = LDFRAG(3, BR + (NI)*16);

#define CLUSTER(MH, NI)                                                          \
  __builtin_amdgcn_s_setprio(1);                                                 \
  _Pragma("unroll") for (int m = 0; m < 4; ++m)                                  \
      acc[(MH)*4 + m][NI] = MFMA_BF16(aH[MH][m], bL, acc[(MH)*4 + m][NI], 0, 0, 0); \
  _Pragma("unroll") for (int m = 0; m < 4; ++m)                                  \
      acc[(MH)*4 + m][NI] = MFMA_BF16(aL[MH][m], bH, acc[(MH)*4 + m][NI], 0, 0, 0); \
  _Pragma("unroll") for (int m = 0; m < 4; ++m)                                  \
      acc[(MH)*4 + m][NI] = MFMA_BF16(aH[MH][m], bH, acc[(MH)*4 + m][NI], 0, 0, 0); \
  __builtin_amdgcn_s_setprio(0);

#define BAR __builtin_amdgcn_s_barrier()

  f32x4 acc[8][4];
#pragma unroll
  for (int m = 0; m < 8; ++m)
#pragma unroll
    for (int n = 0; n < 4; ++n) acc[m][n] = f32x4{0.f, 0.f, 0.f, 0.f};

  bf16x8 aH[2][4], aL[2][4], bH, bL;

  // prologue: stage tile 0 fully (8 loads) into buf 0
  {
    const int cur = 1;  // so cur^1 == 0
#pragma unroll
    for (int u = 0; u < 8; ++u) GL(u);
  }

  for (int kt = 0; kt < nt; ++kt) {
    const int cur = kt & 1;
    const bool more = (kt + 1 < nt);

    if (more) {
      GL(0); GL(1);
      asm volatile("s_waitcnt vmcnt(2)" ::: "memory");
    } else {
      asm volatile("s_waitcnt vmcnt(0)" ::: "memory");
    }
    BAR;  // all waves' tile-kt staging landed; prev-tile reads long done

    // P0: A-mh0 + B-n0 (10 reads); MFMA (0,0)
    RD_A(0); RD_B(0);
    BAR; CLUSTER(0, 0); BAR;
    // P1: A-mh1 (8 reads); stage pair; MFMA (1,0)
    RD_A(1);
    if (more) { GL(2); GL(3); }
    BAR; CLUSTER(1, 0); BAR;
    // P2: B-n1; stage pair; MFMA (0,1)
    RD_B(1);
    if (more) { GL(4); GL(5); }
    BAR; CLUSTER(0, 1); BAR;
    // P3: stage pair; MFMA (1,1)
    if (more) { GL(6); GL(7); }
    BAR; CLUSTER(1, 1); BAR;
    // P4: B-n2; MFMA (0,2)
    RD_B(2);
    BAR; CLUSTER(0, 2); BAR;
    // P5: MFMA (1,2)
    CLUSTER(1, 2); BAR;
    // P6: B-n3; MFMA (0,3)
    RD_B(3);
    BAR; CLUSTER(0, 3); BAR;
    // P7: MFMA (1,3)
    CLUSTER(1, 3); BAR;
  }

  // epilogue: C/D map col=lane&15, row=(lane>>4)*4+reg
  const int cr = (lane >> 4) << 2;
  const int cc = lane & 15;
#pragma unroll
  for (int m = 0; m < 8; ++m)
#pragma unroll
    for (int n = 0; n < 4; ++n)
#pragma unroll
      for (int r = 0; r < 4; ++r) {
        const long long row = (long long)by * 256 + wr * 128 + m * 16 + cr + r;
        const long long col = (long long)bx * 256 + wc * 64 + n * 16 + cc;
        const long long idx = row * N + col;
        const float v = acc[m][n][r];
        if constexpr (EPI == 0) {
          Cf[idx] = v;
        } else {
          u16 h = f2bf(v);
          Ch[idx] = h;
          Cl[idx] = f2bf(v - bf2f(h));
        }
      }
#undef GL
#undef LDFRAG
#undef RD_A
#undef RD_B
#undef CLUSTER
#undef BAR
}

// ============ deep-prefetch 128x128 energy GEMM (4 waves, 2 blk/CU) =======
// energy_b = A_b B_b^T, split-precision 3-pass, causal tile set only.
// A = R [S,D] hi/lo, B = emb [S,E] hi/lo (batch stride S*1024 for both).
__global__ __launch_bounds__(256, 2) void k_energy128(
    const u16* __restrict__ qh, const u16* __restrict__ ql,
    const u16* __restrict__ kh, const u16* __restrict__ kl,
    float* __restrict__ attn) {
  const int nwg = gridDim.x;  // 1088
  const int f = blockIdx.x;
  const int wgid = (f & 7) * (nwg >> 3) + (f >> 3);
  const int bz = wgid / 136;
  const int t = wgid % 136;
  int by = 0, c = 0;
  while (c + by + 1 <= t) { c += by + 1; ++by; }  // <=16 iters
  const int bx = t - c;

  __shared__ __align__(16) u16 lds[2][4][4096];  // 64 KiB -> 2 blocks/CU

  const int tid = threadIdx.x;
  const int lane = tid & 63;
  const int w = tid >> 6;  // 0..3
  const int wr = w >> 1;   // 0..1
  const int wc = w & 1;    // 0..1

  const long long sQ = (long long)bz * Ss * Dd;
  const u16* srcBase[4] = {qh + sQ, ql + sQ, kh + sQ, kl + sQ};
  const long long row0[2] = {(long long)by * 128, (long long)bx * 128};

  const int rL = tid >> 2;  // 0..63
  const int colOff = ((tid & 3) ^ ((tid >> 3) & 3)) * 8;
  const int rdOff = (lane & 15) * 64 + ((((lane >> 4) & 3) ^ ((lane >> 1) & 3)) << 4);

  const int AR = wr * 64;
  const int BR = wc * 64;
  const int nt = Dd / 32;  // 32

#define STAGE8E(buf, kt)                                                \
  {                                                                     \
    _Pragma("unroll") for (int u = 0; u < 8; ++u) {                     \
      const int mat = u >> 1, half = u & 1;                             \
      const long long grow = row0[mat >> 1] + half * 64 + rL;           \
      gload16(srcBase[mat] + grow * Dd + (kt)*32 + colOff,              \
              (char*)&lds[buf][mat][0] + half * 4096 + w * 1024);       \
    }                                                                   \
  }
#define LDFRAGE(buf, mat, R) \
  (*(const bf16x8*)((const char*)&lds[buf][mat][0] + (R)*64 + rdOff))

  f32x4 acc[4][4];
#pragma unroll
  for (int m = 0; m < 4; ++m)
#pragma unroll
    for (int n = 0; n < 4; ++n) acc[m][n] = f32x4{0.f, 0.f, 0.f, 0.f};

  bf16x8 a_h[4], a_l[4], b_h[4], b_l[4];

  STAGE8E(0, 0);

  for (int kt = 0; kt < nt; ++kt) {
    const int cur = kt & 1;
    const bool more = (kt + 1 < nt);

    if (more) {
      STAGE8E(cur ^ 1, kt + 1);
      asm volatile("s_waitcnt vmcnt(8)" ::: "memory");
    } else {
      asm volatile("s_waitcnt vmcnt(0)" ::: "memory");
    }
    __builtin_amdgcn_s_barrier();  // data ready

#pragma unroll
    for (int m = 0; m < 4; ++m) {
      a_h[m] = LDFRAGE(cur, 0, AR + m * 16);
      a_l[m] = LDFRAGE(cur, 1, AR + m * 16);
    }
#pragma unroll
    for (int n = 0; n < 2; ++n) {
      b_h[n] = LDFRAGE(cur, 2, BR + n * 16);
      b_l[n] = LDFRAGE(cur, 3, BR + n * 16);
    }
    __builtin_amdgcn_s_barrier();
    __builtin_amdgcn_s_setprio(1);
#pragma unroll
    for (int m = 0; m < 4; ++m)
#pragma unroll
      for (int n = 0; n < 2; ++n) {
        acc[m][n] = MFMA_BF16(a_h[m], b_l[n], acc[m][n], 0, 0, 0);
        acc[m][n] = MFMA_BF16(a_l[m], b_h[n], acc[m][n], 0, 0, 0);
        acc[m][n] = MFMA_BF16(a_h[m], b_h[n], acc[m][n], 0, 0, 0);
      }
    __builtin_amdgcn_s_setprio(0);
    __builtin_amdgcn_s_barrier();

#pragma unroll
    for (int n = 2; n < 4; ++n) {
      b_h[n] = LDFRAGE(cur, 2, BR + n * 16);
      b_l[n] = LDFRAGE(cur, 3, BR + n * 16);
    }
    __builtin_amdgcn_s_barrier();
    __builtin_amdgcn_s_setprio(1);
#pragma unroll
    for (int m = 0; m < 4; ++m)
#pragma unroll
      for (int n = 2; n < 4; ++n) {
        acc[m][n] = MFMA_BF16(a_h[m], b_l[n], acc[m][n], 0, 0, 0);
        acc[m][n] = MFMA_BF16(a_l[m], b_h[n], acc[m][n], 0, 0, 0);
        acc[m][n] = MFMA_BF16(a_h[m], b_h[n], acc[m][n], 0, 0, 0);
      }
    __builtin_amdgcn_s_setprio(0);
    __builtin_amdgcn_s_barrier();
  }

  const int cr = (lane >> 4) << 2;
  const int cc = lane & 15;
#pragma unroll
  for (int m = 0; m < 4; ++m)
#pragma unroll
    for (int n = 0; n < 4; ++n)
#pragma unroll
      for (int r = 0; r < 4; ++r) {
        const long long row = (long long)by * 128 + wr * 64 + m * 16 + cr + r;
        const long long col = (long long)bx * 128 + wc * 64 + n * 16 + cc;
        attn[(long long)bz * Ss * Ss + row * Ss + col] = acc[m][n][r];
      }
#undef STAGE8E
#undef LDFRAGE
}

// ---------------- 128x128-tile BT-layout MFMA GEMM (NPASS=1) --------------
template <int EPI, bool TRIK>
__global__ __launch_bounds__(256) void k_gemm_bt(
    const u16* __restrict__ Ah, const u16* __restrict__ Bh,
    float* __restrict__ Cf, u16* __restrict__ Ch,
    int M, int N, int K, long long strA, long long strB, long long strC) {
  const int bx = blockIdx.x, by = blockIdx.y, bz = blockIdx.z;

  const int tid = threadIdx.x;
  const int lane = tid & 63;
  const int w = tid >> 6;
  const int wr = w >> 1, wc = w & 1;

  const u16* pAh = Ah + (long long)bz * strA;
  const u16* pBh = Bh + (long long)bz * strB;

  __shared__ __align__(16) u16 lds[2 * 128 * 32];
  char* ldsc = (char*)lds;

  const int srow = tid >> 2;
  const int scol = (tid & 3) * 8;
  const long long arow = (long long)by * 128 + srow;
  const long long brow = (long long)bx * 128 + srow;

  int ktEnd = K / 32;
  if (TRIK) {
    int lim = ((by + 1) * 128) / 32;
    if (lim < ktEnd) ktEnd = lim;
  }

  f32x4 acc[4][4];
#pragma unroll
  for (int i = 0; i < 4; ++i)
#pragma unroll
    for (int j = 0; j < 4; ++j) acc[i][j] = f32x4{0.f, 0.f, 0.f, 0.f};

  for (int kt = 0; kt < ktEnd; ++kt) {
    const int k0 = kt * 32 + scol;
    __syncthreads();
    gload16(pAh + arow * K + k0, ldsc + 0 * 4096 + w * 1024);
    gload16(pAh + (arow + 64) * K + k0, ldsc + 1 * 4096 + w * 1024);
    gload16(pBh + brow * K + k0, ldsc + 8192 + 0 * 4096 + w * 1024);
    gload16(pBh + (brow + 64) * K + k0, ldsc + 8192 + 1 * 4096 + w * 1024);
    __syncthreads();

    const int kk = (lane >> 4) * 8;
    const int ar = wr * 64 + (lane & 15);
    const int br = wc * 64 + (lane & 15);
    bf16x8 avh[4], bvh[4];
#pragma unroll
    for (int m = 0; m < 4; ++m)
      avh[m] = *(const bf16x8*)(lds + (ar + m * 16) * 32 + kk);
#pragma unroll
    for (int n = 0; n < 4; ++n)
      bvh[n] = *(const bf16x8*)(lds + 128 * 32 + (br + n * 16) * 32 + kk);
#pragma unroll
    for (int m = 0; m < 4; ++m)
#pragma unroll
      for (int n = 0; n < 4; ++n)
        acc[m][n] = MFMA_BF16(avh[m], bvh[n], acc[m][n], 0, 0, 0);
  }

  const int cr = wr * 64 + ((lane >> 4) << 2);
  const int cc = wc * 64 + (lane & 15);
  const long long rb = (long long)by * 128 + cr;
  const long long cb = (long long)bx * 128 + cc;
#pragma unroll
  for (int m = 0; m < 4; ++m)
#pragma unroll
    for (int n = 0; n < 4; ++n)
#pragma unroll
      for (int r = 0; r < 4; ++r) {
        const long long idx =
            (long long)bz * strC + (rb + m * 16 + r) * (long long)N + (cb + n * 16);
        const float v = acc[m][n][r];
        if constexpr (EPI == 0) Cf[idx] = v;
        else Ch[idx] = f2bf(v);
      }
}

// -------- causal+pad masked row softmax (in-place, causal-trimmed) --------
__global__ __launch_bounds__(256) void k_softmax(float* __restrict__ attn,
                                                 u16* __restrict__ attn_bf,
                                                 const int* __restrict__ mask,
                                                 float inv_scale) {
  const int q = blockIdx.x;
  const int b = blockIdx.y;
  const int tid = threadIdx.x;
  float* row = attn + ((long long)b * Ss + q) * Ss;
  u16* rowb = attn_bf + ((long long)b * Ss + q) * Ss;
  const int* mrow = mask + b * Ss;
  const int qup = ((q >> 7) + 1) << 7;  // PV's TRIK reads bf16 cols < qup

  float x[8];
  float m = -3.0e38f;
#pragma unroll
  for (int j = 0; j < 8; ++j) {
    const int k = tid + j * 256;
    float v = -3.0e38f;
    if (k <= q) {
      const float e = row[k];
      v = ((mrow[k] != 0) ? e : -1e20f) * inv_scale;
    }
    x[j] = v;
    m = fmaxf(m, v);
  }
#pragma unroll
  for (int o = 32; o > 0; o >>= 1) m = fmaxf(m, __shfl_xor(m, o));
  __shared__ float redm[4], reds[4];
  const int w = tid >> 6;
  if ((tid & 63) == 0) redm[w] = m;
  __syncthreads();
  m = fmaxf(fmaxf(redm[0], redm[1]), fmaxf(redm[2], redm[3]));
  float s = 0.f;
#pragma unroll
  for (int j = 0; j < 8; ++j) {
    x[j] = __expf(x[j] - m);
    s += x[j];
  }
#pragma unroll
  for (int o = 32; o > 0; o >>= 1) s += __shfl_xor(s, o);
  if ((tid & 63) == 0) reds[w] = s;
  __syncthreads();
  s = reds[0] + reds[1] + reds[2] + reds[3];
  const float inv = 1.0f / s;
#pragma unroll
  for (int j = 0; j < 8; ++j) {
    const int k = tid + j * 256;
    if (k <= q) {
      const float a = x[j] * inv;
      row[k] = a;
      rowb[k] = f2bf(a);
    } else {
      row[k] = 0.0f;          // exact: reference gives exp(-inf)=0 here
      if (k < qup) rowb[k] = 0;
    }
  }
}

extern "C" void kernel_launch(void* const* d_in, const int* in_sizes, int n_in,
                              void* d_out, int out_size, void* d_ws, size_t ws_size,
                              hipStream_t stream) {
  const float* emb = (const float*)d_in[0];
  const int* mask = (const int*)d_in[1];
  const float* Wq = (const float*)d_in[2];
  const float* Wk = (const float*)d_in[3];
  const float* Wv = (const float*)d_in[4];

  float* out = (float*)d_out;                   // [8,2048,1024] fp32
  float* attn = out + (long long)Bb * Ss * Dd;  // [8,2048,2048] fp32

  // workspace carve (~206 MB)
  char* p = (char*)d_ws;
  u16* emb_hi = (u16*)p;                    // alive through energy
  u16* emb_lo = emb_hi + 16777216LL;
  u16* R_hi = (u16*)(p + 67108864LL);       // R = emb @ (Wq Wk^T)
  u16* R_lo = R_hi + 16777216LL;
  u16* v_t = R_lo + 16777216LL;             // [b][D][S] bf16
  u16* attn_bf = v_t + 16777216LL;          // own buffer (no alias)
  u16* Wqr_hi = attn_bf + 16777216LL;       // raw Wq split [E,D]
  u16* Wqr_lo = Wqr_hi + 1048576LL;
  u16* Wkr_hi = Wqr_lo + 1048576LL;         // raw Wk split [E,D]
  u16* Wkr_lo = Wkr_hi + 1048576LL;
  u16* M_hi = Wkr_lo + 1048576LL;           // M'' = Wk Wq^T  [e][d]
  u16* M_lo = M_hi + 1048576LL;
  u16* WvT_hi = M_lo + 1048576LL;           // Wv^T [D,E]

  const float inv_scale = 1.0f / (32.0f + 1.1920929e-07f);

  k_split4<<<16384, 256, 0, stream>>>(emb, emb_hi, emb_lo, 4194304LL);
  k_split4<<<1024, 256, 0, stream>>>(Wq, Wqr_hi, Wqr_lo, 262144LL);
  k_split4<<<1024, 256, 0, stream>>>(Wk, Wkr_hi, Wkr_lo, 262144LL);
  k_wt_split<<<dim3(32, 32), 256, 0, stream>>>(Wv, WvT_hi, nullptr);

  // M'' = Wk @ Wq^T  (split 3-pass, split-bf16 out): B-operand for R-GEMM,
  // since R[s,e] = sum_d emb[s,d] * M''[e,d] with M''[e,d] = (Wk Wq^T)[e,d].
  k_gemm256<1><<<16, 512, 0, stream>>>(
      Wkr_hi, Wkr_lo, Wqr_hi, Wqr_lo, nullptr, M_hi, M_lo, 4, 1024, 1024);
  // R = emb @ M''^T(BT form): M=16384, N=1024, K=1024
  k_gemm256<1><<<256, 512, 0, stream>>>(
      emb_hi, emb_lo, M_hi, M_lo, nullptr, R_hi, R_lo, 4, 1024, 1024);
  // v^T per batch: [D,S] = Wv^T[D,E] x emb_b (BT), single-pass bf16
  k_gemm_bt<2, false><<<dim3(16, 8, 8), 256, 0, stream>>>(
      WvT_hi, emb_hi, nullptr, v_t,
      1024, 2048, 1024, 0, (long long)Ss * Ee, (long long)Dd * Ss);
  // energy per batch: [S,S] = R_b emb_b^T  (== q k^T by associativity)
  k_energy128<<<1088, 256, 0, stream>>>(R_hi, R_lo, emb_hi, emb_lo, attn);
  // softmax rows in-place + bf16 copy (causal-trimmed)
  k_softmax<<<dim3(Ss, Bb), 256, 0, stream>>>(attn, attn_bf, mask, inv_scale);
  // out per batch: [S,D] = attn_bf @ v (v_t is BT operand), K truncated causally
  k_gemm_bt<0, true><<<dim3(8, 16, 8), 256, 0, stream>>>(
      attn_bf, v_t, out, nullptr,
      2048, 1024, 2048, (long long)Ss * Ss, (long long)Dd * Ss, (long long)Ss * Dd);
}

// Round 7
// 486.800 us; speedup vs baseline: 1.1395x; 1.0570x over previous
//
#include <hip/hip_runtime.h>

#define Bb 8
#define Ss 2048
#define Ee 1024
#define Dd 1024

typedef __attribute__((ext_vector_type(8))) __bf16 bf16x8;
typedef __attribute__((ext_vector_type(4))) float f32x4;
typedef unsigned short u16;

__device__ __forceinline__ u16 f2bf(float x) {
  unsigned u = __float_as_uint(x);
  return (u16)((u + 0x7fffu + ((u >> 16) & 1u)) >> 16);
}
__device__ __forceinline__ float bf2f(u16 h) {
  return __uint_as_float(((unsigned)h) << 16);
}

__device__ __forceinline__ void gload16(const void* g, void* l) {
  __builtin_amdgcn_global_load_lds(
      (__attribute__((address_space(1))) void*)const_cast<void*>(g),
      (__attribute__((address_space(3))) void*)l, 16, 0, 0);
}

#define MFMA_BF16 __builtin_amdgcn_mfma_f32_16x16x32_bf16

// ---------------- fp32 -> bf16 hi/lo split (vectorized x4) ----------------
__global__ __launch_bounds__(256) void k_split4(const float* __restrict__ in,
                                                u16* __restrict__ hi,
                                                u16* __restrict__ lo,
                                                long long n4) {
  long long i = (long long)blockIdx.x * 256 + threadIdx.x;
  if (i >= n4) return;
  float4 v = ((const float4*)in)[i];
  float xs[4] = {v.x, v.y, v.z, v.w};
  u16 hh[4], ll[4];
#pragma unroll
  for (int j = 0; j < 4; ++j) {
    hh[j] = f2bf(xs[j]);
    ll[j] = f2bf(xs[j] - bf2f(hh[j]));
  }
  ushort4 h, l;
  h.x = hh[0]; h.y = hh[1]; h.z = hh[2]; h.w = hh[3];
  l.x = ll[0]; l.y = ll[1]; l.z = ll[2]; l.w = ll[3];
  ((ushort4*)hi)[i] = h;
  ((ushort4*)lo)[i] = l;
}

// ---------------- W [E,D] fp32 -> W^T [D,E] bf16 hi(/lo) ----------------
__global__ __launch_bounds__(256) void k_wt_split(const float* __restrict__ W,
                                                  u16* __restrict__ hi,
                                                  u16* __restrict__ lo) {
  __shared__ float t[32][33];
  const int tx = threadIdx.x & 31;
  const int ty = threadIdx.x >> 5;  // 0..7
  const int e0 = blockIdx.y * 32, d0 = blockIdx.x * 32;
#pragma unroll
  for (int r = ty; r < 32; r += 8)
    t[r][tx] = W[(long long)(e0 + r) * Dd + d0 + tx];
  __syncthreads();
#pragma unroll
  for (int r = ty; r < 32; r += 8) {
    float x = t[tx][r];  // = W[e0+tx][d0+r]
    long long o = (long long)(d0 + r) * Ee + e0 + tx;
    u16 h = f2bf(x);
    hi[o] = h;
    if (lo) lo[o] = f2bf(x - bf2f(h));
  }
}

// ====== unified 128x128 split-precision 3-pass BT GEMM, 8 waves ==========
// C = (Ah+Al)(Bh+Bl)^T (drop Al*Bl).  512 thr = 8 waves (4M x 2N), per-wave
// 32x64 out, BK=32, dbuf LDS 64 KiB -> 2 blocks/CU = 4 waves/SIMD (the
// occupancy lever: prior structures ran 2 waves/SIMD at 33-40% MfmaUtil).
// Staging burst-4 + vmcnt(4); chunk-XOR swizzle both sides (verified 0-conf).
// EPI: 0 = fp32 store (+strC batch), 1 = split hi/lo bf16 store.
// CAUSAL: grid = 8 batches x 136 lower-triangle tiles; else flat nbx grid.
template <int EPI, bool CAUSAL>
__global__ __launch_bounds__(512, 4) void k_g128(
    const u16* __restrict__ Ah, const u16* __restrict__ Al,
    const u16* __restrict__ Bh, const u16* __restrict__ Bl,
    float* __restrict__ Cf, u16* __restrict__ Ch, u16* __restrict__ Cl,
    int nbx, int N, int K, long long strOp, long long strC) {
  const int nwg = gridDim.x;
  const int f = blockIdx.x;
  const int wgid = (f & 7) * (nwg >> 3) + (f >> 3);  // XCD chunk swizzle
  int bx, by, bz;
  if (CAUSAL) {
    bz = wgid / 136;
    const int t = wgid % 136;
    int yy = 0, c = 0;
    while (c + yy + 1 <= t) { c += yy + 1; ++yy; }  // <=16 iters
    by = yy;
    bx = t - c;
  } else {
    bz = 0;
    bx = wgid % nbx;
    by = wgid / nbx;
  }

  // lds[buf][mat][128 rows x 32 bf16]; mat: 0=Ah 1=Al 2=Bh 3=Bl.
  __shared__ __align__(16) u16 lds[2][4][4096];  // 64 KiB

  const int tid = threadIdx.x;
  const int lane = tid & 63;
  const int w = tid >> 6;  // 0..7
  const int wr = w >> 1;   // 0..3  (M quarter)
  const int wc = w & 1;    // 0..1  (N half)

  const long long ob = (long long)bz * strOp;
  const u16* srcBase[4] = {Ah + ob, Al + ob, Bh + ob, Bl + ob};
  const long long row0[2] = {(long long)by * 128, (long long)bx * 128};

  const int rL = tid >> 2;  // 0..127 (stage row)
  const int colOff = ((tid & 3) ^ ((tid >> 3) & 3)) * 8;
  const int rdOff = (lane & 15) * 64 + ((((lane >> 4) & 3) ^ ((lane >> 1) & 3)) << 4);

  const int AR = wr * 32;
  const int BR = wc * 64;
  const int nt = K / 32;

  // per-thread staging pointers, one per mat (advance +32 u16/tile)
  const u16* gp[4];
#pragma unroll
  for (int m = 0; m < 4; ++m)
    gp[m] = srcBase[m] + (row0[m >> 1] + rL) * (long long)K + colOff;

#define STG(BUF)                                                       \
  {                                                                    \
    _Pragma("unroll") for (int m = 0; m < 4; ++m) {                    \
      gload16(gp[m], (char*)&lds[BUF][m][0] + tid * 16);               \
      gp[m] += 32;                                                     \
    }                                                                  \
  }
#define LDFRAG(MAT, R) \
  (*(const bf16x8*)((const char*)&lds[cur][MAT][0] + (R)*64 + rdOff))
#define BAR __builtin_amdgcn_s_barrier()

// 12 MFMA: pass-major over 2m x 2n (same-acc distance 4)
#define CLUSTER(NH)                                                          \
  __builtin_amdgcn_s_setprio(1);                                             \
  _Pragma("unroll") for (int m = 0; m < 2; ++m)                              \
      _Pragma("unroll") for (int n = 0; n < 2; ++n)                          \
          acc[m][(NH)*2 + n] =                                               \
      MFMA_BF16(aH[m], bL[n], acc[m][(NH)*2 + n], 0, 0, 0);                  \
  _Pragma("unroll") for (int m = 0; m < 2; ++m)                              \
      _Pragma("unroll") for (int n = 0; n < 2; ++n)                          \
          acc[m][(NH)*2 + n] =                                               \
      MFMA_BF16(aL[m], bH[n], acc[m][(NH)*2 + n], 0, 0, 0);                  \
  _Pragma("unroll") for (int m = 0; m < 2; ++m)                              \
      _Pragma("unroll") for (int n = 0; n < 2; ++n)                          \
          acc[m][(NH)*2 + n] =                                               \
      MFMA_BF16(aH[m], bH[n], acc[m][(NH)*2 + n], 0, 0, 0);                  \
  __builtin_amdgcn_s_setprio(0);

  f32x4 acc[2][4];
#pragma unroll
  for (int m = 0; m < 2; ++m)
#pragma unroll
    for (int n = 0; n < 4; ++n) acc[m][n] = f32x4{0.f, 0.f, 0.f, 0.f};

  bf16x8 aH[2], aL[2], bH[2], bL[2];

  STG(0);  // prologue: tile 0

  for (int kt = 0; kt < nt; ++kt) {
    const int cur = kt & 1;
    const bool more = (kt + 1 < nt);

    if (more) {
      STG(cur ^ 1);
      asm volatile("s_waitcnt vmcnt(4)" ::: "memory");
    } else {
      asm volatile("s_waitcnt vmcnt(0)" ::: "memory");
    }
    BAR;  // tile-kt staged everywhere; prev-tile reads done

    // P0: A frags + B n0-1
#pragma unroll
    for (int m = 0; m < 2; ++m) {
      aH[m] = LDFRAG(0, AR + m * 16);
      aL[m] = LDFRAG(1, AR + m * 16);
    }
#pragma unroll
    for (int n = 0; n < 2; ++n) {
      bH[n] = LDFRAG(2, BR + n * 16);
      bL[n] = LDFRAG(3, BR + n * 16);
    }
    BAR;
    CLUSTER(0);
    BAR;

    // P1: B n2-3
#pragma unroll
    for (int n = 0; n < 2; ++n) {
      bH[n] = LDFRAG(2, BR + 32 + n * 16);
      bL[n] = LDFRAG(3, BR + 32 + n * 16);
    }
    BAR;
    CLUSTER(1);
    BAR;
  }

  // epilogue: C/D map col=lane&15, row=(lane>>4)*4+reg
  const int cr = (lane >> 4) << 2;
  const int cc = lane & 15;
#pragma unroll
  for (int m = 0; m < 2; ++m)
#pragma unroll
    for (int n = 0; n < 4; ++n)
#pragma unroll
      for (int r = 0; r < 4; ++r) {
        const long long row = (long long)by * 128 + wr * 32 + m * 16 + cr + r;
        const long long col = (long long)bx * 128 + wc * 64 + n * 16 + cc;
        const float v = acc[m][n][r];
        if constexpr (EPI == 0) {
          Cf[(long long)bz * strC + row * N + col] = v;
        } else {
          const long long idx = row * N + col;
          u16 h = f2bf(v);
          Ch[idx] = h;
          Cl[idx] = f2bf(v - bf2f(h));
        }
      }
#undef STG
#undef LDFRAG
#undef BAR
#undef CLUSTER
}

// ---------------- 128x128-tile BT-layout MFMA GEMM (NPASS=1) --------------
template <int EPI, bool TRIK>
__global__ __launch_bounds__(256) void k_gemm_bt(
    const u16* __restrict__ Ah, const u16* __restrict__ Bh,
    float* __restrict__ Cf, u16* __restrict__ Ch,
    int M, int N, int K, long long strA, long long strB, long long strC) {
  const int bx = blockIdx.x, by = blockIdx.y, bz = blockIdx.z;

  const int tid = threadIdx.x;
  const int lane = tid & 63;
  const int w = tid >> 6;
  const int wr = w >> 1, wc = w & 1;

  const u16* pAh = Ah + (long long)bz * strA;
  const u16* pBh = Bh + (long long)bz * strB;

  __shared__ __align__(16) u16 lds[2 * 128 * 32];
  char* ldsc = (char*)lds;

  const int srow = tid >> 2;
  const int scol = (tid & 3) * 8;
  const long long arow = (long long)by * 128 + srow;
  const long long brow = (long long)bx * 128 + srow;

  int ktEnd = K / 32;
  if (TRIK) {
    int lim = ((by + 1) * 128) / 32;
    if (lim < ktEnd) ktEnd = lim;
  }

  f32x4 acc[4][4];
#pragma unroll
  for (int i = 0; i < 4; ++i)
#pragma unroll
    for (int j = 0; j < 4; ++j) acc[i][j] = f32x4{0.f, 0.f, 0.f, 0.f};

  for (int kt = 0; kt < ktEnd; ++kt) {
    const int k0 = kt * 32 + scol;
    __syncthreads();
    gload16(pAh + arow * K + k0, ldsc + 0 * 4096 + w * 1024);
    gload16(pAh + (arow + 64) * K + k0, ldsc + 1 * 4096 + w * 1024);
    gload16(pBh + brow * K + k0, ldsc + 8192 + 0 * 4096 + w * 1024);
    gload16(pBh + (brow + 64) * K + k0, ldsc + 8192 + 1 * 4096 + w * 1024);
    __syncthreads();

    const int kk = (lane >> 4) * 8;
    const int ar = wr * 64 + (lane & 15);
    const int br = wc * 64 + (lane & 15);
    bf16x8 avh[4], bvh[4];
#pragma unroll
    for (int m = 0; m < 4; ++m)
      avh[m] = *(const bf16x8*)(lds + (ar + m * 16) * 32 + kk);
#pragma unroll
    for (int n = 0; n < 4; ++n)
      bvh[n] = *(const bf16x8*)(lds + 128 * 32 + (br + n * 16) * 32 + kk);
#pragma unroll
    for (int m = 0; m < 4; ++m)
#pragma unroll
      for (int n = 0; n < 4; ++n)
        acc[m][n] = MFMA_BF16(avh[m], bvh[n], acc[m][n], 0, 0, 0);
  }

  const int cr = wr * 64 + ((lane >> 4) << 2);
  const int cc = wc * 64 + (lane & 15);
  const long long rb = (long long)by * 128 + cr;
  const long long cb = (long long)bx * 128 + cc;
#pragma unroll
  for (int m = 0; m < 4; ++m)
#pragma unroll
    for (int n = 0; n < 4; ++n)
#pragma unroll
      for (int r = 0; r < 4; ++r) {
        const long long idx =
            (long long)bz * strC + (rb + m * 16 + r) * (long long)N + (cb + n * 16);
        const float v = acc[m][n][r];
        if constexpr (EPI == 0) Cf[idx] = v;
        else Ch[idx] = f2bf(v);
      }
}

// -------- causal+pad masked row softmax (in-place, causal-trimmed) --------
__global__ __launch_bounds__(256) void k_softmax(float* __restrict__ attn,
                                                 u16* __restrict__ attn_bf,
                                                 const int* __restrict__ mask,
                                                 float inv_scale) {
  const int q = blockIdx.x;
  const int b = blockIdx.y;
  const int tid = threadIdx.x;
  float* row = attn + ((long long)b * Ss + q) * Ss;
  u16* rowb = attn_bf + ((long long)b * Ss + q) * Ss;
  const int* mrow = mask + b * Ss;
  const int qup = ((q >> 7) + 1) << 7;  // PV's TRIK reads bf16 cols < qup

  float x[8];
  float m = -3.0e38f;
#pragma unroll
  for (int j = 0; j < 8; ++j) {
    const int k = tid + j * 256;
    float v = -3.0e38f;
    if (k <= q) {
      const float e = row[k];
      v = ((mrow[k] != 0) ? e : -1e20f) * inv_scale;
    }
    x[j] = v;
    m = fmaxf(m, v);
  }
#pragma unroll
  for (int o = 32; o > 0; o >>= 1) m = fmaxf(m, __shfl_xor(m, o));
  __shared__ float redm[4], reds[4];
  const int w = tid >> 6;
  if ((tid & 63) == 0) redm[w] = m;
  __syncthreads();
  m = fmaxf(fmaxf(redm[0], redm[1]), fmaxf(redm[2], redm[3]));
  float s = 0.f;
#pragma unroll
  for (int j = 0; j < 8; ++j) {
    x[j] = __expf(x[j] - m);
    s += x[j];
  }
#pragma unroll
  for (int o = 32; o > 0; o >>= 1) s += __shfl_xor(s, o);
  if ((tid & 63) == 0) reds[w] = s;
  __syncthreads();
  s = reds[0] + reds[1] + reds[2] + reds[3];
  const float inv = 1.0f / s;
#pragma unroll
  for (int j = 0; j < 8; ++j) {
    const int k = tid + j * 256;
    if (k <= q) {
      const float a = x[j] * inv;
      row[k] = a;
      rowb[k] = f2bf(a);
    } else {
      row[k] = 0.0f;          // exact: reference gives exp(-inf)=0 here
      if (k < qup) rowb[k] = 0;
    }
  }
}

extern "C" void kernel_launch(void* const* d_in, const int* in_sizes, int n_in,
                              void* d_out, int out_size, void* d_ws, size_t ws_size,
                              hipStream_t stream) {
  const float* emb = (const float*)d_in[0];
  const int* mask = (const int*)d_in[1];
  const float* Wq = (const float*)d_in[2];
  const float* Wk = (const float*)d_in[3];
  const float* Wv = (const float*)d_in[4];

  float* out = (float*)d_out;                   // [8,2048,1024] fp32
  float* attn = out + (long long)Bb * Ss * Dd;  // [8,2048,2048] fp32

  // workspace carve (~206 MB)
  char* p = (char*)d_ws;
  u16* emb_hi = (u16*)p;                    // alive through energy
  u16* emb_lo = emb_hi + 16777216LL;
  u16* R_hi = (u16*)(p + 67108864LL);       // R = emb @ (Wq Wk^T)
  u16* R_lo = R_hi + 16777216LL;
  u16* v_t = R_lo + 16777216LL;             // [b][D][S] bf16
  u16* attn_bf = v_t + 16777216LL;          // own buffer (no alias)
  u16* Wqr_hi = attn_bf + 16777216LL;       // raw Wq split [E,D]
  u16* Wqr_lo = Wqr_hi + 1048576LL;
  u16* Wkr_hi = Wqr_lo + 1048576LL;         // raw Wk split [E,D]
  u16* Wkr_lo = Wkr_hi + 1048576LL;
  u16* M_hi = Wkr_lo + 1048576LL;           // M'' = Wk Wq^T  [e][d]
  u16* M_lo = M_hi + 1048576LL;
  u16* WvT_hi = M_lo + 1048576LL;           // Wv^T [D,E]

  const float inv_scale = 1.0f / (32.0f + 1.1920929e-07f);

  k_split4<<<16384, 256, 0, stream>>>(emb, emb_hi, emb_lo, 4194304LL);
  k_split4<<<1024, 256, 0, stream>>>(Wq, Wqr_hi, Wqr_lo, 262144LL);
  k_split4<<<1024, 256, 0, stream>>>(Wk, Wkr_hi, Wkr_lo, 262144LL);
  k_wt_split<<<dim3(32, 32), 256, 0, stream>>>(Wv, WvT_hi, nullptr);

  // M'' = Wk @ Wq^T  (split 3-pass, split-bf16 out)
  k_g128<1, false><<<64, 512, 0, stream>>>(
      Wkr_hi, Wkr_lo, Wqr_hi, Wqr_lo, nullptr, M_hi, M_lo, 8, 1024, 1024, 0, 0);
  // R = emb @ M''^T (BT form): M=16384, N=1024, K=1024 -> 1024 blocks
  k_g128<1, false><<<1024, 512, 0, stream>>>(
      emb_hi, emb_lo, M_hi, M_lo, nullptr, R_hi, R_lo, 8, 1024, 1024, 0, 0);
  // v^T per batch: [D,S] = Wv^T[D,E] x emb_b (BT), single-pass bf16
  k_gemm_bt<2, false><<<dim3(16, 8, 8), 256, 0, stream>>>(
      WvT_hi, emb_hi, nullptr, v_t,
      1024, 2048, 1024, 0, (long long)Ss * Ee, (long long)Dd * Ss);
  // energy per batch: [S,S] = R_b emb_b^T  (== q k^T by associativity)
  k_g128<0, true><<<1088, 512, 0, stream>>>(
      R_hi, R_lo, emb_hi, emb_lo, attn, nullptr, nullptr,
      0, Ss, Dd, (long long)Ss * Dd, (long long)Ss * Ss);
  // softmax rows in-place + bf16 copy (causal-trimmed)
  k_softmax<<<dim3(Ss, Bb), 256, 0, stream>>>(attn, attn_bf, mask, inv_scale);
  // out per batch: [S,D] = attn_bf @ v (v_t is BT operand), K truncated causally
  k_gemm_bt<0, true><<<dim3(8, 16, 8), 256, 0, stream>>>(
      attn_bf, v_t, out, nullptr,
      2048, 1024, 2048, (long long)Ss * Ss, (long long)Dd * Ss, (long long)Ss * Dd);
}

// Round 8
// 469.584 us; speedup vs baseline: 1.1813x; 1.0367x over previous
//
#include <hip/hip_runtime.h>

#define Bb 8
#define Ss 2048
#define Ee 1024
#define Dd 1024

typedef __attribute__((ext_vector_type(8))) __bf16 bf16x8;
typedef __attribute__((ext_vector_type(4))) float f32x4;
typedef unsigned short u16;

__device__ __forceinline__ u16 f2bf(float x) {
  unsigned u = __float_as_uint(x);
  return (u16)((u + 0x7fffu + ((u >> 16) & 1u)) >> 16);
}
__device__ __forceinline__ float bf2f(u16 h) {
  return __uint_as_float(((unsigned)h) << 16);
}

__device__ __forceinline__ void gload16(const void* g, void* l) {
  __builtin_amdgcn_global_load_lds(
      (__attribute__((address_space(1))) void*)const_cast<void*>(g),
      (__attribute__((address_space(3))) void*)l, 16, 0, 0);
}

#define MFMA_BF16 __builtin_amdgcn_mfma_f32_16x16x32_bf16

// ---------------- fp32 -> bf16 hi/lo split (vectorized x4) ----------------
__global__ __launch_bounds__(256) void k_split4(const float* __restrict__ in,
                                                u16* __restrict__ hi,
                                                u16* __restrict__ lo,
                                                long long n4) {
  long long i = (long long)blockIdx.x * 256 + threadIdx.x;
  if (i >= n4) return;
  float4 v = ((const float4*)in)[i];
  float xs[4] = {v.x, v.y, v.z, v.w};
  u16 hh[4], ll[4];
#pragma unroll
  for (int j = 0; j < 4; ++j) {
    hh[j] = f2bf(xs[j]);
    ll[j] = f2bf(xs[j] - bf2f(hh[j]));
  }
  ushort4 h, l;
  h.x = hh[0]; h.y = hh[1]; h.z = hh[2]; h.w = hh[3];
  l.x = ll[0]; l.y = ll[1]; l.z = ll[2]; l.w = ll[3];
  ((ushort4*)hi)[i] = h;
  ((ushort4*)lo)[i] = l;
}

// ---------------- W [E,D] fp32 -> W^T [D,E] bf16 hi(/lo) ----------------
__global__ __launch_bounds__(256) void k_wt_split(const float* __restrict__ W,
                                                  u16* __restrict__ hi,
                                                  u16* __restrict__ lo) {
  __shared__ float t[32][33];
  const int tx = threadIdx.x & 31;
  const int ty = threadIdx.x >> 5;  // 0..7
  const int e0 = blockIdx.y * 32, d0 = blockIdx.x * 32;
#pragma unroll
  for (int r = ty; r < 32; r += 8)
    t[r][tx] = W[(long long)(e0 + r) * Dd + d0 + tx];
  __syncthreads();
#pragma unroll
  for (int r = ty; r < 32; r += 8) {
    float x = t[tx][r];  // = W[e0+tx][d0+r]
    long long o = (long long)(d0 + r) * Ee + e0 + tx;
    u16 h = f2bf(x);
    hi[o] = h;
    if (lo) lo[o] = f2bf(x - bf2f(h));
  }
}

// ====== unified 128x128 BT GEMM, 8 waves (4M x 2N), per-wave 32x64 =======
// NP=3: split-precision C=(Ah+Al)(Bh+Bl)^T (drop AlBl); 4 LDS mats, 64 KiB
// dbuf, vmcnt(4) gate, two read-phases (verified r7: 0 conflicts).
// NP=1: plain bf16 C=A B^T; 2 LDS mats, 32 KiB dbuf, vmcnt(2) gate, one
// read-phase {2A + 4B reads -> 8 MFMA}.
// EPI: 0 = fp32 store (+strC), 1 = split hi/lo bf16 (no stride), 2 = bf16
// store (+strC).  CAUSAL: grid = 8 x 136 lower-triangle tiles (bz folded).
// TRIK: truncate K at (by+1)*128 (PV causal column trim).
template <int NP, int EPI, bool CAUSAL, bool TRIK>
__global__ __launch_bounds__(512, 4) void k_t128(
    const u16* __restrict__ Ah, const u16* __restrict__ Al,
    const u16* __restrict__ Bh, const u16* __restrict__ Bl,
    float* __restrict__ Cf, u16* __restrict__ Ch, u16* __restrict__ Cl,
    int nbx, int N, int K, long long strA, long long strB, long long strC) {
  constexpr int NMAT = (NP == 3) ? 4 : 2;
  const int nwg = gridDim.x;
  const int f = blockIdx.x;
  const int wgid = (f & 7) * (nwg >> 3) + (f >> 3);  // XCD chunk swizzle
  int bx, by, bz;
  if (CAUSAL) {
    bz = wgid / 136;
    const int t = wgid % 136;
    int yy = 0, c = 0;
    while (c + yy + 1 <= t) { c += yy + 1; ++yy; }  // <=16 iters
    by = yy;
    bx = t - c;
  } else {
    bz = blockIdx.y;
    bx = wgid % nbx;
    by = wgid / nbx;
  }

  __shared__ __align__(16) u16 lds[2][NMAT][4096];

  const int tid = threadIdx.x;
  const int lane = tid & 63;
  const int w = tid >> 6;  // 0..7
  const int wr = w >> 1;   // 0..3  (M quarter)
  const int wc = w & 1;    // 0..1  (N half)

  const u16* srcBase[NMAT];
  if constexpr (NP == 3) {
    srcBase[0] = Ah + (long long)bz * strA;
    srcBase[1] = Al + (long long)bz * strA;
    srcBase[2] = Bh + (long long)bz * strB;
    srcBase[3] = Bl + (long long)bz * strB;
  } else {
    srcBase[0] = Ah + (long long)bz * strA;
    srcBase[1] = Bh + (long long)bz * strB;
  }
  const long long row0[2] = {(long long)by * 128, (long long)bx * 128};

  const int rL = tid >> 2;  // 0..127 (stage row)
  const int colOff = ((tid & 3) ^ ((tid >> 3) & 3)) * 8;
  const int rdOff = (lane & 15) * 64 + ((((lane >> 4) & 3) ^ ((lane >> 1) & 3)) << 4);

  const int AR = wr * 32;
  const int BR = wc * 64;
  int nt = K / 32;
  if (TRIK) {
    const int lim = ((by + 1) * 128) / 32;
    if (lim < nt) nt = lim;
  }

  // per-thread staging pointers, one per mat (advance +32 u16/tile)
  const u16* gp[NMAT];
#pragma unroll
  for (int m = 0; m < NMAT; ++m) {
    const int opsel = (NP == 3) ? (m >> 1) : m;
    gp[m] = srcBase[m] + (row0[opsel] + rL) * (long long)K + colOff;
  }

#define STG(BUF)                                                       \
  {                                                                    \
    _Pragma("unroll") for (int m = 0; m < NMAT; ++m) {                 \
      gload16(gp[m], (char*)&lds[BUF][m][0] + tid * 16);               \
      gp[m] += 32;                                                     \
    }                                                                  \
  }
#define LDFRAG(MAT, R) \
  (*(const bf16x8*)((const char*)&lds[cur][MAT][0] + (R)*64 + rdOff))
#define BAR __builtin_amdgcn_s_barrier()

// NP3: 12 MFMA pass-major over 2m x 2n (same-acc distance 4)
#define CLUSTER3(NH)                                                         \
  __builtin_amdgcn_s_setprio(1);                                             \
  _Pragma("unroll") for (int m = 0; m < 2; ++m)                              \
      _Pragma("unroll") for (int n = 0; n < 2; ++n)                          \
          acc[m][(NH)*2 + n] =                                               \
      MFMA_BF16(aH[m], bL[n], acc[m][(NH)*2 + n], 0, 0, 0);                  \
  _Pragma("unroll") for (int m = 0; m < 2; ++m)                              \
      _Pragma("unroll") for (int n = 0; n < 2; ++n)                          \
          acc[m][(NH)*2 + n] =                                               \
      MFMA_BF16(aL[m], bH[n], acc[m][(NH)*2 + n], 0, 0, 0);                  \
  _Pragma("unroll") for (int m = 0; m < 2; ++m)                              \
      _Pragma("unroll") for (int n = 0; n < 2; ++n)                          \
          acc[m][(NH)*2 + n] =                                               \
      MFMA_BF16(aH[m], bH[n], acc[m][(NH)*2 + n], 0, 0, 0);                  \
  __builtin_amdgcn_s_setprio(0);

  f32x4 acc[2][4];
#pragma unroll
  for (int m = 0; m < 2; ++m)
#pragma unroll
    for (int n = 0; n < 4; ++n) acc[m][n] = f32x4{0.f, 0.f, 0.f, 0.f};

  bf16x8 aH[2], aL[2], bH[2], bL[2];
  bf16x8 bF[4];  // NP1 full B frags

  STG(0);  // prologue: tile 0

  for (int kt = 0; kt < nt; ++kt) {
    const int cur = kt & 1;
    const bool more = (kt + 1 < nt);

    if (more) {
      STG(cur ^ 1);
      if constexpr (NP == 3)
        asm volatile("s_waitcnt vmcnt(4)" ::: "memory");
      else
        asm volatile("s_waitcnt vmcnt(2)" ::: "memory");
    } else {
      asm volatile("s_waitcnt vmcnt(0)" ::: "memory");
    }
    BAR;  // tile-kt staged everywhere; prev-tile reads done

    if constexpr (NP == 3) {
      // P0: A frags + B n0-1
#pragma unroll
      for (int m = 0; m < 2; ++m) {
        aH[m] = LDFRAG(0, AR + m * 16);
        aL[m] = LDFRAG(1, AR + m * 16);
      }
#pragma unroll
      for (int n = 0; n < 2; ++n) {
        bH[n] = LDFRAG(2, BR + n * 16);
        bL[n] = LDFRAG(3, BR + n * 16);
      }
      BAR;
      CLUSTER3(0);
      BAR;
      // P1: B n2-3
#pragma unroll
      for (int n = 0; n < 2; ++n) {
        bH[n] = LDFRAG(2, BR + 32 + n * 16);
        bL[n] = LDFRAG(3, BR + 32 + n * 16);
      }
      BAR;
      CLUSTER3(1);
      BAR;
    } else {
      // single phase: 2 A + 4 B reads -> 8 MFMA
#pragma unroll
      for (int m = 0; m < 2; ++m) aH[m] = LDFRAG(0, AR + m * 16);
#pragma unroll
      for (int n = 0; n < 4; ++n) bF[n] = LDFRAG(1, BR + n * 16);
      BAR;
      __builtin_amdgcn_s_setprio(1);
#pragma unroll
      for (int m = 0; m < 2; ++m)
#pragma unroll
        for (int n = 0; n < 4; ++n)
          acc[m][n] = MFMA_BF16(aH[m], bF[n], acc[m][n], 0, 0, 0);
      __builtin_amdgcn_s_setprio(0);
      BAR;
    }
  }

  // epilogue: C/D map col=lane&15, row=(lane>>4)*4+reg
  const int cr = (lane >> 4) << 2;
  const int cc = lane & 15;
#pragma unroll
  for (int m = 0; m < 2; ++m)
#pragma unroll
    for (int n = 0; n < 4; ++n)
#pragma unroll
      for (int r = 0; r < 4; ++r) {
        const long long row = (long long)by * 128 + wr * 32 + m * 16 + cr + r;
        const long long col = (long long)bx * 128 + wc * 64 + n * 16 + cc;
        const float v = acc[m][n][r];
        if constexpr (EPI == 0) {
          Cf[(long long)bz * strC + row * N + col] = v;
        } else if constexpr (EPI == 1) {
          const long long idx = row * N + col;
          u16 h = f2bf(v);
          Ch[idx] = h;
          Cl[idx] = f2bf(v - bf2f(h));
        } else {
          Ch[(long long)bz * strC + row * N + col] = f2bf(v);
        }
      }
#undef STG
#undef LDFRAG
#undef BAR
#undef CLUSTER3
}

// -------- causal+pad masked row softmax (in-place, causal-trimmed) --------
__global__ __launch_bounds__(256) void k_softmax(float* __restrict__ attn,
                                                 u16* __restrict__ attn_bf,
                                                 const int* __restrict__ mask,
                                                 float inv_scale) {
  const int q = blockIdx.x;
  const int b = blockIdx.y;
  const int tid = threadIdx.x;
  float* row = attn + ((long long)b * Ss + q) * Ss;
  u16* rowb = attn_bf + ((long long)b * Ss + q) * Ss;
  const int* mrow = mask + b * Ss;
  const int qup = ((q >> 7) + 1) << 7;  // PV's TRIK reads bf16 cols < qup

  float x[8];
  float m = -3.0e38f;
#pragma unroll
  for (int j = 0; j < 8; ++j) {
    const int k = tid + j * 256;
    float v = -3.0e38f;
    if (k <= q) {
      const float e = row[k];
      v = ((mrow[k] != 0) ? e : -1e20f) * inv_scale;
    }
    x[j] = v;
    m = fmaxf(m, v);
  }
#pragma unroll
  for (int o = 32; o > 0; o >>= 1) m = fmaxf(m, __shfl_xor(m, o));
  __shared__ float redm[4], reds[4];
  const int w = tid >> 6;
  if ((tid & 63) == 0) redm[w] = m;
  __syncthreads();
  m = fmaxf(fmaxf(redm[0], redm[1]), fmaxf(redm[2], redm[3]));
  float s = 0.f;
#pragma unroll
  for (int j = 0; j < 8; ++j) {
    x[j] = __expf(x[j] - m);
    s += x[j];
  }
#pragma unroll
  for (int o = 32; o > 0; o >>= 1) s += __shfl_xor(s, o);
  if ((tid & 63) == 0) reds[w] = s;
  __syncthreads();
  s = reds[0] + reds[1] + reds[2] + reds[3];
  const float inv = 1.0f / s;
#pragma unroll
  for (int j = 0; j < 8; ++j) {
    const int k = tid + j * 256;
    if (k <= q) {
      const float a = x[j] * inv;
      row[k] = a;
      rowb[k] = f2bf(a);
    } else {
      row[k] = 0.0f;          // exact: reference gives exp(-inf)=0 here
      if (k < qup) rowb[k] = 0;
    }
  }
}

extern "C" void kernel_launch(void* const* d_in, const int* in_sizes, int n_in,
                              void* d_out, int out_size, void* d_ws, size_t ws_size,
                              hipStream_t stream) {
  const float* emb = (const float*)d_in[0];
  const int* mask = (const int*)d_in[1];
  const float* Wq = (const float*)d_in[2];
  const float* Wk = (const float*)d_in[3];
  const float* Wv = (const float*)d_in[4];

  float* out = (float*)d_out;                   // [8,2048,1024] fp32
  float* attn = out + (long long)Bb * Ss * Dd;  // [8,2048,2048] fp32

  // workspace carve (~206 MB)
  char* p = (char*)d_ws;
  u16* emb_hi = (u16*)p;                    // alive through energy
  u16* emb_lo = emb_hi + 16777216LL;
  u16* R_hi = (u16*)(p + 67108864LL);       // R = emb @ (Wq Wk^T)
  u16* R_lo = R_hi + 16777216LL;
  u16* v_t = R_lo + 16777216LL;             // [b][D][S] bf16
  u16* attn_bf = v_t + 16777216LL;          // own buffer (no alias)
  u16* Wqr_hi = attn_bf + 16777216LL;       // raw Wq split [E,D]
  u16* Wqr_lo = Wqr_hi + 1048576LL;
  u16* Wkr_hi = Wqr_lo + 1048576LL;         // raw Wk split [E,D]
  u16* Wkr_lo = Wkr_hi + 1048576LL;
  u16* M_hi = Wkr_lo + 1048576LL;           // M'' = Wk Wq^T  [e][d]
  u16* M_lo = M_hi + 1048576LL;
  u16* WvT_hi = M_lo + 1048576LL;           // Wv^T [D,E]

  const float inv_scale = 1.0f / (32.0f + 1.1920929e-07f);

  k_split4<<<16384, 256, 0, stream>>>(emb, emb_hi, emb_lo, 4194304LL);
  k_split4<<<1024, 256, 0, stream>>>(Wq, Wqr_hi, Wqr_lo, 262144LL);
  k_split4<<<1024, 256, 0, stream>>>(Wk, Wkr_hi, Wkr_lo, 262144LL);
  k_wt_split<<<dim3(32, 32), 256, 0, stream>>>(Wv, WvT_hi, nullptr);

  // M'' = Wk @ Wq^T  (split 3-pass, split-bf16 out)
  k_t128<3, 1, false, false><<<64, 512, 0, stream>>>(
      Wkr_hi, Wkr_lo, Wqr_hi, Wqr_lo, nullptr, M_hi, M_lo,
      8, 1024, 1024, 0, 0, 0);
  // R = emb @ M''^T (BT form): M=16384, N=1024, K=1024 -> 1024 blocks
  k_t128<3, 1, false, false><<<1024, 512, 0, stream>>>(
      emb_hi, emb_lo, M_hi, M_lo, nullptr, R_hi, R_lo,
      8, 1024, 1024, 0, 0, 0);
  // v^T per batch: [D,S] = Wv^T[D,E] x emb_b (BT), 1-pass bf16
  k_t128<1, 2, false, false><<<dim3(128, 8), 512, 0, stream>>>(
      WvT_hi, nullptr, emb_hi, nullptr, nullptr, v_t, nullptr,
      16, Ss, Ee, 0, (long long)Ss * Ee, (long long)Dd * Ss);
  // energy per batch: [S,S] = R_b emb_b^T  (== q k^T by associativity)
  k_t128<3, 0, true, false><<<1088, 512, 0, stream>>>(
      R_hi, R_lo, emb_hi, emb_lo, attn, nullptr, nullptr,
      0, Ss, Dd, (long long)Ss * Dd, (long long)Ss * Dd, (long long)Ss * Ss);
  // softmax rows in-place + bf16 copy (causal-trimmed)
  k_softmax<<<dim3(Ss, Bb), 256, 0, stream>>>(attn, attn_bf, mask, inv_scale);
  // out per batch: [S,D] = attn_bf @ v_t^T (BT), K truncated causally
  k_t128<1, 0, false, true><<<dim3(128, 8), 512, 0, stream>>>(
      attn_bf, nullptr, v_t, nullptr, out, nullptr, nullptr,
      8, Dd, Ss, (long long)Ss * Ss, (long long)Dd * Ss, (long long)Ss * Dd);
}

// Round 9
// 468.714 us; speedup vs baseline: 1.1835x; 1.0019x over previous
//
#include <hip/hip_runtime.h>

#define Bb 8
#define Ss 2048
#define Ee 1024
#define Dd 1024

typedef __attribute__((ext_vector_type(8))) __bf16 bf16x8;
typedef __attribute__((ext_vector_type(4))) float f32x4;
typedef unsigned short u16;

__device__ __forceinline__ u16 f2bf(float x) {
  unsigned u = __float_as_uint(x);
  return (u16)((u + 0x7fffu + ((u >> 16) & 1u)) >> 16);
}
__device__ __forceinline__ float bf2f(u16 h) {
  return __uint_as_float(((unsigned)h) << 16);
}

__device__ __forceinline__ void gload16(const void* g, void* l) {
  __builtin_amdgcn_global_load_lds(
      (__attribute__((address_space(1))) void*)const_cast<void*>(g),
      (__attribute__((address_space(3))) void*)l, 16, 0, 0);
}

#define MFMA_BF16 __builtin_amdgcn_mfma_f32_16x16x32_bf16

// ---------------- fp32 -> bf16 hi/lo split (vectorized x4) ----------------
__global__ __launch_bounds__(256) void k_split4(const float* __restrict__ in,
                                                u16* __restrict__ hi,
                                                u16* __restrict__ lo,
                                                long long n4) {
  long long i = (long long)blockIdx.x * 256 + threadIdx.x;
  if (i >= n4) return;
  float4 v = ((const float4*)in)[i];
  float xs[4] = {v.x, v.y, v.z, v.w};
  u16 hh[4], ll[4];
#pragma unroll
  for (int j = 0; j < 4; ++j) {
    hh[j] = f2bf(xs[j]);
    ll[j] = f2bf(xs[j] - bf2f(hh[j]));
  }
  ushort4 h, l;
  h.x = hh[0]; h.y = hh[1]; h.z = hh[2]; h.w = hh[3];
  l.x = ll[0]; l.y = ll[1]; l.z = ll[2]; l.w = ll[3];
  ((ushort4*)hi)[i] = h;
  ((ushort4*)lo)[i] = l;
}

// ---------------- W [E,D] fp32 -> W^T [D,E] bf16 hi(/lo) ----------------
__global__ __launch_bounds__(256) void k_wt_split(const float* __restrict__ W,
                                                  u16* __restrict__ hi,
                                                  u16* __restrict__ lo) {
  __shared__ float t[32][33];
  const int tx = threadIdx.x & 31;
  const int ty = threadIdx.x >> 5;  // 0..7
  const int e0 = blockIdx.y * 32, d0 = blockIdx.x * 32;
#pragma unroll
  for (int r = ty; r < 32; r += 8)
    t[r][tx] = W[(long long)(e0 + r) * Dd + d0 + tx];
  __syncthreads();
#pragma unroll
  for (int r = ty; r < 32; r += 8) {
    float x = t[tx][r];  // = W[e0+tx][d0+r]
    long long o = (long long)(d0 + r) * Ee + e0 + tx;
    u16 h = f2bf(x);
    hi[o] = h;
    if (lo) lo[o] = f2bf(x - bf2f(h));
  }
}

// ====== 256x128 BT GEMM, 8 waves (4M x 2N), per-wave 64x64, FREE-RUN ======
// Model (r8 counters): {reads;BAR;MFMA;BAR} serializes LDS + MFMA (sum=4240
// cy/tile measured).  Fix: 2 barriers/tile only (gate after counted vmcnt,
// end-of-tile); reads+MFMA free-run so de-synced waves overlap LDS and MFMA.
// 64x64 wave tile: 16 ds_read_b128 -> 48 MFMA (NP3) = LDS 1536 < MFMA 1862
// cy/CU-tile -> MFMA-bound.
// NP=3: split C=(Ah+Al)(Bh+Bl)^T drop AlBl; LDS 96 KiB, 1 blk/CU.
// NP=1: plain bf16; LDS 48 KiB, 2 blk/CU, VGPR<=128 (bounds 512,4).
// EPI: 0 fp32 (+strC), 1 split hi/lo bf16, 2 bf16 (+strC).
// CAUSAL: grid 8 x 72 (by 0..7, bx<=2by+1).  TRIK: nt<=(by+1)*8.
template <int NP, int EPI, bool CAUSAL, bool TRIK>
__global__ __launch_bounds__(512, (NP == 3) ? 2 : 4) void k_t256(
    const u16* __restrict__ Ah, const u16* __restrict__ Al,
    const u16* __restrict__ Bh, const u16* __restrict__ Bl,
    float* __restrict__ Cf, u16* __restrict__ Ch, u16* __restrict__ Cl,
    int nbx, int N, int K, long long strA, long long strB, long long strC) {
  constexpr int NLD = (NP == 3) ? 6 : 3;
  constexpr int LDSB = (NP == 3) ? 49152 : 24576;  // bytes per buffer
  constexpr int OFF_AL = 16384;
  constexpr int OFF_BH = (NP == 3) ? 32768 : 16384;
  constexpr int OFF_BL = 40960;
  __shared__ __align__(16) char lds[2][LDSB];

  const int nwg = gridDim.x;
  const int f = blockIdx.x;
  const int wgid = (f & 7) * (nwg >> 3) + (f >> 3);  // XCD chunk swizzle
  int bx, by, bz;
  if (CAUSAL) {
    bz = wgid / 72;
    const int t = wgid % 72;
    int yy = 0, c = 0;
    while (c + 2 * yy + 2 <= t) { c += 2 * yy + 2; ++yy; }
    by = yy;
    bx = t - c;
  } else {
    bz = blockIdx.y;
    bx = wgid % nbx;
    by = wgid / nbx;
  }

  const int tid = threadIdx.x;
  const int lane = tid & 63;
  const int w = tid >> 6;  // 0..7
  const int wr = w >> 1;   // 0..3  (M quarter of 256)
  const int wc = w & 1;    // 0..1  (N half of 128)
  const int AR = wr * 64;
  const int BR = wc * 64;

  const int rL = tid >> 2;  // 0..127 (stage row)
  const int colOff = ((tid & 3) ^ ((tid >> 3) & 3)) * 8;
  const int rdOff = (lane & 15) * 64 + ((((lane >> 4) & 3) ^ ((lane >> 1) & 3)) << 4);

  const long long rowA0 = (long long)by * 256;
  const long long rowB0 = (long long)bx * 128;

  int nt = K / 32;
  if (TRIK) {
    const int lim = (by + 1) * 8;
    if (lim < nt) nt = lim;
  }

  const u16* gp[NLD];
  int dst[NLD];
  if constexpr (NP == 3) {
    const u16* pAh = Ah + (long long)bz * strA;
    const u16* pAl = Al + (long long)bz * strA;
    const u16* pBh = Bh + (long long)bz * strB;
    const u16* pBl = Bl + (long long)bz * strB;
    gp[0] = pAh + (rowA0 + rL) * (long long)K + colOff;       dst[0] = tid * 16;
    gp[1] = pAh + (rowA0 + 128 + rL) * (long long)K + colOff; dst[1] = 8192 + tid * 16;
    gp[2] = pAl + (rowA0 + rL) * (long long)K + colOff;       dst[2] = OFF_AL + tid * 16;
    gp[3] = pAl + (rowA0 + 128 + rL) * (long long)K + colOff; dst[3] = OFF_AL + 8192 + tid * 16;
    gp[4] = pBh + (rowB0 + rL) * (long long)K + colOff;       dst[4] = OFF_BH + tid * 16;
    gp[5] = pBl + (rowB0 + rL) * (long long)K + colOff;       dst[5] = OFF_BL + tid * 16;
  } else {
    const u16* pA = Ah + (long long)bz * strA;
    const u16* pB = Bh + (long long)bz * strB;
    gp[0] = pA + (rowA0 + rL) * (long long)K + colOff;        dst[0] = tid * 16;
    gp[1] = pA + (rowA0 + 128 + rL) * (long long)K + colOff;  dst[1] = 8192 + tid * 16;
    gp[2] = pB + (rowB0 + rL) * (long long)K + colOff;        dst[2] = OFF_BH + tid * 16;
  }

#define STG(BUF)                                               \
  {                                                            \
    _Pragma("unroll") for (int u = 0; u < NLD; ++u) {          \
      gload16(gp[u], lds[BUF] + dst[u]);                       \
      gp[u] += 32;                                             \
    }                                                          \
  }
#define BAR __builtin_amdgcn_s_barrier()

  f32x4 acc[4][4];
#pragma unroll
  for (int m = 0; m < 4; ++m)
#pragma unroll
    for (int n = 0; n < 4; ++n) acc[m][n] = f32x4{0.f, 0.f, 0.f, 0.f};

  STG(0);  // prologue: tile 0

  for (int kt = 0; kt < nt; ++kt) {
    const int cur = kt & 1;
    const bool more = (kt + 1 < nt);

    // ---- gate: issue next tile, counted wait for current, sync ----
    if (more) {
      STG(cur ^ 1);
      if constexpr (NP == 3)
        asm volatile("s_waitcnt vmcnt(6)" ::: "memory");
      else
        asm volatile("s_waitcnt vmcnt(3)" ::: "memory");
    } else {
      asm volatile("s_waitcnt vmcnt(0)" ::: "memory");
    }
    BAR;

    // ---- free-run: reads + MFMA (compiler inserts fine lgkmcnt) ----
    const char* bb = lds[cur];
    if constexpr (NP == 3) {
      bf16x8 aH[4], aL[4], bH[4], bL[4];
#pragma unroll
      for (int m = 0; m < 4; ++m) {
        aH[m] = *(const bf16x8*)(bb + (AR + m * 16) * 64 + rdOff);
        aL[m] = *(const bf16x8*)(bb + OFF_AL + (AR + m * 16) * 64 + rdOff);
      }
#pragma unroll
      for (int n = 0; n < 4; ++n) {
        bH[n] = *(const bf16x8*)(bb + OFF_BH + (BR + n * 16) * 64 + rdOff);
        bL[n] = *(const bf16x8*)(bb + OFF_BL + (BR + n * 16) * 64 + rdOff);
      }
#pragma unroll
      for (int m = 0; m < 4; ++m)
#pragma unroll
        for (int n = 0; n < 4; ++n)
          acc[m][n] = MFMA_BF16(aH[m], bL[n], acc[m][n], 0, 0, 0);
#pragma unroll
      for (int m = 0; m < 4; ++m)
#pragma unroll
        for (int n = 0; n < 4; ++n)
          acc[m][n] = MFMA_BF16(aL[m], bH[n], acc[m][n], 0, 0, 0);
#pragma unroll
      for (int m = 0; m < 4; ++m)
#pragma unroll
        for (int n = 0; n < 4; ++n)
          acc[m][n] = MFMA_BF16(aH[m], bH[n], acc[m][n], 0, 0, 0);
    } else {
      bf16x8 a[4], b[4];
#pragma unroll
      for (int m = 0; m < 4; ++m)
        a[m] = *(const bf16x8*)(bb + (AR + m * 16) * 64 + rdOff);
#pragma unroll
      for (int n = 0; n < 4; ++n)
        b[n] = *(const bf16x8*)(bb + OFF_BH + (BR + n * 16) * 64 + rdOff);
#pragma unroll
      for (int m = 0; m < 4; ++m)
#pragma unroll
        for (int n = 0; n < 4; ++n)
          acc[m][n] = MFMA_BF16(a[m], b[n], acc[m][n], 0, 0, 0);
    }
    BAR;  // all reads of buf cur consumed before next gate's staging
  }

  // epilogue: C/D map col=lane&15, row=(lane>>4)*4+reg
  const int cr = (lane >> 4) << 2;
  const int cc = lane & 15;
#pragma unroll
  for (int m = 0; m < 4; ++m)
#pragma unroll
    for (int n = 0; n < 4; ++n)
#pragma unroll
      for (int r = 0; r < 4; ++r) {
        const long long row = (long long)by * 256 + AR + m * 16 + cr + r;
        const long long col = (long long)bx * 128 + BR + n * 16 + cc;
        const float v = acc[m][n][r];
        if constexpr (EPI == 0) {
          Cf[(long long)bz * strC + row * N + col] = v;
        } else if constexpr (EPI == 1) {
          const long long idx = row * N + col;
          u16 h = f2bf(v);
          Ch[idx] = h;
          Cl[idx] = f2bf(v - bf2f(h));
        } else {
          Ch[(long long)bz * strC + row * N + col] = f2bf(v);
        }
      }
#undef STG
#undef BAR
}

// -------- causal+pad masked row softmax (in-place, causal-trimmed) --------
__global__ __launch_bounds__(256) void k_softmax(float* __restrict__ attn,
                                                 u16* __restrict__ attn_bf,
                                                 const int* __restrict__ mask,
                                                 float inv_scale) {
  const int q = blockIdx.x;
  const int b = blockIdx.y;
  const int tid = threadIdx.x;
  float* row = attn + ((long long)b * Ss + q) * Ss;
  u16* rowb = attn_bf + ((long long)b * Ss + q) * Ss;
  const int* mrow = mask + b * Ss;
  const int qup = ((q >> 8) + 1) << 8;  // PV TRIK reads bf16 cols < 256-block

  float x[8];
  float m = -3.0e38f;
#pragma unroll
  for (int j = 0; j < 8; ++j) {
    const int k = tid + j * 256;
    float v = -3.0e38f;
    if (k <= q) {
      const float e = row[k];
      v = ((mrow[k] != 0) ? e : -1e20f) * inv_scale;
    }
    x[j] = v;
    m = fmaxf(m, v);
  }
#pragma unroll
  for (int o = 32; o > 0; o >>= 1) m = fmaxf(m, __shfl_xor(m, o));
  __shared__ float redm[4], reds[4];
  const int w = tid >> 6;
  if ((tid & 63) == 0) redm[w] = m;
  __syncthreads();
  m = fmaxf(fmaxf(redm[0], redm[1]), fmaxf(redm[2], redm[3]));
  float s = 0.f;
#pragma unroll
  for (int j = 0; j < 8; ++j) {
    x[j] = __expf(x[j] - m);
    s += x[j];
  }
#pragma unroll
  for (int o = 32; o > 0; o >>= 1) s += __shfl_xor(s, o);
  if ((tid & 63) == 0) reds[w] = s;
  __syncthreads();
  s = reds[0] + reds[1] + reds[2] + reds[3];
  const float inv = 1.0f / s;
#pragma unroll
  for (int j = 0; j < 8; ++j) {
    const int k = tid + j * 256;
    if (k <= q) {
      const float a = x[j] * inv;
      row[k] = a;
      rowb[k] = f2bf(a);
    } else {
      row[k] = 0.0f;          // exact: reference gives exp(-inf)=0 here
      if (k < qup) rowb[k] = 0;
    }
  }
}

extern "C" void kernel_launch(void* const* d_in, const int* in_sizes, int n_in,
                              void* d_out, int out_size, void* d_ws, size_t ws_size,
                              hipStream_t stream) {
  const float* emb = (const float*)d_in[0];
  const int* mask = (const int*)d_in[1];
  const float* Wq = (const float*)d_in[2];
  const float* Wk = (const float*)d_in[3];
  const float* Wv = (const float*)d_in[4];

  float* out = (float*)d_out;                   // [8,2048,1024] fp32
  float* attn = out + (long long)Bb * Ss * Dd;  // [8,2048,2048] fp32

  // workspace carve (~206 MB)
  char* p = (char*)d_ws;
  u16* emb_hi = (u16*)p;                    // alive through energy
  u16* emb_lo = emb_hi + 16777216LL;
  u16* R_hi = (u16*)(p + 67108864LL);       // R = emb @ (Wq Wk^T)
  u16* R_lo = R_hi + 16777216LL;
  u16* v_t = R_lo + 16777216LL;             // [b][D][S] bf16
  u16* attn_bf = v_t + 16777216LL;          // own buffer (no alias)
  u16* Wqr_hi = attn_bf + 16777216LL;       // raw Wq split [E,D]
  u16* Wqr_lo = Wqr_hi + 1048576LL;
  u16* Wkr_hi = Wqr_lo + 1048576LL;         // raw Wk split [E,D]
  u16* Wkr_lo = Wkr_hi + 1048576LL;
  u16* M_hi = Wkr_lo + 1048576LL;           // M'' = Wk Wq^T  [e][d]
  u16* M_lo = M_hi + 1048576LL;
  u16* WvT_hi = M_lo + 1048576LL;           // Wv^T [D,E]

  const float inv_scale = 1.0f / (32.0f + 1.1920929e-07f);

  k_split4<<<16384, 256, 0, stream>>>(emb, emb_hi, emb_lo, 4194304LL);
  k_split4<<<1024, 256, 0, stream>>>(Wq, Wqr_hi, Wqr_lo, 262144LL);
  k_split4<<<1024, 256, 0, stream>>>(Wk, Wkr_hi, Wkr_lo, 262144LL);
  k_wt_split<<<dim3(32, 32), 256, 0, stream>>>(Wv, WvT_hi, nullptr);

  // M'' = Wk @ Wq^T  (split 3-pass, split-bf16 out): 4x8 tiles = 32 blocks
  k_t256<3, 1, false, false><<<32, 512, 0, stream>>>(
      Wkr_hi, Wkr_lo, Wqr_hi, Wqr_lo, nullptr, M_hi, M_lo,
      8, 1024, 1024, 0, 0, 0);
  // R = emb @ M''^T: 64x8 tiles = 512 blocks (2 clean rounds)
  k_t256<3, 1, false, false><<<512, 512, 0, stream>>>(
      emb_hi, emb_lo, M_hi, M_lo, nullptr, R_hi, R_lo,
      8, 1024, 1024, 0, 0, 0);
  // v^T per batch: [D,S] = Wv^T x emb_b (BT), 1-pass bf16: 4x16 = 64 /batch
  k_t256<1, 2, false, false><<<dim3(64, 8), 512, 0, stream>>>(
      WvT_hi, nullptr, emb_hi, nullptr, nullptr, v_t, nullptr,
      16, Ss, Ee, 0, (long long)Ss * Ee, (long long)Dd * Ss);
  // energy per batch: [S,S] = R_b emb_b^T, causal 72 tiles/batch = 576
  k_t256<3, 0, true, false><<<576, 512, 0, stream>>>(
      R_hi, R_lo, emb_hi, emb_lo, attn, nullptr, nullptr,
      0, Ss, Dd, (long long)Ss * Dd, (long long)Ss * Ee, (long long)Ss * Ss);
  // softmax rows in-place + bf16 copy (causal-trimmed)
  k_softmax<<<dim3(Ss, Bb), 256, 0, stream>>>(attn, attn_bf, mask, inv_scale);
  // out per batch: [S,D] = attn_bf @ v_t^T (BT), K trunc at (by+1)*256
  k_t256<1, 0, false, true><<<dim3(64, 8), 512, 0, stream>>>(
      attn_bf, nullptr, v_t, nullptr, out, nullptr, nullptr,
      8, Dd, Ss, (long long)Ss * Ss, (long long)Dd * Ss, (long long)Ss * Dd);
}

// Round 10
// 449.599 us; speedup vs baseline: 1.2338x; 1.0425x over previous
//
#include <hip/hip_runtime.h>

#define Bb 8
#define Ss 2048
#define Ee 1024
#define Dd 1024

typedef __attribute__((ext_vector_type(8))) __bf16 bf16x8;
typedef __attribute__((ext_vector_type(4))) float f32x4;
typedef unsigned short u16;

__device__ __forceinline__ u16 f2bf(float x) {
  unsigned u = __float_as_uint(x);
  return (u16)((u + 0x7fffu + ((u >> 16) & 1u)) >> 16);
}
__device__ __forceinline__ float bf2f(u16 h) {
  return __uint_as_float(((unsigned)h) << 16);
}

__device__ __forceinline__ void gload16(const void* g, void* l) {
  __builtin_amdgcn_global_load_lds(
      (__attribute__((address_space(1))) void*)const_cast<void*>(g),
      (__attribute__((address_space(3))) void*)l, 16, 0, 0);
}

#define MFMA_BF16 __builtin_amdgcn_mfma_f32_16x16x32_bf16

// ---------------- fp32 -> bf16 hi/lo split (vectorized x4) ----------------
__global__ __launch_bounds__(256) void k_split4(const float* __restrict__ in,
                                                u16* __restrict__ hi,
                                                u16* __restrict__ lo,
                                                long long n4) {
  long long i = (long long)blockIdx.x * 256 + threadIdx.x;
  if (i >= n4) return;
  float4 v = ((const float4*)in)[i];
  float xs[4] = {v.x, v.y, v.z, v.w};
  u16 hh[4], ll[4];
#pragma unroll
  for (int j = 0; j < 4; ++j) {
    hh[j] = f2bf(xs[j]);
    ll[j] = f2bf(xs[j] - bf2f(hh[j]));
  }
  ushort4 h, l;
  h.x = hh[0]; h.y = hh[1]; h.z = hh[2]; h.w = hh[3];
  l.x = ll[0]; l.y = ll[1]; l.z = ll[2]; l.w = ll[3];
  ((ushort4*)hi)[i] = h;
  ((ushort4*)lo)[i] = l;
}

// ---------------- W [E,D] fp32 -> W^T [D,E] bf16 hi(/lo) ----------------
__global__ __launch_bounds__(256) void k_wt_split(const float* __restrict__ W,
                                                  u16* __restrict__ hi,
                                                  u16* __restrict__ lo) {
  __shared__ float t[32][33];
  const int tx = threadIdx.x & 31;
  const int ty = threadIdx.x >> 5;  // 0..7
  const int e0 = blockIdx.y * 32, d0 = blockIdx.x * 32;
#pragma unroll
  for (int r = ty; r < 32; r += 8)
    t[r][tx] = W[(long long)(e0 + r) * Dd + d0 + tx];
  __syncthreads();
#pragma unroll
  for (int r = ty; r < 32; r += 8) {
    float x = t[tx][r];  // = W[e0+tx][d0+r]
    long long o = (long long)(d0 + r) * Ee + e0 + tx;
    u16 h = f2bf(x);
    hi[o] = h;
    if (lo) lo[o] = f2bf(x - bf2f(h));
  }
}

// ====== r8-proven 128x128 BT GEMM, 8 waves (4M x 2N), per-wave 32x64 ======
// NP=3: split-precision; 4 LDS mats, 64 KiB dbuf, vmcnt(4), 2 read-phases.
template <int NP, int EPI, bool CAUSAL, bool TRIK>
__global__ __launch_bounds__(512, 4) void k_t128(
    const u16* __restrict__ Ah, const u16* __restrict__ Al,
    const u16* __restrict__ Bh, const u16* __restrict__ Bl,
    float* __restrict__ Cf, u16* __restrict__ Ch, u16* __restrict__ Cl,
    int nbx, int N, int K, long long strA, long long strB, long long strC) {
  constexpr int NMAT = (NP == 3) ? 4 : 2;
  const int nwg = gridDim.x;
  const int f = blockIdx.x;
  const int wgid = (f & 7) * (nwg >> 3) + (f >> 3);  // XCD chunk swizzle
  int bx, by, bz;
  if (CAUSAL) {
    bz = wgid / 136;
    const int t = wgid % 136;
    int yy = 0, c = 0;
    while (c + yy + 1 <= t) { c += yy + 1; ++yy; }  // <=16 iters
    by = yy;
    bx = t - c;
  } else {
    bz = blockIdx.y;
    bx = wgid % nbx;
    by = wgid / nbx;
  }

  __shared__ __align__(16) u16 lds[2][NMAT][4096];

  const int tid = threadIdx.x;
  const int lane = tid & 63;
  const int w = tid >> 6;  // 0..7
  const int wr = w >> 1;   // 0..3  (M quarter)
  const int wc = w & 1;    // 0..1  (N half)

  const u16* srcBase[NMAT];
  if constexpr (NP == 3) {
    srcBase[0] = Ah + (long long)bz * strA;
    srcBase[1] = Al + (long long)bz * strA;
    srcBase[2] = Bh + (long long)bz * strB;
    srcBase[3] = Bl + (long long)bz * strB;
  } else {
    srcBase[0] = Ah + (long long)bz * strA;
    srcBase[1] = Bh + (long long)bz * strB;
  }
  const long long row0[2] = {(long long)by * 128, (long long)bx * 128};

  const int rL = tid >> 2;
  const int colOff = ((tid & 3) ^ ((tid >> 3) & 3)) * 8;
  const int rdOff = (lane & 15) * 64 + ((((lane >> 4) & 3) ^ ((lane >> 1) & 3)) << 4);

  const int AR = wr * 32;
  const int BR = wc * 64;
  int nt = K / 32;
  if (TRIK) {
    const int lim = ((by + 1) * 128) / 32;
    if (lim < nt) nt = lim;
  }

  const u16* gp[NMAT];
#pragma unroll
  for (int m = 0; m < NMAT; ++m) {
    const int opsel = (NP == 3) ? (m >> 1) : m;
    gp[m] = srcBase[m] + (row0[opsel] + rL) * (long long)K + colOff;
  }

#define STG(BUF)                                                       \
  {                                                                    \
    _Pragma("unroll") for (int m = 0; m < NMAT; ++m) {                 \
      gload16(gp[m], (char*)&lds[BUF][m][0] + tid * 16);               \
      gp[m] += 32;                                                     \
    }                                                                  \
  }
#define LDFRAG(MAT, R) \
  (*(const bf16x8*)((const char*)&lds[cur][MAT][0] + (R)*64 + rdOff))
#define BAR __builtin_amdgcn_s_barrier()

#define CLUSTER3(NH)                                                         \
  __builtin_amdgcn_s_setprio(1);                                             \
  _Pragma("unroll") for (int m = 0; m < 2; ++m)                              \
      _Pragma("unroll") for (int n = 0; n < 2; ++n)                          \
          acc[m][(NH)*2 + n] =                                               \
      MFMA_BF16(aH[m], bL[n], acc[m][(NH)*2 + n], 0, 0, 0);                  \
  _Pragma("unroll") for (int m = 0; m < 2; ++m)                              \
      _Pragma("unroll") for (int n = 0; n < 2; ++n)                          \
          acc[m][(NH)*2 + n] =                                               \
      MFMA_BF16(aL[m], bH[n], acc[m][(NH)*2 + n], 0, 0, 0);                  \
  _Pragma("unroll") for (int m = 0; m < 2; ++m)                              \
      _Pragma("unroll") for (int n = 0; n < 2; ++n)                          \
          acc[m][(NH)*2 + n] =                                               \
      MFMA_BF16(aH[m], bH[n], acc[m][(NH)*2 + n], 0, 0, 0);                  \
  __builtin_amdgcn_s_setprio(0);

  f32x4 acc[2][4];
#pragma unroll
  for (int m = 0; m < 2; ++m)
#pragma unroll
    for (int n = 0; n < 4; ++n) acc[m][n] = f32x4{0.f, 0.f, 0.f, 0.f};

  bf16x8 aH[2], aL[2], bH[2], bL[2];
  bf16x8 bF[4];

  STG(0);

  for (int kt = 0; kt < nt; ++kt) {
    const int cur = kt & 1;
    const bool more = (kt + 1 < nt);

    if (more) {
      STG(cur ^ 1);
      if constexpr (NP == 3)
        asm volatile("s_waitcnt vmcnt(4)" ::: "memory");
      else
        asm volatile("s_waitcnt vmcnt(2)" ::: "memory");
    } else {
      asm volatile("s_waitcnt vmcnt(0)" ::: "memory");
    }
    BAR;

    if constexpr (NP == 3) {
#pragma unroll
      for (int m = 0; m < 2; ++m) {
        aH[m] = LDFRAG(0, AR + m * 16);
        aL[m] = LDFRAG(1, AR + m * 16);
      }
#pragma unroll
      for (int n = 0; n < 2; ++n) {
        bH[n] = LDFRAG(2, BR + n * 16);
        bL[n] = LDFRAG(3, BR + n * 16);
      }
      BAR;
      CLUSTER3(0);
      BAR;
#pragma unroll
      for (int n = 0; n < 2; ++n) {
        bH[n] = LDFRAG(2, BR + 32 + n * 16);
        bL[n] = LDFRAG(3, BR + 32 + n * 16);
      }
      BAR;
      CLUSTER3(1);
      BAR;
    } else {
#pragma unroll
      for (int m = 0; m < 2; ++m) aH[m] = LDFRAG(0, AR + m * 16);
#pragma unroll
      for (int n = 0; n < 4; ++n) bF[n] = LDFRAG(1, BR + n * 16);
      BAR;
      __builtin_amdgcn_s_setprio(1);
#pragma unroll
      for (int m = 0; m < 2; ++m)
#pragma unroll
        for (int n = 0; n < 4; ++n)
          acc[m][n] = MFMA_BF16(aH[m], bF[n], acc[m][n], 0, 0, 0);
      __builtin_amdgcn_s_setprio(0);
      BAR;
    }
  }

  const int cr = (lane >> 4) << 2;
  const int cc = lane & 15;
#pragma unroll
  for (int m = 0; m < 2; ++m)
#pragma unroll
    for (int n = 0; n < 4; ++n)
#pragma unroll
      for (int r = 0; r < 4; ++r) {
        const long long row = (long long)by * 128 + wr * 32 + m * 16 + cr + r;
        const long long col = (long long)bx * 128 + wc * 64 + n * 16 + cc;
        const float v = acc[m][n][r];
        if constexpr (EPI == 0) {
          Cf[(long long)bz * strC + row * N + col] = v;
        } else if constexpr (EPI == 1) {
          const long long idx = row * N + col;
          u16 h = f2bf(v);
          Ch[idx] = h;
          Cl[idx] = f2bf(v - bf2f(h));
        } else {
          Ch[(long long)bz * strC + row * N + col] = f2bf(v);
        }
      }
#undef STG
#undef LDFRAG
#undef BAR
#undef CLUSTER3
}

// == EXPERIMENT: single-buffer NP3 256x128, 48 KiB LDS -> 2 blk/CU TLP ====
// Staging of one block overlaps compute of the co-resident block (block-
// level TLP replaces double-buffering).  8 waves (4M x 2N), per-wave 64x64.
// Product-major B frags keep live regs ~120 (acc 64 + aH/aL 32 + bHbL 8).
// Sync: STG; vmcnt(0); BAR; reads+MFMA; BAR  (conservative, correct).
template <int EPI>
__global__ __launch_bounds__(512, 4) void k_s256(
    const u16* __restrict__ Ah, const u16* __restrict__ Al,
    const u16* __restrict__ Bh, const u16* __restrict__ Bl,
    float* __restrict__ Cf, u16* __restrict__ Ch, u16* __restrict__ Cl,
    int nbx, int N, int K) {
  constexpr int OFF_AL = 16384;
  constexpr int OFF_BH = 32768;
  constexpr int OFF_BL = 40960;
  __shared__ __align__(16) char lds[49152];

  const int nwg = gridDim.x;
  const int f = blockIdx.x;
  const int wgid = (f & 7) * (nwg >> 3) + (f >> 3);
  const int bx = wgid % nbx;
  const int by = wgid / nbx;

  const int tid = threadIdx.x;
  const int lane = tid & 63;
  const int w = tid >> 6;  // 0..7
  const int wr = w >> 1;   // 0..3 (64-row quarter of 256)
  const int wc = w & 1;    // 0..1 (64-col half of 128)
  const int AR = wr * 64;
  const int BR = wc * 64;

  const int rL = tid >> 2;  // 0..127
  const int colOff = ((tid & 3) ^ ((tid >> 3) & 3)) * 8;
  const int rdOff = (lane & 15) * 64 + ((((lane >> 4) & 3) ^ ((lane >> 1) & 3)) << 4);

  const long long rowA0 = (long long)by * 256;
  const long long rowB0 = (long long)bx * 128;
  const int nt = K / 32;

  const u16* gp[6];
  int dst[6];
  gp[0] = Ah + (rowA0 + rL) * (long long)K + colOff;        dst[0] = tid * 16;
  gp[1] = Ah + (rowA0 + 128 + rL) * (long long)K + colOff;  dst[1] = 8192 + tid * 16;
  gp[2] = Al + (rowA0 + rL) * (long long)K + colOff;        dst[2] = OFF_AL + tid * 16;
  gp[3] = Al + (rowA0 + 128 + rL) * (long long)K + colOff;  dst[3] = OFF_AL + 8192 + tid * 16;
  gp[4] = Bh + (rowB0 + rL) * (long long)K + colOff;        dst[4] = OFF_BH + tid * 16;
  gp[5] = Bl + (rowB0 + rL) * (long long)K + colOff;        dst[5] = OFF_BL + tid * 16;

  f32x4 acc[4][4];
#pragma unroll
  for (int m = 0; m < 4; ++m)
#pragma unroll
    for (int n = 0; n < 4; ++n) acc[m][n] = f32x4{0.f, 0.f, 0.f, 0.f};

  for (int kt = 0; kt < nt; ++kt) {
#pragma unroll
    for (int u = 0; u < 6; ++u) {
      gload16(gp[u], lds + dst[u]);
      gp[u] += 32;
    }
    asm volatile("s_waitcnt vmcnt(0)" ::: "memory");
    __builtin_amdgcn_s_barrier();  // whole tile staged by all waves

    bf16x8 aH[4], aL[4];
#pragma unroll
    for (int m = 0; m < 4; ++m) {
      aH[m] = *(const bf16x8*)(lds + (AR + m * 16) * 64 + rdOff);
      aL[m] = *(const bf16x8*)(lds + OFF_AL + (AR + m * 16) * 64 + rdOff);
    }
#pragma unroll
    for (int n = 0; n < 4; ++n) {
      bf16x8 bH = *(const bf16x8*)(lds + OFF_BH + (BR + n * 16) * 64 + rdOff);
      bf16x8 bL = *(const bf16x8*)(lds + OFF_BL + (BR + n * 16) * 64 + rdOff);
#pragma unroll
      for (int m = 0; m < 4; ++m)
        acc[m][n] = MFMA_BF16(aH[m], bL, acc[m][n], 0, 0, 0);
#pragma unroll
      for (int m = 0; m < 4; ++m)
        acc[m][n] = MFMA_BF16(aL[m], bH, acc[m][n], 0, 0, 0);
#pragma unroll
      for (int m = 0; m < 4; ++m)
        acc[m][n] = MFMA_BF16(aH[m], bH, acc[m][n], 0, 0, 0);
    }
    __builtin_amdgcn_s_barrier();  // all reads done before restaging
  }

  const int cr = (lane >> 4) << 2;
  const int cc = lane & 15;
#pragma unroll
  for (int m = 0; m < 4; ++m)
#pragma unroll
    for (int n = 0; n < 4; ++n)
#pragma unroll
      for (int r = 0; r < 4; ++r) {
        const long long row = (long long)by * 256 + AR + m * 16 + cr + r;
        const long long col = (long long)bx * 128 + BR + n * 16 + cc;
        const float v = acc[m][n][r];
        if constexpr (EPI == 0) {
          Cf[row * N + col] = v;
        } else {
          const long long idx = row * N + col;
          u16 h = f2bf(v);
          Ch[idx] = h;
          Cl[idx] = f2bf(v - bf2f(h));
        }
      }
}

// ====== 256x128 NP1 bf16 BT GEMM (r9, kept for v_t / PV) =================
template <int EPI, bool TRIK>
__global__ __launch_bounds__(512, 4) void k_t256(
    const u16* __restrict__ Ah, const u16* __restrict__ Bh,
    float* __restrict__ Cf, u16* __restrict__ Ch,
    int nbx, int N, int K, long long strA, long long strB, long long strC) {
  constexpr int OFF_BH = 16384;
  __shared__ __align__(16) char lds[2][24576];

  const int nwg = gridDim.x;
  const int f = blockIdx.x;
  const int wgid = (f & 7) * (nwg >> 3) + (f >> 3);
  const int bz = blockIdx.y;
  const int bx = wgid % nbx;
  const int by = wgid / nbx;

  const int tid = threadIdx.x;
  const int lane = tid & 63;
  const int w = tid >> 6;
  const int wr = w >> 1;   // 0..3
  const int wc = w & 1;    // 0..1
  const int AR = wr * 64;
  const int BR = wc * 64;

  const int rL = tid >> 2;
  const int colOff = ((tid & 3) ^ ((tid >> 3) & 3)) * 8;
  const int rdOff = (lane & 15) * 64 + ((((lane >> 4) & 3) ^ ((lane >> 1) & 3)) << 4);

  const long long rowA0 = (long long)by * 256;
  const long long rowB0 = (long long)bx * 128;

  int nt = K / 32;
  if (TRIK) {
    const int lim = (by + 1) * 8;
    if (lim < nt) nt = lim;
  }

  const u16* pA = Ah + (long long)bz * strA;
  const u16* pB = Bh + (long long)bz * strB;
  const u16* gp[3];
  int dst[3];
  gp[0] = pA + (rowA0 + rL) * (long long)K + colOff;        dst[0] = tid * 16;
  gp[1] = pA + (rowA0 + 128 + rL) * (long long)K + colOff;  dst[1] = 8192 + tid * 16;
  gp[2] = pB + (rowB0 + rL) * (long long)K + colOff;        dst[2] = OFF_BH + tid * 16;

#define STG(BUF)                                               \
  {                                                            \
    _Pragma("unroll") for (int u = 0; u < 3; ++u) {            \
      gload16(gp[u], lds[BUF] + dst[u]);                       \
      gp[u] += 32;                                             \
    }                                                          \
  }
#define BAR __builtin_amdgcn_s_barrier()

  f32x4 acc[4][4];
#pragma unroll
  for (int m = 0; m < 4; ++m)
#pragma unroll
    for (int n = 0; n < 4; ++n) acc[m][n] = f32x4{0.f, 0.f, 0.f, 0.f};

  STG(0);

  for (int kt = 0; kt < nt; ++kt) {
    const int cur = kt & 1;
    const bool more = (kt + 1 < nt);

    if (more) {
      STG(cur ^ 1);
      asm volatile("s_waitcnt vmcnt(3)" ::: "memory");
    } else {
      asm volatile("s_waitcnt vmcnt(0)" ::: "memory");
    }
    BAR;

    const char* bb = lds[cur];
    bf16x8 a[4], b[4];
#pragma unroll
    for (int m = 0; m < 4; ++m)
      a[m] = *(const bf16x8*)(bb + (AR + m * 16) * 64 + rdOff);
#pragma unroll
    for (int n = 0; n < 4; ++n)
      b[n] = *(const bf16x8*)(bb + OFF_BH + (BR + n * 16) * 64 + rdOff);
#pragma unroll
    for (int m = 0; m < 4; ++m)
#pragma unroll
      for (int n = 0; n < 4; ++n)
        acc[m][n] = MFMA_BF16(a[m], b[n], acc[m][n], 0, 0, 0);
    BAR;
  }

  const int cr = (lane >> 4) << 2;
  const int cc = lane & 15;
#pragma unroll
  for (int m = 0; m < 4; ++m)
#pragma unroll
    for (int n = 0; n < 4; ++n)
#pragma unroll
      for (int r = 0; r < 4; ++r) {
        const long long row = (long long)by * 256 + AR + m * 16 + cr + r;
        const long long col = (long long)bx * 128 + BR + n * 16 + cc;
        const float v = acc[m][n][r];
        if constexpr (EPI == 0) {
          Cf[(long long)bz * strC + row * N + col] = v;
        } else {
          Ch[(long long)bz * strC + row * N + col] = f2bf(v);
        }
      }
#undef STG
#undef BAR
}

// -------- causal+pad masked row softmax (in-place, causal-trimmed) --------
__global__ __launch_bounds__(256) void k_softmax(float* __restrict__ attn,
                                                 u16* __restrict__ attn_bf,
                                                 const int* __restrict__ mask,
                                                 float inv_scale) {
  const int q = blockIdx.x;
  const int b = blockIdx.y;
  const int tid = threadIdx.x;
  float* row = attn + ((long long)b * Ss + q) * Ss;
  u16* rowb = attn_bf + ((long long)b * Ss + q) * Ss;
  const int* mrow = mask + b * Ss;
  const int qup = ((q >> 8) + 1) << 8;  // PV TRIK reads bf16 cols < 256-block

  float x[8];
  float m = -3.0e38f;
#pragma unroll
  for (int j = 0; j < 8; ++j) {
    const int k = tid + j * 256;
    float v = -3.0e38f;
    if (k <= q) {
      const float e = row[k];
      v = ((mrow[k] != 0) ? e : -1e20f) * inv_scale;
    }
    x[j] = v;
    m = fmaxf(m, v);
  }
#pragma unroll
  for (int o = 32; o > 0; o >>= 1) m = fmaxf(m, __shfl_xor(m, o));
  __shared__ float redm[4], reds[4];
  const int w = tid >> 6;
  if ((tid & 63) == 0) redm[w] = m;
  __syncthreads();
  m = fmaxf(fmaxf(redm[0], redm[1]), fmaxf(redm[2], redm[3]));
  float s = 0.f;
#pragma unroll
  for (int j = 0; j < 8; ++j) {
    x[j] = __expf(x[j] - m);
    s += x[j];
  }
#pragma unroll
  for (int o = 32; o > 0; o >>= 1) s += __shfl_xor(s, o);
  if ((tid & 63) == 0) reds[w] = s;
  __syncthreads();
  s = reds[0] + reds[1] + reds[2] + reds[3];
  const float inv = 1.0f / s;
#pragma unroll
  for (int j = 0; j < 8; ++j) {
    const int k = tid + j * 256;
    if (k <= q) {
      const float a = x[j] * inv;
      row[k] = a;
      rowb[k] = f2bf(a);
    } else {
      row[k] = 0.0f;
      if (k < qup) rowb[k] = 0;
    }
  }
}

extern "C" void kernel_launch(void* const* d_in, const int* in_sizes, int n_in,
                              void* d_out, int out_size, void* d_ws, size_t ws_size,
                              hipStream_t stream) {
  const float* emb = (const float*)d_in[0];
  const int* mask = (const int*)d_in[1];
  const float* Wq = (const float*)d_in[2];
  const float* Wk = (const float*)d_in[3];
  const float* Wv = (const float*)d_in[4];

  float* out = (float*)d_out;                   // [8,2048,1024] fp32
  float* attn = out + (long long)Bb * Ss * Dd;  // [8,2048,2048] fp32

  char* p = (char*)d_ws;
  u16* emb_hi = (u16*)p;                    // alive through energy
  u16* emb_lo = emb_hi + 16777216LL;
  u16* R_hi = (u16*)(p + 67108864LL);       // R = emb @ (Wq Wk^T)
  u16* R_lo = R_hi + 16777216LL;
  u16* v_t = R_lo + 16777216LL;             // [b][D][S] bf16
  u16* attn_bf = v_t + 16777216LL;
  u16* Wqr_hi = attn_bf + 16777216LL;       // raw Wq split [E,D]
  u16* Wqr_lo = Wqr_hi + 1048576LL;
  u16* Wkr_hi = Wqr_lo + 1048576LL;
  u16* Wkr_lo = Wkr_hi + 1048576LL;
  u16* M_hi = Wkr_lo + 1048576LL;           // M'' = Wk Wq^T
  u16* M_lo = M_hi + 1048576LL;
  u16* WvT_hi = M_lo + 1048576LL;           // Wv^T [D,E]

  const float inv_scale = 1.0f / (32.0f + 1.1920929e-07f);

  k_split4<<<16384, 256, 0, stream>>>(emb, emb_hi, emb_lo, 4194304LL);
  k_split4<<<1024, 256, 0, stream>>>(Wq, Wqr_hi, Wqr_lo, 262144LL);
  k_split4<<<1024, 256, 0, stream>>>(Wk, Wkr_hi, Wkr_lo, 262144LL);
  k_wt_split<<<dim3(32, 32), 256, 0, stream>>>(Wv, WvT_hi, nullptr);

  // M'' = Wk @ Wq^T (split 3-pass): 8x8 128-tiles = 64 blocks
  k_t128<3, 1, false, false><<<64, 512, 0, stream>>>(
      Wkr_hi, Wkr_lo, Wqr_hi, Wqr_lo, nullptr, M_hi, M_lo,
      8, 1024, 1024, 0, 0, 0);
  // R = emb @ M''^T  [EXPERIMENT: single-buffer 256x128 2blk/CU TLP]
  k_s256<1><<<512, 512, 0, stream>>>(
      emb_hi, emb_lo, M_hi, M_lo, nullptr, R_hi, R_lo, 8, 1024, 1024);
  // v^T per batch: [D,S] = Wv^T x emb_b (BT), 1-pass bf16
  k_t256<2, false><<<dim3(64, 8), 512, 0, stream>>>(
      WvT_hi, emb_hi, nullptr, v_t,
      16, Ss, Ee, 0, (long long)Ss * Ee, (long long)Dd * Ss);
  // energy per batch: [S,S] = R_b emb_b^T (r8-proven 128^2 causal)
  k_t128<3, 0, true, false><<<1088, 512, 0, stream>>>(
      R_hi, R_lo, emb_hi, emb_lo, attn, nullptr, nullptr,
      0, Ss, Dd, (long long)Ss * Dd, (long long)Ss * Dd, (long long)Ss * Ss);
  // softmax rows in-place + bf16 copy (causal-trimmed)
  k_softmax<<<dim3(Ss, Bb), 256, 0, stream>>>(attn, attn_bf, mask, inv_scale);
  // out per batch: [S,D] = attn_bf @ v_t^T (BT), K trunc at (by+1)*256
  k_t256<0, true><<<dim3(64, 8), 512, 0, stream>>>(
      attn_bf, v_t, out, nullptr,
      8, Dd, Ss, (long long)Ss * Ss, (long long)Dd * Ss, (long long)Ss * Dd);
}

// Round 11
// 426.647 us; speedup vs baseline: 1.3002x; 1.0538x over previous
//
#include <hip/hip_runtime.h>

#define Bb 8
#define Ss 2048
#define Ee 1024
#define Dd 1024

typedef __attribute__((ext_vector_type(8))) __bf16 bf16x8;
typedef __attribute__((ext_vector_type(4))) float f32x4;
typedef unsigned short u16;

__device__ __forceinline__ u16 f2bf(float x) {
  unsigned u = __float_as_uint(x);
  return (u16)((u + 0x7fffu + ((u >> 16) & 1u)) >> 16);
}
__device__ __forceinline__ float bf2f(u16 h) {
  return __uint_as_float(((unsigned)h) << 16);
}

__device__ __forceinline__ void gload16(const void* g, void* l) {
  __builtin_amdgcn_global_load_lds(
      (__attribute__((address_space(1))) void*)const_cast<void*>(g),
      (__attribute__((address_space(3))) void*)l, 16, 0, 0);
}

#define MFMA_BF16 __builtin_amdgcn_mfma_f32_16x16x32_bf16

// ---------------- fp32 -> bf16 hi/lo split (vectorized x4) ----------------
__global__ __launch_bounds__(256) void k_split4(const float* __restrict__ in,
                                                u16* __restrict__ hi,
                                                u16* __restrict__ lo,
                                                long long n4) {
  long long i = (long long)blockIdx.x * 256 + threadIdx.x;
  if (i >= n4) return;
  float4 v = ((const float4*)in)[i];
  float xs[4] = {v.x, v.y, v.z, v.w};
  u16 hh[4], ll[4];
#pragma unroll
  for (int j = 0; j < 4; ++j) {
    hh[j] = f2bf(xs[j]);
    ll[j] = f2bf(xs[j] - bf2f(hh[j]));
  }
  ushort4 h, l;
  h.x = hh[0]; h.y = hh[1]; h.z = hh[2]; h.w = hh[3];
  l.x = ll[0]; l.y = ll[1]; l.z = ll[2]; l.w = ll[3];
  ((ushort4*)hi)[i] = h;
  ((ushort4*)lo)[i] = l;
}

// ---------------- W [E,D] fp32 -> W^T [D,E] bf16 hi(/lo) ----------------
__global__ __launch_bounds__(256) void k_wt_split(const float* __restrict__ W,
                                                  u16* __restrict__ hi,
                                                  u16* __restrict__ lo) {
  __shared__ float t[32][33];
  const int tx = threadIdx.x & 31;
  const int ty = threadIdx.x >> 5;  // 0..7
  const int e0 = blockIdx.y * 32, d0 = blockIdx.x * 32;
#pragma unroll
  for (int r = ty; r < 32; r += 8)
    t[r][tx] = W[(long long)(e0 + r) * Dd + d0 + tx];
  __syncthreads();
#pragma unroll
  for (int r = ty; r < 32; r += 8) {
    float x = t[tx][r];  // = W[e0+tx][d0+r]
    long long o = (long long)(d0 + r) * Ee + e0 + tx;
    u16 h = f2bf(x);
    hi[o] = h;
    if (lo) lo[o] = f2bf(x - bf2f(h));
  }
}

// ====== r8-proven 128x128 BT GEMM, 8 waves (4M x 2N), per-wave 32x64 ======
// NP=3: split-precision; 4 LDS mats, 64 KiB dbuf, vmcnt(4), 2 read-phases.
template <int NP, int EPI, bool CAUSAL>
__global__ __launch_bounds__(512, 4) void k_t128(
    const u16* __restrict__ Ah, const u16* __restrict__ Al,
    const u16* __restrict__ Bh, const u16* __restrict__ Bl,
    float* __restrict__ Cf, u16* __restrict__ Ch, u16* __restrict__ Cl,
    int nbx, int N, int K, long long strA, long long strB, long long strC) {
  constexpr int NMAT = (NP == 3) ? 4 : 2;
  const int nwg = gridDim.x;
  const int f = blockIdx.x;
  const int wgid = (f & 7) * (nwg >> 3) + (f >> 3);  // XCD chunk swizzle
  int bx, by, bz;
  if (CAUSAL) {
    bz = wgid / 136;
    const int t = wgid % 136;
    int yy = 0, c = 0;
    while (c + yy + 1 <= t) { c += yy + 1; ++yy; }  // <=16 iters
    by = yy;
    bx = t - c;
  } else {
    bz = blockIdx.y;
    bx = wgid % nbx;
    by = wgid / nbx;
  }

  __shared__ __align__(16) u16 lds[2][NMAT][4096];

  const int tid = threadIdx.x;
  const int lane = tid & 63;
  const int w = tid >> 6;  // 0..7
  const int wr = w >> 1;   // 0..3  (M quarter)
  const int wc = w & 1;    // 0..1  (N half)

  const u16* srcBase[NMAT];
  if constexpr (NP == 3) {
    srcBase[0] = Ah + (long long)bz * strA;
    srcBase[1] = Al + (long long)bz * strA;
    srcBase[2] = Bh + (long long)bz * strB;
    srcBase[3] = Bl + (long long)bz * strB;
  } else {
    srcBase[0] = Ah + (long long)bz * strA;
    srcBase[1] = Bh + (long long)bz * strB;
  }
  const long long row0[2] = {(long long)by * 128, (long long)bx * 128};

  const int rL = tid >> 2;
  const int colOff = ((tid & 3) ^ ((tid >> 3) & 3)) * 8;
  const int rdOff = (lane & 15) * 64 + ((((lane >> 4) & 3) ^ ((lane >> 1) & 3)) << 4);

  const int AR = wr * 32;
  const int BR = wc * 64;
  const int nt = K / 32;

  const u16* gp[NMAT];
#pragma unroll
  for (int m = 0; m < NMAT; ++m) {
    const int opsel = (NP == 3) ? (m >> 1) : m;
    gp[m] = srcBase[m] + (row0[opsel] + rL) * (long long)K + colOff;
  }

#define STG(BUF)                                                       \
  {                                                                    \
    _Pragma("unroll") for (int m = 0; m < NMAT; ++m) {                 \
      gload16(gp[m], (char*)&lds[BUF][m][0] + tid * 16);               \
      gp[m] += 32;                                                     \
    }                                                                  \
  }
#define LDFRAG(MAT, R) \
  (*(const bf16x8*)((const char*)&lds[cur][MAT][0] + (R)*64 + rdOff))
#define BAR __builtin_amdgcn_s_barrier()

#define CLUSTER3(NH)                                                         \
  __builtin_amdgcn_s_setprio(1);                                             \
  _Pragma("unroll") for (int m = 0; m < 2; ++m)                              \
      _Pragma("unroll") for (int n = 0; n < 2; ++n)                          \
          acc[m][(NH)*2 + n] =                                               \
      MFMA_BF16(aH[m], bL[n], acc[m][(NH)*2 + n], 0, 0, 0);                  \
  _Pragma("unroll") for (int m = 0; m < 2; ++m)                              \
      _Pragma("unroll") for (int n = 0; n < 2; ++n)                          \
          acc[m][(NH)*2 + n] =                                               \
      MFMA_BF16(aL[m], bH[n], acc[m][(NH)*2 + n], 0, 0, 0);                  \
  _Pragma("unroll") for (int m = 0; m < 2; ++m)                              \
      _Pragma("unroll") for (int n = 0; n < 2; ++n)                          \
          acc[m][(NH)*2 + n] =                                               \
      MFMA_BF16(aH[m], bH[n], acc[m][(NH)*2 + n], 0, 0, 0);                  \
  __builtin_amdgcn_s_setprio(0);

  f32x4 acc[2][4];
#pragma unroll
  for (int m = 0; m < 2; ++m)
#pragma unroll
    for (int n = 0; n < 4; ++n) acc[m][n] = f32x4{0.f, 0.f, 0.f, 0.f};

  bf16x8 aH[2], aL[2], bH[2], bL[2];
  bf16x8 bF[4];

  STG(0);

  for (int kt = 0; kt < nt; ++kt) {
    const int cur = kt & 1;
    const bool more = (kt + 1 < nt);

    if (more) {
      STG(cur ^ 1);
      if constexpr (NP == 3)
        asm volatile("s_waitcnt vmcnt(4)" ::: "memory");
      else
        asm volatile("s_waitcnt vmcnt(2)" ::: "memory");
    } else {
      asm volatile("s_waitcnt vmcnt(0)" ::: "memory");
    }
    BAR;

    if constexpr (NP == 3) {
#pragma unroll
      for (int m = 0; m < 2; ++m) {
        aH[m] = LDFRAG(0, AR + m * 16);
        aL[m] = LDFRAG(1, AR + m * 16);
      }
#pragma unroll
      for (int n = 0; n < 2; ++n) {
        bH[n] = LDFRAG(2, BR + n * 16);
        bL[n] = LDFRAG(3, BR + n * 16);
      }
      BAR;
      CLUSTER3(0);
      BAR;
#pragma unroll
      for (int n = 0; n < 2; ++n) {
        bH[n] = LDFRAG(2, BR + 32 + n * 16);
        bL[n] = LDFRAG(3, BR + 32 + n * 16);
      }
      BAR;
      CLUSTER3(1);
      BAR;
    } else {
#pragma unroll
      for (int m = 0; m < 2; ++m) aH[m] = LDFRAG(0, AR + m * 16);
#pragma unroll
      for (int n = 0; n < 4; ++n) bF[n] = LDFRAG(1, BR + n * 16);
      BAR;
      __builtin_amdgcn_s_setprio(1);
#pragma unroll
      for (int m = 0; m < 2; ++m)
#pragma unroll
        for (int n = 0; n < 4; ++n)
          acc[m][n] = MFMA_BF16(aH[m], bF[n], acc[m][n], 0, 0, 0);
      __builtin_amdgcn_s_setprio(0);
      BAR;
    }
  }

  const int cr = (lane >> 4) << 2;
  const int cc = lane & 15;
#pragma unroll
  for (int m = 0; m < 2; ++m)
#pragma unroll
    for (int n = 0; n < 4; ++n)
#pragma unroll
      for (int r = 0; r < 4; ++r) {
        const long long row = (long long)by * 128 + wr * 32 + m * 16 + cr + r;
        const long long col = (long long)bx * 128 + wc * 64 + n * 16 + cc;
        const float v = acc[m][n][r];
        if constexpr (EPI == 0) {
          Cf[(long long)bz * strC + row * N + col] = v;
        } else if constexpr (EPI == 1) {
          const long long idx = row * N + col;
          u16 h = f2bf(v);
          Ch[idx] = h;
          Cl[idx] = f2bf(v - bf2f(h));
        } else {
          Ch[(long long)bz * strC + row * N + col] = f2bf(v);
        }
      }
#undef STG
#undef LDFRAG
#undef BAR
#undef CLUSTER3
}

// ====== single-buffer NP3 256x128, 48 KiB LDS, 2 blk/CU (r10, R-GEMM) ====
template <int EPI>
__global__ __launch_bounds__(512, 4) void k_s256(
    const u16* __restrict__ Ah, const u16* __restrict__ Al,
    const u16* __restrict__ Bh, const u16* __restrict__ Bl,
    float* __restrict__ Cf, u16* __restrict__ Ch, u16* __restrict__ Cl,
    int nbx, int N, int K) {
  constexpr int OFF_AL = 16384;
  constexpr int OFF_BH = 32768;
  constexpr int OFF_BL = 40960;
  __shared__ __align__(16) char lds[49152];

  const int nwg = gridDim.x;
  const int f = blockIdx.x;
  const int wgid = (f & 7) * (nwg >> 3) + (f >> 3);
  const int bx = wgid % nbx;
  const int by = wgid / nbx;

  const int tid = threadIdx.x;
  const int lane = tid & 63;
  const int w = tid >> 6;
  const int wr = w >> 1;
  const int wc = w & 1;
  const int AR = wr * 64;
  const int BR = wc * 64;

  const int rL = tid >> 2;
  const int colOff = ((tid & 3) ^ ((tid >> 3) & 3)) * 8;
  const int rdOff = (lane & 15) * 64 + ((((lane >> 4) & 3) ^ ((lane >> 1) & 3)) << 4);

  const long long rowA0 = (long long)by * 256;
  const long long rowB0 = (long long)bx * 128;
  const int nt = K / 32;

  const u16* gp[6];
  int dst[6];
  gp[0] = Ah + (rowA0 + rL) * (long long)K + colOff;        dst[0] = tid * 16;
  gp[1] = Ah + (rowA0 + 128 + rL) * (long long)K + colOff;  dst[1] = 8192 + tid * 16;
  gp[2] = Al + (rowA0 + rL) * (long long)K + colOff;        dst[2] = OFF_AL + tid * 16;
  gp[3] = Al + (rowA0 + 128 + rL) * (long long)K + colOff;  dst[3] = OFF_AL + 8192 + tid * 16;
  gp[4] = Bh + (rowB0 + rL) * (long long)K + colOff;        dst[4] = OFF_BH + tid * 16;
  gp[5] = Bl + (rowB0 + rL) * (long long)K + colOff;        dst[5] = OFF_BL + tid * 16;

  f32x4 acc[4][4];
#pragma unroll
  for (int m = 0; m < 4; ++m)
#pragma unroll
    for (int n = 0; n < 4; ++n) acc[m][n] = f32x4{0.f, 0.f, 0.f, 0.f};

  for (int kt = 0; kt < nt; ++kt) {
#pragma unroll
    for (int u = 0; u < 6; ++u) {
      gload16(gp[u], lds + dst[u]);
      gp[u] += 32;
    }
    asm volatile("s_waitcnt vmcnt(0)" ::: "memory");
    __builtin_amdgcn_s_barrier();

    bf16x8 aH[4], aL[4];
#pragma unroll
    for (int m = 0; m < 4; ++m) {
      aH[m] = *(const bf16x8*)(lds + (AR + m * 16) * 64 + rdOff);
      aL[m] = *(const bf16x8*)(lds + OFF_AL + (AR + m * 16) * 64 + rdOff);
    }
#pragma unroll
    for (int n = 0; n < 4; ++n) {
      bf16x8 bH = *(const bf16x8*)(lds + OFF_BH + (BR + n * 16) * 64 + rdOff);
      bf16x8 bL = *(const bf16x8*)(lds + OFF_BL + (BR + n * 16) * 64 + rdOff);
#pragma unroll
      for (int m = 0; m < 4; ++m)
        acc[m][n] = MFMA_BF16(aH[m], bL, acc[m][n], 0, 0, 0);
#pragma unroll
      for (int m = 0; m < 4; ++m)
        acc[m][n] = MFMA_BF16(aL[m], bH, acc[m][n], 0, 0, 0);
#pragma unroll
      for (int m = 0; m < 4; ++m)
        acc[m][n] = MFMA_BF16(aH[m], bH, acc[m][n], 0, 0, 0);
    }
    __builtin_amdgcn_s_barrier();
  }

  const int cr = (lane >> 4) << 2;
  const int cc = lane & 15;
#pragma unroll
  for (int m = 0; m < 4; ++m)
#pragma unroll
    for (int n = 0; n < 4; ++n)
#pragma unroll
      for (int r = 0; r < 4; ++r) {
        const long long row = (long long)by * 256 + AR + m * 16 + cr + r;
        const long long col = (long long)bx * 128 + BR + n * 16 + cc;
        const float v = acc[m][n][r];
        if constexpr (EPI == 0) {
          Cf[row * N + col] = v;
        } else {
          const long long idx = row * N + col;
          u16 h = f2bf(v);
          Ch[idx] = h;
          Cl[idx] = f2bf(v - bf2f(h));
        }
      }
}

// ====== 256x128 NP1 bf16 BT GEMM (r9, kept for v_t) ======================
template <int EPI>
__global__ __launch_bounds__(512, 4) void k_t256(
    const u16* __restrict__ Ah, const u16* __restrict__ Bh,
    float* __restrict__ Cf, u16* __restrict__ Ch,
    int nbx, int N, int K, long long strA, long long strB, long long strC) {
  constexpr int OFF_BH = 16384;
  __shared__ __align__(16) char lds[2][24576];

  const int nwg = gridDim.x;
  const int f = blockIdx.x;
  const int wgid = (f & 7) * (nwg >> 3) + (f >> 3);
  const int bz = blockIdx.y;
  const int bx = wgid % nbx;
  const int by = wgid / nbx;

  const int tid = threadIdx.x;
  const int lane = tid & 63;
  const int w = tid >> 6;
  const int wr = w >> 1;
  const int wc = w & 1;
  const int AR = wr * 64;
  const int BR = wc * 64;

  const int rL = tid >> 2;
  const int colOff = ((tid & 3) ^ ((tid >> 3) & 3)) * 8;
  const int rdOff = (lane & 15) * 64 + ((((lane >> 4) & 3) ^ ((lane >> 1) & 3)) << 4);

  const long long rowA0 = (long long)by * 256;
  const long long rowB0 = (long long)bx * 128;
  const int nt = K / 32;

  const u16* pA = Ah + (long long)bz * strA;
  const u16* pB = Bh + (long long)bz * strB;
  const u16* gp[3];
  int dst[3];
  gp[0] = pA + (rowA0 + rL) * (long long)K + colOff;        dst[0] = tid * 16;
  gp[1] = pA + (rowA0 + 128 + rL) * (long long)K + colOff;  dst[1] = 8192 + tid * 16;
  gp[2] = pB + (rowB0 + rL) * (long long)K + colOff;        dst[2] = OFF_BH + tid * 16;

#define STG(BUF)                                               \
  {                                                            \
    _Pragma("unroll") for (int u = 0; u < 3; ++u) {            \
      gload16(gp[u], lds[BUF] + dst[u]);                       \
      gp[u] += 32;                                             \
    }                                                          \
  }
#define BAR __builtin_amdgcn_s_barrier()

  f32x4 acc[4][4];
#pragma unroll
  for (int m = 0; m < 4; ++m)
#pragma unroll
    for (int n = 0; n < 4; ++n) acc[m][n] = f32x4{0.f, 0.f, 0.f, 0.f};

  STG(0);

  for (int kt = 0; kt < nt; ++kt) {
    const int cur = kt & 1;
    const bool more = (kt + 1 < nt);

    if (more) {
      STG(cur ^ 1);
      asm volatile("s_waitcnt vmcnt(3)" ::: "memory");
    } else {
      asm volatile("s_waitcnt vmcnt(0)" ::: "memory");
    }
    BAR;

    const char* bb = lds[cur];
    bf16x8 a[4], b[4];
#pragma unroll
    for (int m = 0; m < 4; ++m)
      a[m] = *(const bf16x8*)(bb + (AR + m * 16) * 64 + rdOff);
#pragma unroll
    for (int n = 0; n < 4; ++n)
      b[n] = *(const bf16x8*)(bb + OFF_BH + (BR + n * 16) * 64 + rdOff);
#pragma unroll
    for (int m = 0; m < 4; ++m)
#pragma unroll
      for (int n = 0; n < 4; ++n)
        acc[m][n] = MFMA_BF16(a[m], b[n], acc[m][n], 0, 0, 0);
    BAR;
  }

  const int cr = (lane >> 4) << 2;
  const int cc = lane & 15;
#pragma unroll
  for (int m = 0; m < 4; ++m)
#pragma unroll
    for (int n = 0; n < 4; ++n)
#pragma unroll
      for (int r = 0; r < 4; ++r) {
        const long long row = (long long)by * 256 + AR + m * 16 + cr + r;
        const long long col = (long long)bx * 128 + BR + n * 16 + cc;
        const float v = acc[m][n][r];
        if constexpr (EPI == 0) {
          Cf[(long long)bz * strC + row * N + col] = v;
        } else {
          Ch[(long long)bz * strC + row * N + col] = f2bf(v);
        }
      }
#undef STG
#undef BAR
}

// ====== PV: 128x128, 4 waves (2x2), dbuf 32KiB -> 4 blk/CU, tall-first ====
// out_b[2048,1024] = attn_bf_b @ v_t_b^T; K truncated causally per row tile.
// Grid 1024 = 8 XCD-chunks x 128; XCD chunk == batch; within batch tiles
// ordered by DESCENDING nt (by=15 first) so flow scheduling backfills.
__global__ __launch_bounds__(256, 4) void k_pv128(
    const u16* __restrict__ A, const u16* __restrict__ B,
    float* __restrict__ C) {
  __shared__ __align__(16) u16 lds[2][2][4096];  // 32 KiB

  const int f = blockIdx.x;
  const int wgid = (f & 7) * 128 + (f >> 3);  // XCD chunk
  const int bz = wgid >> 7;                   // batch == chunk
  const int t = wgid & 127;
  const int by = 15 - (t >> 3);               // tall-first
  const int bx = t & 7;

  const int tid = threadIdx.x;
  const int lane = tid & 63;
  const int w = tid >> 6;  // 0..3
  const int wr = w >> 1;   // 0..1
  const int wc = w & 1;    // 0..1
  const int AR = wr * 64;
  const int BR = wc * 64;

  const int rL = tid >> 2;  // 0..63
  const int colOff = ((tid & 3) ^ ((tid >> 3) & 3)) * 8;
  const int rdOff = (lane & 15) * 64 + ((((lane >> 4) & 3) ^ ((lane >> 1) & 3)) << 4);

  const int nt = (by + 1) * 4;  // K = (by+1)*128 causal columns

  const u16* pA = A + (long long)bz * Ss * Ss;
  const u16* pB = B + (long long)bz * Dd * Ss;
  const long long rowA0 = (long long)by * 128;
  const long long rowB0 = (long long)bx * 128;

  const u16* gp[4];
  int dst[4];
  gp[0] = pA + (rowA0 + rL) * (long long)Ss + colOff;       dst[0] = tid * 16;
  gp[1] = pA + (rowA0 + 64 + rL) * (long long)Ss + colOff;  dst[1] = 4096 + tid * 16;
  gp[2] = pB + (rowB0 + rL) * (long long)Ss + colOff;       dst[2] = 8192 + tid * 16;
  gp[3] = pB + (rowB0 + 64 + rL) * (long long)Ss + colOff;  dst[3] = 12288 + tid * 16;

#define STG(BUF)                                               \
  {                                                            \
    _Pragma("unroll") for (int u = 0; u < 4; ++u) {            \
      gload16(gp[u], (char*)&lds[BUF][0][0] + dst[u]);         \
      gp[u] += 32;                                             \
    }                                                          \
  }
#define BAR __builtin_amdgcn_s_barrier()

  f32x4 acc[4][4];
#pragma unroll
  for (int m = 0; m < 4; ++m)
#pragma unroll
    for (int n = 0; n < 4; ++n) acc[m][n] = f32x4{0.f, 0.f, 0.f, 0.f};

  STG(0);

  for (int kt = 0; kt < nt; ++kt) {
    const int cur = kt & 1;
    const bool more = (kt + 1 < nt);

    if (more) {
      STG(cur ^ 1);
      asm volatile("s_waitcnt vmcnt(4)" ::: "memory");
    } else {
      asm volatile("s_waitcnt vmcnt(0)" ::: "memory");
    }
    BAR;

    const char* bb = (const char*)&lds[cur][0][0];
    bf16x8 a[4], b[4];
#pragma unroll
    for (int m = 0; m < 4; ++m)
      a[m] = *(const bf16x8*)(bb + (AR + m * 16) * 64 + rdOff);
#pragma unroll
    for (int n = 0; n < 4; ++n)
      b[n] = *(const bf16x8*)(bb + 8192 + (BR + n * 16) * 64 + rdOff);
    __builtin_amdgcn_s_setprio(1);
#pragma unroll
    for (int m = 0; m < 4; ++m)
#pragma unroll
      for (int n = 0; n < 4; ++n)
        acc[m][n] = MFMA_BF16(a[m], b[n], acc[m][n], 0, 0, 0);
    __builtin_amdgcn_s_setprio(0);
    BAR;
  }

  const int cr = (lane >> 4) << 2;
  const int cc = lane & 15;
#pragma unroll
  for (int m = 0; m < 4; ++m)
#pragma unroll
    for (int n = 0; n < 4; ++n)
#pragma unroll
      for (int r = 0; r < 4; ++r) {
        const long long row = (long long)by * 128 + AR + m * 16 + cr + r;
        const long long col = (long long)bx * 128 + BR + n * 16 + cc;
        C[(long long)bz * Ss * Dd + row * Dd + col] = acc[m][n][r];
      }
#undef STG
#undef BAR
}

// -------- causal+pad masked row softmax (in-place, causal-trimmed) --------
__global__ __launch_bounds__(256) void k_softmax(float* __restrict__ attn,
                                                 u16* __restrict__ attn_bf,
                                                 const int* __restrict__ mask,
                                                 float inv_scale) {
  const int q = blockIdx.x;
  const int b = blockIdx.y;
  const int tid = threadIdx.x;
  float* row = attn + ((long long)b * Ss + q) * Ss;
  u16* rowb = attn_bf + ((long long)b * Ss + q) * Ss;
  const int* mrow = mask + b * Ss;
  const int qup = ((q >> 7) + 1) << 7;  // PV reads bf16 cols < 128-boundary

  float x[8];
  float m = -3.0e38f;
#pragma unroll
  for (int j = 0; j < 8; ++j) {
    const int k = tid + j * 256;
    float v = -3.0e38f;
    if (k <= q) {
      const float e = row[k];
      v = ((mrow[k] != 0) ? e : -1e20f) * inv_scale;
    }
    x[j] = v;
    m = fmaxf(m, v);
  }
#pragma unroll
  for (int o = 32; o > 0; o >>= 1) m = fmaxf(m, __shfl_xor(m, o));
  __shared__ float redm[4], reds[4];
  const int w = tid >> 6;
  if ((tid & 63) == 0) redm[w] = m;
  __syncthreads();
  m = fmaxf(fmaxf(redm[0], redm[1]), fmaxf(redm[2], redm[3]));
  float s = 0.f;
#pragma unroll
  for (int j = 0; j < 8; ++j) {
    x[j] = __expf(x[j] - m);
    s += x[j];
  }
#pragma unroll
  for (int o = 32; o > 0; o >>= 1) s += __shfl_xor(s, o);
  if ((tid & 63) == 0) reds[w] = s;
  __syncthreads();
  s = reds[0] + reds[1] + reds[2] + reds[3];
  const float inv = 1.0f / s;
#pragma unroll
  for (int j = 0; j < 8; ++j) {
    const int k = tid + j * 256;
    if (k <= q) {
      const float a = x[j] * inv;
      row[k] = a;
      rowb[k] = f2bf(a);
    } else {
      row[k] = 0.0f;
      if (k < qup) rowb[k] = 0;
    }
  }
}

extern "C" void kernel_launch(void* const* d_in, const int* in_sizes, int n_in,
                              void* d_out, int out_size, void* d_ws, size_t ws_size,
                              hipStream_t stream) {
  const float* emb = (const float*)d_in[0];
  const int* mask = (const int*)d_in[1];
  const float* Wq = (const float*)d_in[2];
  const float* Wk = (const float*)d_in[3];
  const float* Wv = (const float*)d_in[4];

  float* out = (float*)d_out;                   // [8,2048,1024] fp32
  float* attn = out + (long long)Bb * Ss * Dd;  // [8,2048,2048] fp32

  char* p = (char*)d_ws;
  u16* emb_hi = (u16*)p;                    // alive through energy
  u16* emb_lo = emb_hi + 16777216LL;
  u16* R_hi = (u16*)(p + 67108864LL);       // R = emb @ (Wq Wk^T)
  u16* R_lo = R_hi + 16777216LL;
  u16* v_t = R_lo + 16777216LL;             // [b][D][S] bf16
  u16* attn_bf = v_t + 16777216LL;
  u16* Wqr_hi = attn_bf + 16777216LL;       // raw Wq split [E,D]
  u16* Wqr_lo = Wqr_hi + 1048576LL;
  u16* Wkr_hi = Wqr_lo + 1048576LL;
  u16* Wkr_lo = Wkr_hi + 1048576LL;
  u16* M_hi = Wkr_lo + 1048576LL;           // M'' = Wk Wq^T
  u16* M_lo = M_hi + 1048576LL;
  u16* WvT_hi = M_lo + 1048576LL;           // Wv^T [D,E]

  const float inv_scale = 1.0f / (32.0f + 1.1920929e-07f);

  k_split4<<<16384, 256, 0, stream>>>(emb, emb_hi, emb_lo, 4194304LL);
  k_split4<<<1024, 256, 0, stream>>>(Wq, Wqr_hi, Wqr_lo, 262144LL);
  k_split4<<<1024, 256, 0, stream>>>(Wk, Wkr_hi, Wkr_lo, 262144LL);
  k_wt_split<<<dim3(32, 32), 256, 0, stream>>>(Wv, WvT_hi, nullptr);

  // M'' = Wk @ Wq^T (split 3-pass): 8x8 128-tiles = 64 blocks
  k_t128<3, 1, false><<<64, 512, 0, stream>>>(
      Wkr_hi, Wkr_lo, Wqr_hi, Wqr_lo, nullptr, M_hi, M_lo,
      8, 1024, 1024, 0, 0, 0);
  // R = emb @ M''^T (single-buffer 256x128 TLP, r10-proven)
  k_s256<1><<<512, 512, 0, stream>>>(
      emb_hi, emb_lo, M_hi, M_lo, nullptr, R_hi, R_lo, 8, 1024, 1024);
  // v^T per batch: [D,S] = Wv^T x emb_b (BT), 1-pass bf16
  k_t256<2><<<dim3(64, 8), 512, 0, stream>>>(
      WvT_hi, emb_hi, nullptr, v_t,
      16, Ss, Ee, 0, (long long)Ss * Ee, (long long)Dd * Ss);
  // energy per batch: [S,S] = R_b emb_b^T (r8-proven 128^2 causal)
  k_t128<3, 0, true><<<1088, 512, 0, stream>>>(
      R_hi, R_lo, emb_hi, emb_lo, attn, nullptr, nullptr,
      0, Ss, Dd, (long long)Ss * Dd, (long long)Ss * Dd, (long long)Ss * Ss);
  // softmax rows in-place + bf16 copy (causal-trimmed)
  k_softmax<<<dim3(Ss, Bb), 256, 0, stream>>>(attn, attn_bf, mask, inv_scale);
  // out per batch: PV 128^2 tall-first flow-balanced
  k_pv128<<<1024, 256, 0, stream>>>(attn_bf, v_t, out);
}

// Round 12
// 418.833 us; speedup vs baseline: 1.3245x; 1.0187x over previous
//
#include <hip/hip_runtime.h>

#define Bb 8
#define Ss 2048
#define Ee 1024
#define Dd 1024

typedef __attribute__((ext_vector_type(8))) __bf16 bf16x8;
typedef __attribute__((ext_vector_type(4))) float f32x4;
typedef unsigned short u16;

__device__ __forceinline__ u16 f2bf(float x) {
  unsigned u = __float_as_uint(x);
  return (u16)((u + 0x7fffu + ((u >> 16) & 1u)) >> 16);
}
__device__ __forceinline__ float bf2f(u16 h) {
  return __uint_as_float(((unsigned)h) << 16);
}

__device__ __forceinline__ void gload16(const void* g, void* l) {
  __builtin_amdgcn_global_load_lds(
      (__attribute__((address_space(1))) void*)const_cast<void*>(g),
      (__attribute__((address_space(3))) void*)l, 16, 0, 0);
}

#define MFMA_BF16 __builtin_amdgcn_mfma_f32_16x16x32_bf16

// ---------------- fp32 -> bf16 hi/lo split (vectorized x4) ----------------
__global__ __launch_bounds__(256) void k_split4(const float* __restrict__ in,
                                                u16* __restrict__ hi,
                                                u16* __restrict__ lo,
                                                long long n4) {
  long long i = (long long)blockIdx.x * 256 + threadIdx.x;
  if (i >= n4) return;
  float4 v = ((const float4*)in)[i];
  float xs[4] = {v.x, v.y, v.z, v.w};
  u16 hh[4], ll[4];
#pragma unroll
  for (int j = 0; j < 4; ++j) {
    hh[j] = f2bf(xs[j]);
    ll[j] = f2bf(xs[j] - bf2f(hh[j]));
  }
  ushort4 h, l;
  h.x = hh[0]; h.y = hh[1]; h.z = hh[2]; h.w = hh[3];
  l.x = ll[0]; l.y = ll[1]; l.z = ll[2]; l.w = ll[3];
  ((ushort4*)hi)[i] = h;
  ((ushort4*)lo)[i] = l;
}

// ---------------- W [E,D] fp32 -> W^T [D,E] bf16 hi(/lo) ----------------
__global__ __launch_bounds__(256) void k_wt_split(const float* __restrict__ W,
                                                  u16* __restrict__ hi,
                                                  u16* __restrict__ lo) {
  __shared__ float t[32][33];
  const int tx = threadIdx.x & 31;
  const int ty = threadIdx.x >> 5;  // 0..7
  const int e0 = blockIdx.y * 32, d0 = blockIdx.x * 32;
#pragma unroll
  for (int r = ty; r < 32; r += 8)
    t[r][tx] = W[(long long)(e0 + r) * Dd + d0 + tx];
  __syncthreads();
#pragma unroll
  for (int r = ty; r < 32; r += 8) {
    float x = t[tx][r];  // = W[e0+tx][d0+r]
    long long o = (long long)(d0 + r) * Ee + e0 + tx;
    u16 h = f2bf(x);
    hi[o] = h;
    if (lo) lo[o] = f2bf(x - bf2f(h));
  }
}

// ====== r8-proven 128x128 BT GEMM, 8 waves (4M x 2N), per-wave 32x64 ======
// NP=3: split-precision; 4 LDS mats, 64 KiB dbuf, vmcnt(4), 2 read-phases.
template <int NP, int EPI, bool CAUSAL>
__global__ __launch_bounds__(512, 4) void k_t128(
    const u16* __restrict__ Ah, const u16* __restrict__ Al,
    const u16* __restrict__ Bh, const u16* __restrict__ Bl,
    float* __restrict__ Cf, u16* __restrict__ Ch, u16* __restrict__ Cl,
    int nbx, int N, int K, long long strA, long long strB, long long strC) {
  constexpr int NMAT = (NP == 3) ? 4 : 2;
  const int nwg = gridDim.x;
  const int f = blockIdx.x;
  const int wgid = (f & 7) * (nwg >> 3) + (f >> 3);  // XCD chunk swizzle
  int bx, by, bz;
  if (CAUSAL) {
    bz = wgid / 136;
    const int t = wgid % 136;
    int yy = 0, c = 0;
    while (c + yy + 1 <= t) { c += yy + 1; ++yy; }  // <=16 iters
    by = yy;
    bx = t - c;
  } else {
    bz = blockIdx.y;
    bx = wgid % nbx;
    by = wgid / nbx;
  }

  __shared__ __align__(16) u16 lds[2][NMAT][4096];

  const int tid = threadIdx.x;
  const int lane = tid & 63;
  const int w = tid >> 6;  // 0..7
  const int wr = w >> 1;   // 0..3  (M quarter)
  const int wc = w & 1;    // 0..1  (N half)

  const u16* srcBase[NMAT];
  if constexpr (NP == 3) {
    srcBase[0] = Ah + (long long)bz * strA;
    srcBase[1] = Al + (long long)bz * strA;
    srcBase[2] = Bh + (long long)bz * strB;
    srcBase[3] = Bl + (long long)bz * strB;
  } else {
    srcBase[0] = Ah + (long long)bz * strA;
    srcBase[1] = Bh + (long long)bz * strB;
  }
  const long long row0[2] = {(long long)by * 128, (long long)bx * 128};

  const int rL = tid >> 2;
  const int colOff = ((tid & 3) ^ ((tid >> 3) & 3)) * 8;
  const int rdOff = (lane & 15) * 64 + ((((lane >> 4) & 3) ^ ((lane >> 1) & 3)) << 4);

  const int AR = wr * 32;
  const int BR = wc * 64;
  const int nt = K / 32;

  const u16* gp[NMAT];
#pragma unroll
  for (int m = 0; m < NMAT; ++m) {
    const int opsel = (NP == 3) ? (m >> 1) : m;
    gp[m] = srcBase[m] + (row0[opsel] + rL) * (long long)K + colOff;
  }

#define STG(BUF)                                                       \
  {                                                                    \
    _Pragma("unroll") for (int m = 0; m < NMAT; ++m) {                 \
      gload16(gp[m], (char*)&lds[BUF][m][0] + tid * 16);               \
      gp[m] += 32;                                                     \
    }                                                                  \
  }
#define LDFRAG(MAT, R) \
  (*(const bf16x8*)((const char*)&lds[cur][MAT][0] + (R)*64 + rdOff))
#define BAR __builtin_amdgcn_s_barrier()

#define CLUSTER3(NH)                                                         \
  __builtin_amdgcn_s_setprio(1);                                             \
  _Pragma("unroll") for (int m = 0; m < 2; ++m)                              \
      _Pragma("unroll") for (int n = 0; n < 2; ++n)                          \
          acc[m][(NH)*2 + n] =                                               \
      MFMA_BF16(aH[m], bL[n], acc[m][(NH)*2 + n], 0, 0, 0);                  \
  _Pragma("unroll") for (int m = 0; m < 2; ++m)                              \
      _Pragma("unroll") for (int n = 0; n < 2; ++n)                          \
          acc[m][(NH)*2 + n] =                                               \
      MFMA_BF16(aL[m], bH[n], acc[m][(NH)*2 + n], 0, 0, 0);                  \
  _Pragma("unroll") for (int m = 0; m < 2; ++m)                              \
      _Pragma("unroll") for (int n = 0; n < 2; ++n)                          \
          acc[m][(NH)*2 + n] =                                               \
      MFMA_BF16(aH[m], bH[n], acc[m][(NH)*2 + n], 0, 0, 0);                  \
  __builtin_amdgcn_s_setprio(0);

  f32x4 acc[2][4];
#pragma unroll
  for (int m = 0; m < 2; ++m)
#pragma unroll
    for (int n = 0; n < 4; ++n) acc[m][n] = f32x4{0.f, 0.f, 0.f, 0.f};

  bf16x8 aH[2], aL[2], bH[2], bL[2];
  bf16x8 bF[4];

  STG(0);

  for (int kt = 0; kt < nt; ++kt) {
    const int cur = kt & 1;
    const bool more = (kt + 1 < nt);

    if (more) {
      STG(cur ^ 1);
      if constexpr (NP == 3)
        asm volatile("s_waitcnt vmcnt(4)" ::: "memory");
      else
        asm volatile("s_waitcnt vmcnt(2)" ::: "memory");
    } else {
      asm volatile("s_waitcnt vmcnt(0)" ::: "memory");
    }
    BAR;

    if constexpr (NP == 3) {
#pragma unroll
      for (int m = 0; m < 2; ++m) {
        aH[m] = LDFRAG(0, AR + m * 16);
        aL[m] = LDFRAG(1, AR + m * 16);
      }
#pragma unroll
      for (int n = 0; n < 2; ++n) {
        bH[n] = LDFRAG(2, BR + n * 16);
        bL[n] = LDFRAG(3, BR + n * 16);
      }
      BAR;
      CLUSTER3(0);
      BAR;
#pragma unroll
      for (int n = 0; n < 2; ++n) {
        bH[n] = LDFRAG(2, BR + 32 + n * 16);
        bL[n] = LDFRAG(3, BR + 32 + n * 16);
      }
      BAR;
      CLUSTER3(1);
      BAR;
    } else {
#pragma unroll
      for (int m = 0; m < 2; ++m) aH[m] = LDFRAG(0, AR + m * 16);
#pragma unroll
      for (int n = 0; n < 4; ++n) bF[n] = LDFRAG(1, BR + n * 16);
      BAR;
      __builtin_amdgcn_s_setprio(1);
#pragma unroll
      for (int m = 0; m < 2; ++m)
#pragma unroll
        for (int n = 0; n < 4; ++n)
          acc[m][n] = MFMA_BF16(aH[m], bF[n], acc[m][n], 0, 0, 0);
      __builtin_amdgcn_s_setprio(0);
      BAR;
    }
  }

  const int cr = (lane >> 4) << 2;
  const int cc = lane & 15;
#pragma unroll
  for (int m = 0; m < 2; ++m)
#pragma unroll
    for (int n = 0; n < 4; ++n)
#pragma unroll
      for (int r = 0; r < 4; ++r) {
        const long long row = (long long)by * 128 + wr * 32 + m * 16 + cr + r;
        const long long col = (long long)bx * 128 + wc * 64 + n * 16 + cc;
        const float v = acc[m][n][r];
        if constexpr (EPI == 0) {
          Cf[(long long)bz * strC + row * N + col] = v;
        } else if constexpr (EPI == 1) {
          const long long idx = row * N + col;
          u16 h = f2bf(v);
          Ch[idx] = h;
          Cl[idx] = f2bf(v - bf2f(h));
        } else {
          Ch[(long long)bz * strC + row * N + col] = f2bf(v);
        }
      }
#undef STG
#undef LDFRAG
#undef BAR
#undef CLUSTER3
}

// ====== single-buffer NP3 256x128, 48 KiB LDS, 2 blk/CU (r10, R-GEMM) ====
template <int EPI>
__global__ __launch_bounds__(512, 4) void k_s256(
    const u16* __restrict__ Ah, const u16* __restrict__ Al,
    const u16* __restrict__ Bh, const u16* __restrict__ Bl,
    float* __restrict__ Cf, u16* __restrict__ Ch, u16* __restrict__ Cl,
    int nbx, int N, int K) {
  constexpr int OFF_AL = 16384;
  constexpr int OFF_BH = 32768;
  constexpr int OFF_BL = 40960;
  __shared__ __align__(16) char lds[49152];

  const int nwg = gridDim.x;
  const int f = blockIdx.x;
  const int wgid = (f & 7) * (nwg >> 3) + (f >> 3);
  const int bx = wgid % nbx;
  const int by = wgid / nbx;

  const int tid = threadIdx.x;
  const int lane = tid & 63;
  const int w = tid >> 6;
  const int wr = w >> 1;
  const int wc = w & 1;
  const int AR = wr * 64;
  const int BR = wc * 64;

  const int rL = tid >> 2;
  const int colOff = ((tid & 3) ^ ((tid >> 3) & 3)) * 8;
  const int rdOff = (lane & 15) * 64 + ((((lane >> 4) & 3) ^ ((lane >> 1) & 3)) << 4);

  const long long rowA0 = (long long)by * 256;
  const long long rowB0 = (long long)bx * 128;
  const int nt = K / 32;

  const u16* gp[6];
  int dst[6];
  gp[0] = Ah + (rowA0 + rL) * (long long)K + colOff;        dst[0] = tid * 16;
  gp[1] = Ah + (rowA0 + 128 + rL) * (long long)K + colOff;  dst[1] = 8192 + tid * 16;
  gp[2] = Al + (rowA0 + rL) * (long long)K + colOff;        dst[2] = OFF_AL + tid * 16;
  gp[3] = Al + (rowA0 + 128 + rL) * (long long)K + colOff;  dst[3] = OFF_AL + 8192 + tid * 16;
  gp[4] = Bh + (rowB0 + rL) * (long long)K + colOff;        dst[4] = OFF_BH + tid * 16;
  gp[5] = Bl + (rowB0 + rL) * (long long)K + colOff;        dst[5] = OFF_BL + tid * 16;

  f32x4 acc[4][4];
#pragma unroll
  for (int m = 0; m < 4; ++m)
#pragma unroll
    for (int n = 0; n < 4; ++n) acc[m][n] = f32x4{0.f, 0.f, 0.f, 0.f};

  for (int kt = 0; kt < nt; ++kt) {
#pragma unroll
    for (int u = 0; u < 6; ++u) {
      gload16(gp[u], lds + dst[u]);
      gp[u] += 32;
    }
    asm volatile("s_waitcnt vmcnt(0)" ::: "memory");
    __builtin_amdgcn_s_barrier();

    bf16x8 aH[4], aL[4];
#pragma unroll
    for (int m = 0; m < 4; ++m) {
      aH[m] = *(const bf16x8*)(lds + (AR + m * 16) * 64 + rdOff);
      aL[m] = *(const bf16x8*)(lds + OFF_AL + (AR + m * 16) * 64 + rdOff);
    }
#pragma unroll
    for (int n = 0; n < 4; ++n) {
      bf16x8 bH = *(const bf16x8*)(lds + OFF_BH + (BR + n * 16) * 64 + rdOff);
      bf16x8 bL = *(const bf16x8*)(lds + OFF_BL + (BR + n * 16) * 64 + rdOff);
#pragma unroll
      for (int m = 0; m < 4; ++m)
        acc[m][n] = MFMA_BF16(aH[m], bL, acc[m][n], 0, 0, 0);
#pragma unroll
      for (int m = 0; m < 4; ++m)
        acc[m][n] = MFMA_BF16(aL[m], bH, acc[m][n], 0, 0, 0);
#pragma unroll
      for (int m = 0; m < 4; ++m)
        acc[m][n] = MFMA_BF16(aH[m], bH, acc[m][n], 0, 0, 0);
    }
    __builtin_amdgcn_s_barrier();
  }

  const int cr = (lane >> 4) << 2;
  const int cc = lane & 15;
#pragma unroll
  for (int m = 0; m < 4; ++m)
#pragma unroll
    for (int n = 0; n < 4; ++n)
#pragma unroll
      for (int r = 0; r < 4; ++r) {
        const long long row = (long long)by * 256 + AR + m * 16 + cr + r;
        const long long col = (long long)bx * 128 + BR + n * 16 + cc;
        const float v = acc[m][n][r];
        if constexpr (EPI == 0) {
          Cf[row * N + col] = v;
        } else {
          const long long idx = row * N + col;
          u16 h = f2bf(v);
          Ch[idx] = h;
          Cl[idx] = f2bf(v - bf2f(h));
        }
      }
}

// ====== 256x128 NP1 bf16 BT GEMM (r9, kept for v_t) ======================
template <int EPI>
__global__ __launch_bounds__(512, 4) void k_t256(
    const u16* __restrict__ Ah, const u16* __restrict__ Bh,
    float* __restrict__ Cf, u16* __restrict__ Ch,
    int nbx, int N, int K, long long strA, long long strB, long long strC) {
  constexpr int OFF_BH = 16384;
  __shared__ __align__(16) char lds[2][24576];

  const int nwg = gridDim.x;
  const int f = blockIdx.x;
  const int wgid = (f & 7) * (nwg >> 3) + (f >> 3);
  const int bz = blockIdx.y;
  const int bx = wgid % nbx;
  const int by = wgid / nbx;

  const int tid = threadIdx.x;
  const int lane = tid & 63;
  const int w = tid >> 6;
  const int wr = w >> 1;
  const int wc = w & 1;
  const int AR = wr * 64;
  const int BR = wc * 64;

  const int rL = tid >> 2;
  const int colOff = ((tid & 3) ^ ((tid >> 3) & 3)) * 8;
  const int rdOff = (lane & 15) * 64 + ((((lane >> 4) & 3) ^ ((lane >> 1) & 3)) << 4);

  const long long rowA0 = (long long)by * 256;
  const long long rowB0 = (long long)bx * 128;
  const int nt = K / 32;

  const u16* pA = Ah + (long long)bz * strA;
  const u16* pB = Bh + (long long)bz * strB;
  const u16* gp[3];
  int dst[3];
  gp[0] = pA + (rowA0 + rL) * (long long)K + colOff;        dst[0] = tid * 16;
  gp[1] = pA + (rowA0 + 128 + rL) * (long long)K + colOff;  dst[1] = 8192 + tid * 16;
  gp[2] = pB + (rowB0 + rL) * (long long)K + colOff;        dst[2] = OFF_BH + tid * 16;

#define STG(BUF)                                               \
  {                                                            \
    _Pragma("unroll") for (int u = 0; u < 3; ++u) {            \
      gload16(gp[u], lds[BUF] + dst[u]);                       \
      gp[u] += 32;                                             \
    }                                                          \
  }
#define BAR __builtin_amdgcn_s_barrier()

  f32x4 acc[4][4];
#pragma unroll
  for (int m = 0; m < 4; ++m)
#pragma unroll
    for (int n = 0; n < 4; ++n) acc[m][n] = f32x4{0.f, 0.f, 0.f, 0.f};

  STG(0);

  for (int kt = 0; kt < nt; ++kt) {
    const int cur = kt & 1;
    const bool more = (kt + 1 < nt);

    if (more) {
      STG(cur ^ 1);
      asm volatile("s_waitcnt vmcnt(3)" ::: "memory");
    } else {
      asm volatile("s_waitcnt vmcnt(0)" ::: "memory");
    }
    BAR;

    const char* bb = lds[cur];
    bf16x8 a[4], b[4];
#pragma unroll
    for (int m = 0; m < 4; ++m)
      a[m] = *(const bf16x8*)(bb + (AR + m * 16) * 64 + rdOff);
#pragma unroll
    for (int n = 0; n < 4; ++n)
      b[n] = *(const bf16x8*)(bb + OFF_BH + (BR + n * 16) * 64 + rdOff);
#pragma unroll
    for (int m = 0; m < 4; ++m)
#pragma unroll
      for (int n = 0; n < 4; ++n)
        acc[m][n] = MFMA_BF16(a[m], b[n], acc[m][n], 0, 0, 0);
    BAR;
  }

  const int cr = (lane >> 4) << 2;
  const int cc = lane & 15;
#pragma unroll
  for (int m = 0; m < 4; ++m)
#pragma unroll
    for (int n = 0; n < 4; ++n)
#pragma unroll
      for (int r = 0; r < 4; ++r) {
        const long long row = (long long)by * 256 + AR + m * 16 + cr + r;
        const long long col = (long long)bx * 128 + BR + n * 16 + cc;
        const float v = acc[m][n][r];
        if constexpr (EPI == 0) {
          Cf[(long long)bz * strC + row * N + col] = v;
        } else {
          Ch[(long long)bz * strC + row * N + col] = f2bf(v);
        }
      }
#undef STG
#undef BAR
}

// ====== PV: 128x128, 4 waves (2x2), dbuf 32KiB -> 4 blk/CU, tall-first ====
__global__ __launch_bounds__(256, 4) void k_pv128(
    const u16* __restrict__ A, const u16* __restrict__ B,
    float* __restrict__ C) {
  __shared__ __align__(16) u16 lds[2][2][4096];  // 32 KiB

  const int f = blockIdx.x;
  const int wgid = (f & 7) * 128 + (f >> 3);  // XCD chunk
  const int bz = wgid >> 7;                   // batch == chunk
  const int t = wgid & 127;
  const int by = 15 - (t >> 3);               // tall-first
  const int bx = t & 7;

  const int tid = threadIdx.x;
  const int lane = tid & 63;
  const int w = tid >> 6;  // 0..3
  const int wr = w >> 1;   // 0..1
  const int wc = w & 1;    // 0..1
  const int AR = wr * 64;
  const int BR = wc * 64;

  const int rL = tid >> 2;  // 0..63
  const int colOff = ((tid & 3) ^ ((tid >> 3) & 3)) * 8;
  const int rdOff = (lane & 15) * 64 + ((((lane >> 4) & 3) ^ ((lane >> 1) & 3)) << 4);

  const int nt = (by + 1) * 4;  // K = (by+1)*128 causal columns

  const u16* pA = A + (long long)bz * Ss * Ss;
  const u16* pB = B + (long long)bz * Dd * Ss;
  const long long rowA0 = (long long)by * 128;
  const long long rowB0 = (long long)bx * 128;

  const u16* gp[4];
  int dst[4];
  gp[0] = pA + (rowA0 + rL) * (long long)Ss + colOff;       dst[0] = tid * 16;
  gp[1] = pA + (rowA0 + 64 + rL) * (long long)Ss + colOff;  dst[1] = 4096 + tid * 16;
  gp[2] = pB + (rowB0 + rL) * (long long)Ss + colOff;       dst[2] = 8192 + tid * 16;
  gp[3] = pB + (rowB0 + 64 + rL) * (long long)Ss + colOff;  dst[3] = 12288 + tid * 16;

#define STG(BUF)                                               \
  {                                                            \
    _Pragma("unroll") for (int u = 0; u < 4; ++u) {            \
      gload16(gp[u], (char*)&lds[BUF][0][0] + dst[u]);         \
      gp[u] += 32;                                             \
    }                                                          \
  }
#define BAR __builtin_amdgcn_s_barrier()

  f32x4 acc[4][4];
#pragma unroll
  for (int m = 0; m < 4; ++m)
#pragma unroll
    for (int n = 0; n < 4; ++n) acc[m][n] = f32x4{0.f, 0.f, 0.f, 0.f};

  STG(0);

  for (int kt = 0; kt < nt; ++kt) {
    const int cur = kt & 1;
    const bool more = (kt + 1 < nt);

    if (more) {
      STG(cur ^ 1);
      asm volatile("s_waitcnt vmcnt(4)" ::: "memory");
    } else {
      asm volatile("s_waitcnt vmcnt(0)" ::: "memory");
    }
    BAR;

    const char* bb = (const char*)&lds[cur][0][0];
    bf16x8 a[4], b[4];
#pragma unroll
    for (int m = 0; m < 4; ++m)
      a[m] = *(const bf16x8*)(bb + (AR + m * 16) * 64 + rdOff);
#pragma unroll
    for (int n = 0; n < 4; ++n)
      b[n] = *(const bf16x8*)(bb + 8192 + (BR + n * 16) * 64 + rdOff);
    __builtin_amdgcn_s_setprio(1);
#pragma unroll
    for (int m = 0; m < 4; ++m)
#pragma unroll
      for (int n = 0; n < 4; ++n)
        acc[m][n] = MFMA_BF16(a[m], b[n], acc[m][n], 0, 0, 0);
    __builtin_amdgcn_s_setprio(0);
    BAR;
  }

  const int cr = (lane >> 4) << 2;
  const int cc = lane & 15;
#pragma unroll
  for (int m = 0; m < 4; ++m)
#pragma unroll
    for (int n = 0; n < 4; ++n)
#pragma unroll
      for (int r = 0; r < 4; ++r) {
        const long long row = (long long)by * 128 + AR + m * 16 + cr + r;
        const long long col = (long long)bx * 128 + BR + n * 16 + cc;
        C[(long long)bz * Ss * Dd + row * Dd + col] = acc[m][n][r];
      }
#undef STG
#undef BAR
}

// ---- causal+pad masked row softmax (in-place, VECTORIZED 16B/lane) ------
// Thread t owns 8 consecutive elements [t*8, t*8+8).  float4 x2 loads
// (skipped above diagonal), float4 x2 fp32 stores, ushort4 x2 bf16 stores
// gated on k0 < qup (qup is a multiple of 128 so the 8-group never
// straddles).  Element math identical to r11 (sum order differs ~1 ulp).
__global__ __launch_bounds__(256) void k_softmax(float* __restrict__ attn,
                                                 u16* __restrict__ attn_bf,
                                                 const int* __restrict__ mask,
                                                 float inv_scale) {
  const int q = blockIdx.x;
  const int b = blockIdx.y;
  const int tid = threadIdx.x;
  float* row = attn + ((long long)b * Ss + q) * Ss;
  u16* rowb = attn_bf + ((long long)b * Ss + q) * Ss;
  const int* mrow = mask + b * Ss;
  const int k0 = tid * 8;
  const int qup = ((q >> 7) + 1) << 7;  // PV reads bf16 cols < 128-boundary

  float x[8];
  float m = -3.0e38f;
  if (k0 <= q) {
    const float4 v0 = *(const float4*)(row + k0);
    const float4 v1 = *(const float4*)(row + k0 + 4);
    const int4 m0 = *(const int4*)(mrow + k0);
    const int4 m1 = *(const int4*)(mrow + k0 + 4);
    const float vs[8] = {v0.x, v0.y, v0.z, v0.w, v1.x, v1.y, v1.z, v1.w};
    const int ms[8] = {m0.x, m0.y, m0.z, m0.w, m1.x, m1.y, m1.z, m1.w};
#pragma unroll
    for (int j = 0; j < 8; ++j) {
      const int k = k0 + j;
      float v = -3.0e38f;
      if (k <= q) v = ((ms[j] != 0) ? vs[j] : -1e20f) * inv_scale;
      x[j] = v;
      m = fmaxf(m, v);
    }
  } else {
#pragma unroll
    for (int j = 0; j < 8; ++j) x[j] = -3.0e38f;
  }

#pragma unroll
  for (int o = 32; o > 0; o >>= 1) m = fmaxf(m, __shfl_xor(m, o));
  __shared__ float redm[4], reds[4];
  const int w = tid >> 6;
  if ((tid & 63) == 0) redm[w] = m;
  __syncthreads();
  m = fmaxf(fmaxf(redm[0], redm[1]), fmaxf(redm[2], redm[3]));
  float s = 0.f;
#pragma unroll
  for (int j = 0; j < 8; ++j) {
    x[j] = __expf(x[j] - m);
    s += x[j];
  }
#pragma unroll
  for (int o = 32; o > 0; o >>= 1) s += __shfl_xor(s, o);
  if ((tid & 63) == 0) reds[w] = s;
  __syncthreads();
  s = reds[0] + reds[1] + reds[2] + reds[3];
  const float inv = 1.0f / s;

  float o8[8];
  u16 ob[8];
#pragma unroll
  for (int j = 0; j < 8; ++j) {
    const int k = k0 + j;
    const float a = (k <= q) ? x[j] * inv : 0.0f;
    o8[j] = a;
    ob[j] = f2bf(a);
  }
  float4 w0, w1;
  w0.x = o8[0]; w0.y = o8[1]; w0.z = o8[2]; w0.w = o8[3];
  w1.x = o8[4]; w1.y = o8[5]; w1.z = o8[6]; w1.w = o8[7];
  *(float4*)(row + k0) = w0;
  *(float4*)(row + k0 + 4) = w1;
  if (k0 < qup) {
    ushort4 b0, b1;
    b0.x = ob[0]; b0.y = ob[1]; b0.z = ob[2]; b0.w = ob[3];
    b1.x = ob[4]; b1.y = ob[5]; b1.z = ob[6]; b1.w = ob[7];
    *(ushort4*)(rowb + k0) = b0;
    *(ushort4*)(rowb + k0 + 4) = b1;
  }
}

extern "C" void kernel_launch(void* const* d_in, const int* in_sizes, int n_in,
                              void* d_out, int out_size, void* d_ws, size_t ws_size,
                              hipStream_t stream) {
  const float* emb = (const float*)d_in[0];
  const int* mask = (const int*)d_in[1];
  const float* Wq = (const float*)d_in[2];
  const float* Wk = (const float*)d_in[3];
  const float* Wv = (const float*)d_in[4];

  float* out = (float*)d_out;                   // [8,2048,1024] fp32
  float* attn = out + (long long)Bb * Ss * Dd;  // [8,2048,2048] fp32

  char* p = (char*)d_ws;
  u16* emb_hi = (u16*)p;                    // alive through energy
  u16* emb_lo = emb_hi + 16777216LL;
  u16* R_hi = (u16*)(p + 67108864LL);       // R = emb @ (Wq Wk^T)
  u16* R_lo = R_hi + 16777216LL;
  u16* v_t = R_lo + 16777216LL;             // [b][D][S] bf16
  u16* attn_bf = v_t + 16777216LL;
  u16* Wqr_hi = attn_bf + 16777216LL;       // raw Wq split [E,D]
  u16* Wqr_lo = Wqr_hi + 1048576LL;
  u16* Wkr_hi = Wqr_lo + 1048576LL;
  u16* Wkr_lo = Wkr_hi + 1048576LL;
  u16* M_hi = Wkr_lo + 1048576LL;           // M'' = Wk Wq^T
  u16* M_lo = M_hi + 1048576LL;
  u16* WvT_hi = M_lo + 1048576LL;           // Wv^T [D,E]

  const float inv_scale = 1.0f / (32.0f + 1.1920929e-07f);

  k_split4<<<16384, 256, 0, stream>>>(emb, emb_hi, emb_lo, 4194304LL);
  k_split4<<<1024, 256, 0, stream>>>(Wq, Wqr_hi, Wqr_lo, 262144LL);
  k_split4<<<1024, 256, 0, stream>>>(Wk, Wkr_hi, Wkr_lo, 262144LL);
  k_wt_split<<<dim3(32, 32), 256, 0, stream>>>(Wv, WvT_hi, nullptr);

  // M'' = Wk @ Wq^T (split 3-pass): 8x8 128-tiles = 64 blocks
  k_t128<3, 1, false><<<64, 512, 0, stream>>>(
      Wkr_hi, Wkr_lo, Wqr_hi, Wqr_lo, nullptr, M_hi, M_lo,
      8, 1024, 1024, 0, 0, 0);
  // R = emb @ M''^T (single-buffer 256x128 TLP, r10-proven)
  k_s256<1><<<512, 512, 0, stream>>>(
      emb_hi, emb_lo, M_hi, M_lo, nullptr, R_hi, R_lo, 8, 1024, 1024);
  // v^T per batch: [D,S] = Wv^T x emb_b (BT), 1-pass bf16
  k_t256<2><<<dim3(64, 8), 512, 0, stream>>>(
      WvT_hi, emb_hi, nullptr, v_t,
      16, Ss, Ee, 0, (long long)Ss * Ee, (long long)Dd * Ss);
  // energy per batch: [S,S] = R_b emb_b^T (r8-proven 128^2 causal)
  k_t128<3, 0, true><<<1088, 512, 0, stream>>>(
      R_hi, R_lo, emb_hi, emb_lo, attn, nullptr, nullptr,
      0, Ss, Dd, (long long)Ss * Dd, (long long)Ss * Dd, (long long)Ss * Ss);
  // softmax rows in-place + bf16 copy (vectorized, causal-trimmed)
  k_softmax<<<dim3(Ss, Bb), 256, 0, stream>>>(attn, attn_bf, mask, inv_scale);
  // out per batch: PV 128^2 tall-first flow-balanced
  k_pv128<<<1024, 256, 0, stream>>>(attn_bf, v_t, out);
}

// Round 13
// 412.186 us; speedup vs baseline: 1.3458x; 1.0161x over previous
//
#include <hip/hip_runtime.h>

#define Bb 8
#define Ss 2048
#define Ee 1024
#define Dd 1024

typedef __attribute__((ext_vector_type(8))) __bf16 bf16x8;
typedef __attribute__((ext_vector_type(4))) float f32x4;
typedef unsigned short u16;

__device__ __forceinline__ u16 f2bf(float x) {
  unsigned u = __float_as_uint(x);
  return (u16)((u + 0x7fffu + ((u >> 16) & 1u)) >> 16);
}
__device__ __forceinline__ float bf2f(u16 h) {
  return __uint_as_float(((unsigned)h) << 16);
}

__device__ __forceinline__ void gload16(const void* g, void* l) {
  __builtin_amdgcn_global_load_lds(
      (__attribute__((address_space(1))) void*)const_cast<void*>(g),
      (__attribute__((address_space(3))) void*)l, 16, 0, 0);
}

#define MFMA_BF16 __builtin_amdgcn_mfma_f32_16x16x32_bf16

// ====== fused preprocessing: emb/Wq/Wk hi-lo splits + Wv^T split =========
// blocks [0,16384): emb  [16384,17408): Wq  [17408,18432): Wk
// [18432,19456): Wv transpose (bb&31 -> d-block, bb>>5 -> e-block)
__global__ __launch_bounds__(256) void k_pre(
    const float* __restrict__ emb, const float* __restrict__ Wq,
    const float* __restrict__ Wk, const float* __restrict__ Wv,
    u16* __restrict__ emb_hi, u16* __restrict__ emb_lo,
    u16* __restrict__ Wqr_hi, u16* __restrict__ Wqr_lo,
    u16* __restrict__ Wkr_hi, u16* __restrict__ Wkr_lo,
    u16* __restrict__ WvT_hi) {
  __shared__ float t[32][33];
  const int b = blockIdx.x;
  const int tid = threadIdx.x;
  if (b < 18432) {
    const float* in;
    u16 *hi, *lo;
    long long i;
    if (b < 16384) {
      in = emb; hi = emb_hi; lo = emb_lo;
      i = (long long)b * 256 + tid;
    } else if (b < 17408) {
      in = Wq; hi = Wqr_hi; lo = Wqr_lo;
      i = (long long)(b - 16384) * 256 + tid;
    } else {
      in = Wk; hi = Wkr_hi; lo = Wkr_lo;
      i = (long long)(b - 17408) * 256 + tid;
    }
    float4 v = ((const float4*)in)[i];
    float xs[4] = {v.x, v.y, v.z, v.w};
    u16 hh[4], ll[4];
#pragma unroll
    for (int j = 0; j < 4; ++j) {
      hh[j] = f2bf(xs[j]);
      ll[j] = f2bf(xs[j] - bf2f(hh[j]));
    }
    ushort4 h, l;
    h.x = hh[0]; h.y = hh[1]; h.z = hh[2]; h.w = hh[3];
    l.x = ll[0]; l.y = ll[1]; l.z = ll[2]; l.w = ll[3];
    ((ushort4*)hi)[i] = h;
    ((ushort4*)lo)[i] = l;
  } else {
    const int bb = b - 18432;
    const int bxx = bb & 31, byy = bb >> 5;
    const int tx = tid & 31;
    const int ty = tid >> 5;  // 0..7
    const int e0 = byy * 32, d0 = bxx * 32;
#pragma unroll
    for (int r = ty; r < 32; r += 8)
      t[r][tx] = Wv[(long long)(e0 + r) * Dd + d0 + tx];
    __syncthreads();
#pragma unroll
    for (int r = ty; r < 32; r += 8) {
      float x = t[tx][r];  // = Wv[e0+tx][d0+r]
      WvT_hi[(long long)(d0 + r) * Ee + e0 + tx] = f2bf(x);
    }
  }
}

// ====== r8-proven 128x128 BT GEMM, 8 waves (4M x 2N), per-wave 32x64 ======
// NP=3: split-precision; 4 LDS mats, 64 KiB dbuf, vmcnt(4), 2 read-phases.
template <int NP, int EPI, bool CAUSAL>
__global__ __launch_bounds__(512, 4) void k_t128(
    const u16* __restrict__ Ah, const u16* __restrict__ Al,
    const u16* __restrict__ Bh, const u16* __restrict__ Bl,
    float* __restrict__ Cf, u16* __restrict__ Ch, u16* __restrict__ Cl,
    int nbx, int N, int K, long long strA, long long strB, long long strC) {
  constexpr int NMAT = (NP == 3) ? 4 : 2;
  const int nwg = gridDim.x;
  const int f = blockIdx.x;
  const int wgid = (f & 7) * (nwg >> 3) + (f >> 3);  // XCD chunk swizzle
  int bx, by, bz;
  if (CAUSAL) {
    bz = wgid / 136;
    const int t = wgid % 136;
    int yy = 0, c = 0;
    while (c + yy + 1 <= t) { c += yy + 1; ++yy; }  // <=16 iters
    by = yy;
    bx = t - c;
  } else {
    bz = blockIdx.y;
    bx = wgid % nbx;
    by = wgid / nbx;
  }

  __shared__ __align__(16) u16 lds[2][NMAT][4096];

  const int tid = threadIdx.x;
  const int lane = tid & 63;
  const int w = tid >> 6;  // 0..7
  const int wr = w >> 1;   // 0..3  (M quarter)
  const int wc = w & 1;    // 0..1  (N half)

  const u16* srcBase[NMAT];
  if constexpr (NP == 3) {
    srcBase[0] = Ah + (long long)bz * strA;
    srcBase[1] = Al + (long long)bz * strA;
    srcBase[2] = Bh + (long long)bz * strB;
    srcBase[3] = Bl + (long long)bz * strB;
  } else {
    srcBase[0] = Ah + (long long)bz * strA;
    srcBase[1] = Bh + (long long)bz * strB;
  }
  const long long row0[2] = {(long long)by * 128, (long long)bx * 128};

  const int rL = tid >> 2;
  const int colOff = ((tid & 3) ^ ((tid >> 3) & 3)) * 8;
  const int rdOff = (lane & 15) * 64 + ((((lane >> 4) & 3) ^ ((lane >> 1) & 3)) << 4);

  const int AR = wr * 32;
  const int BR = wc * 64;
  const int nt = K / 32;

  const u16* gp[NMAT];
#pragma unroll
  for (int m = 0; m < NMAT; ++m) {
    const int opsel = (NP == 3) ? (m >> 1) : m;
    gp[m] = srcBase[m] + (row0[opsel] + rL) * (long long)K + colOff;
  }

#define STG(BUF)                                                       \
  {                                                                    \
    _Pragma("unroll") for (int m = 0; m < NMAT; ++m) {                 \
      gload16(gp[m], (char*)&lds[BUF][m][0] + tid * 16);               \
      gp[m] += 32;                                                     \
    }                                                                  \
  }
#define LDFRAG(MAT, R) \
  (*(const bf16x8*)((const char*)&lds[cur][MAT][0] + (R)*64 + rdOff))
#define BAR __builtin_amdgcn_s_barrier()

#define CLUSTER3(NH)                                                         \
  __builtin_amdgcn_s_setprio(1);                                             \
  _Pragma("unroll") for (int m = 0; m < 2; ++m)                              \
      _Pragma("unroll") for (int n = 0; n < 2; ++n)                          \
          acc[m][(NH)*2 + n] =                                               \
      MFMA_BF16(aH[m], bL[n], acc[m][(NH)*2 + n], 0, 0, 0);                  \
  _Pragma("unroll") for (int m = 0; m < 2; ++m)                              \
      _Pragma("unroll") for (int n = 0; n < 2; ++n)                          \
          acc[m][(NH)*2 + n] =                                               \
      MFMA_BF16(aL[m], bH[n], acc[m][(NH)*2 + n], 0, 0, 0);                  \
  _Pragma("unroll") for (int m = 0; m < 2; ++m)                              \
      _Pragma("unroll") for (int n = 0; n < 2; ++n)                          \
          acc[m][(NH)*2 + n] =                                               \
      MFMA_BF16(aH[m], bH[n], acc[m][(NH)*2 + n], 0, 0, 0);                  \
  __builtin_amdgcn_s_setprio(0);

  f32x4 acc[2][4];
#pragma unroll
  for (int m = 0; m < 2; ++m)
#pragma unroll
    for (int n = 0; n < 4; ++n) acc[m][n] = f32x4{0.f, 0.f, 0.f, 0.f};

  bf16x8 aH[2], aL[2], bH[2], bL[2];
  bf16x8 bF[4];

  STG(0);

  for (int kt = 0; kt < nt; ++kt) {
    const int cur = kt & 1;
    const bool more = (kt + 1 < nt);

    if (more) {
      STG(cur ^ 1);
      if constexpr (NP == 3)
        asm volatile("s_waitcnt vmcnt(4)" ::: "memory");
      else
        asm volatile("s_waitcnt vmcnt(2)" ::: "memory");
    } else {
      asm volatile("s_waitcnt vmcnt(0)" ::: "memory");
    }
    BAR;

    if constexpr (NP == 3) {
#pragma unroll
      for (int m = 0; m < 2; ++m) {
        aH[m] = LDFRAG(0, AR + m * 16);
        aL[m] = LDFRAG(1, AR + m * 16);
      }
#pragma unroll
      for (int n = 0; n < 2; ++n) {
        bH[n] = LDFRAG(2, BR + n * 16);
        bL[n] = LDFRAG(3, BR + n * 16);
      }
      BAR;
      CLUSTER3(0);
      BAR;
#pragma unroll
      for (int n = 0; n < 2; ++n) {
        bH[n] = LDFRAG(2, BR + 32 + n * 16);
        bL[n] = LDFRAG(3, BR + 32 + n * 16);
      }
      BAR;
      CLUSTER3(1);
      BAR;
    } else {
#pragma unroll
      for (int m = 0; m < 2; ++m) aH[m] = LDFRAG(0, AR + m * 16);
#pragma unroll
      for (int n = 0; n < 4; ++n) bF[n] = LDFRAG(1, BR + n * 16);
      BAR;
      __builtin_amdgcn_s_setprio(1);
#pragma unroll
      for (int m = 0; m < 2; ++m)
#pragma unroll
        for (int n = 0; n < 4; ++n)
          acc[m][n] = MFMA_BF16(aH[m], bF[n], acc[m][n], 0, 0, 0);
      __builtin_amdgcn_s_setprio(0);
      BAR;
    }
  }

  const int cr = (lane >> 4) << 2;
  const int cc = lane & 15;
#pragma unroll
  for (int m = 0; m < 2; ++m)
#pragma unroll
    for (int n = 0; n < 4; ++n)
#pragma unroll
      for (int r = 0; r < 4; ++r) {
        const long long row = (long long)by * 128 + wr * 32 + m * 16 + cr + r;
        const long long col = (long long)bx * 128 + wc * 64 + n * 16 + cc;
        const float v = acc[m][n][r];
        if constexpr (EPI == 0) {
          Cf[(long long)bz * strC + row * N + col] = v;
        } else if constexpr (EPI == 1) {
          const long long idx = row * N + col;
          u16 h = f2bf(v);
          Ch[idx] = h;
          Cl[idx] = f2bf(v - bf2f(h));
        } else {
          Ch[(long long)bz * strC + row * N + col] = f2bf(v);
        }
      }
#undef STG
#undef LDFRAG
#undef BAR
#undef CLUSTER3
}

// ====== single-buffer NP3 256x128, 48 KiB LDS, 2 blk/CU (r10, R-GEMM) ====
template <int EPI>
__global__ __launch_bounds__(512, 4) void k_s256(
    const u16* __restrict__ Ah, const u16* __restrict__ Al,
    const u16* __restrict__ Bh, const u16* __restrict__ Bl,
    float* __restrict__ Cf, u16* __restrict__ Ch, u16* __restrict__ Cl,
    int nbx, int N, int K) {
  constexpr int OFF_AL = 16384;
  constexpr int OFF_BH = 32768;
  constexpr int OFF_BL = 40960;
  __shared__ __align__(16) char lds[49152];

  const int nwg = gridDim.x;
  const int f = blockIdx.x;
  const int wgid = (f & 7) * (nwg >> 3) + (f >> 3);
  const int bx = wgid % nbx;
  const int by = wgid / nbx;

  const int tid = threadIdx.x;
  const int lane = tid & 63;
  const int w = tid >> 6;
  const int wr = w >> 1;
  const int wc = w & 1;
  const int AR = wr * 64;
  const int BR = wc * 64;

  const int rL = tid >> 2;
  const int colOff = ((tid & 3) ^ ((tid >> 3) & 3)) * 8;
  const int rdOff = (lane & 15) * 64 + ((((lane >> 4) & 3) ^ ((lane >> 1) & 3)) << 4);

  const long long rowA0 = (long long)by * 256;
  const long long rowB0 = (long long)bx * 128;
  const int nt = K / 32;

  const u16* gp[6];
  int dst[6];
  gp[0] = Ah + (rowA0 + rL) * (long long)K + colOff;        dst[0] = tid * 16;
  gp[1] = Ah + (rowA0 + 128 + rL) * (long long)K + colOff;  dst[1] = 8192 + tid * 16;
  gp[2] = Al + (rowA0 + rL) * (long long)K + colOff;        dst[2] = OFF_AL + tid * 16;
  gp[3] = Al + (rowA0 + 128 + rL) * (long long)K + colOff;  dst[3] = OFF_AL + 8192 + tid * 16;
  gp[4] = Bh + (rowB0 + rL) * (long long)K + colOff;        dst[4] = OFF_BH + tid * 16;
  gp[5] = Bl + (rowB0 + rL) * (long long)K + colOff;        dst[5] = OFF_BL + tid * 16;

  f32x4 acc[4][4];
#pragma unroll
  for (int m = 0; m < 4; ++m)
#pragma unroll
    for (int n = 0; n < 4; ++n) acc[m][n] = f32x4{0.f, 0.f, 0.f, 0.f};

  for (int kt = 0; kt < nt; ++kt) {
#pragma unroll
    for (int u = 0; u < 6; ++u) {
      gload16(gp[u], lds + dst[u]);
      gp[u] += 32;
    }
    asm volatile("s_waitcnt vmcnt(0)" ::: "memory");
    __builtin_amdgcn_s_barrier();

    bf16x8 aH[4], aL[4];
#pragma unroll
    for (int m = 0; m < 4; ++m) {
      aH[m] = *(const bf16x8*)(lds + (AR + m * 16) * 64 + rdOff);
      aL[m] = *(const bf16x8*)(lds + OFF_AL + (AR + m * 16) * 64 + rdOff);
    }
#pragma unroll
    for (int n = 0; n < 4; ++n) {
      bf16x8 bH = *(const bf16x8*)(lds + OFF_BH + (BR + n * 16) * 64 + rdOff);
      bf16x8 bL = *(const bf16x8*)(lds + OFF_BL + (BR + n * 16) * 64 + rdOff);
#pragma unroll
      for (int m = 0; m < 4; ++m)
        acc[m][n] = MFMA_BF16(aH[m], bL, acc[m][n], 0, 0, 0);
#pragma unroll
      for (int m = 0; m < 4; ++m)
        acc[m][n] = MFMA_BF16(aL[m], bH, acc[m][n], 0, 0, 0);
#pragma unroll
      for (int m = 0; m < 4; ++m)
        acc[m][n] = MFMA_BF16(aH[m], bH, acc[m][n], 0, 0, 0);
    }
    __builtin_amdgcn_s_barrier();
  }

  const int cr = (lane >> 4) << 2;
  const int cc = lane & 15;
#pragma unroll
  for (int m = 0; m < 4; ++m)
#pragma unroll
    for (int n = 0; n < 4; ++n)
#pragma unroll
      for (int r = 0; r < 4; ++r) {
        const long long row = (long long)by * 256 + AR + m * 16 + cr + r;
        const long long col = (long long)bx * 128 + BR + n * 16 + cc;
        const float v = acc[m][n][r];
        if constexpr (EPI == 0) {
          Cf[row * N + col] = v;
        } else {
          const long long idx = row * N + col;
          u16 h = f2bf(v);
          Ch[idx] = h;
          Cl[idx] = f2bf(v - bf2f(h));
        }
      }
}

// ====== 256x128 NP1 bf16 BT GEMM (r9, kept for v_t) ======================
template <int EPI>
__global__ __launch_bounds__(512, 4) void k_t256(
    const u16* __restrict__ Ah, const u16* __restrict__ Bh,
    float* __restrict__ Cf, u16* __restrict__ Ch,
    int nbx, int N, int K, long long strA, long long strB, long long strC) {
  constexpr int OFF_BH = 16384;
  __shared__ __align__(16) char lds[2][24576];

  const int nwg = gridDim.x;
  const int f = blockIdx.x;
  const int wgid = (f & 7) * (nwg >> 3) + (f >> 3);
  const int bz = blockIdx.y;
  const int bx = wgid % nbx;
  const int by = wgid / nbx;

  const int tid = threadIdx.x;
  const int lane = tid & 63;
  const int w = tid >> 6;
  const int wr = w >> 1;
  const int wc = w & 1;
  const int AR = wr * 64;
  const int BR = wc * 64;

  const int rL = tid >> 2;
  const int colOff = ((tid & 3) ^ ((tid >> 3) & 3)) * 8;
  const int rdOff = (lane & 15) * 64 + ((((lane >> 4) & 3) ^ ((lane >> 1) & 3)) << 4);

  const long long rowA0 = (long long)by * 256;
  const long long rowB0 = (long long)bx * 128;
  const int nt = K / 32;

  const u16* pA = Ah + (long long)bz * strA;
  const u16* pB = Bh + (long long)bz * strB;
  const u16* gp[3];
  int dst[3];
  gp[0] = pA + (rowA0 + rL) * (long long)K + colOff;        dst[0] = tid * 16;
  gp[1] = pA + (rowA0 + 128 + rL) * (long long)K + colOff;  dst[1] = 8192 + tid * 16;
  gp[2] = pB + (rowB0 + rL) * (long long)K + colOff;        dst[2] = OFF_BH + tid * 16;

#define STG(BUF)                                               \
  {                                                            \
    _Pragma("unroll") for (int u = 0; u < 3; ++u) {            \
      gload16(gp[u], lds[BUF] + dst[u]);                       \
      gp[u] += 32;                                             \
    }                                                          \
  }
#define BAR __builtin_amdgcn_s_barrier()

  f32x4 acc[4][4];
#pragma unroll
  for (int m = 0; m < 4; ++m)
#pragma unroll
    for (int n = 0; n < 4; ++n) acc[m][n] = f32x4{0.f, 0.f, 0.f, 0.f};

  STG(0);

  for (int kt = 0; kt < nt; ++kt) {
    const int cur = kt & 1;
    const bool more = (kt + 1 < nt);

    if (more) {
      STG(cur ^ 1);
      asm volatile("s_waitcnt vmcnt(3)" ::: "memory");
    } else {
      asm volatile("s_waitcnt vmcnt(0)" ::: "memory");
    }
    BAR;

    const char* bb = lds[cur];
    bf16x8 a[4], b[4];
#pragma unroll
    for (int m = 0; m < 4; ++m)
      a[m] = *(const bf16x8*)(bb + (AR + m * 16) * 64 + rdOff);
#pragma unroll
    for (int n = 0; n < 4; ++n)
      b[n] = *(const bf16x8*)(bb + OFF_BH + (BR + n * 16) * 64 + rdOff);
#pragma unroll
    for (int m = 0; m < 4; ++m)
#pragma unroll
      for (int n = 0; n < 4; ++n)
        acc[m][n] = MFMA_BF16(a[m], b[n], acc[m][n], 0, 0, 0);
    BAR;
  }

  const int cr = (lane >> 4) << 2;
  const int cc = lane & 15;
#pragma unroll
  for (int m = 0; m < 4; ++m)
#pragma unroll
    for (int n = 0; n < 4; ++n)
#pragma unroll
      for (int r = 0; r < 4; ++r) {
        const long long row = (long long)by * 256 + AR + m * 16 + cr + r;
        const long long col = (long long)bx * 128 + BR + n * 16 + cc;
        const float v = acc[m][n][r];
        if constexpr (EPI == 0) {
          Cf[(long long)bz * strC + row * N + col] = v;
        } else {
          Ch[(long long)bz * strC + row * N + col] = f2bf(v);
        }
      }
#undef STG
#undef BAR
}

// ====== PV: 128x128, 4 waves (2x2), dbuf 32KiB -> 4 blk/CU, tall-first ====
__global__ __launch_bounds__(256, 4) void k_pv128(
    const u16* __restrict__ A, const u16* __restrict__ B,
    float* __restrict__ C) {
  __shared__ __align__(16) u16 lds[2][2][4096];  // 32 KiB

  const int f = blockIdx.x;
  const int wgid = (f & 7) * 128 + (f >> 3);  // XCD chunk
  const int bz = wgid >> 7;                   // batch == chunk
  const int t = wgid & 127;
  const int by = 15 - (t >> 3);               // tall-first
  const int bx = t & 7;

  const int tid = threadIdx.x;
  const int lane = tid & 63;
  const int w = tid >> 6;  // 0..3
  const int wr = w >> 1;   // 0..1
  const int wc = w & 1;    // 0..1
  const int AR = wr * 64;
  const int BR = wc * 64;

  const int rL = tid >> 2;  // 0..63
  const int colOff = ((tid & 3) ^ ((tid >> 3) & 3)) * 8;
  const int rdOff = (lane & 15) * 64 + ((((lane >> 4) & 3) ^ ((lane >> 1) & 3)) << 4);

  const int nt = (by + 1) * 4;  // K = (by+1)*128 causal columns

  const u16* pA = A + (long long)bz * Ss * Ss;
  const u16* pB = B + (long long)bz * Dd * Ss;
  const long long rowA0 = (long long)by * 128;
  const long long rowB0 = (long long)bx * 128;

  const u16* gp[4];
  int dst[4];
  gp[0] = pA + (rowA0 + rL) * (long long)Ss + colOff;       dst[0] = tid * 16;
  gp[1] = pA + (rowA0 + 64 + rL) * (long long)Ss + colOff;  dst[1] = 4096 + tid * 16;
  gp[2] = pB + (rowB0 + rL) * (long long)Ss + colOff;       dst[2] = 8192 + tid * 16;
  gp[3] = pB + (rowB0 + 64 + rL) * (long long)Ss + colOff;  dst[3] = 12288 + tid * 16;

#define STG(BUF)                                               \
  {                                                            \
    _Pragma("unroll") for (int u = 0; u < 4; ++u) {            \
      gload16(gp[u], (char*)&lds[BUF][0][0] + dst[u]);         \
      gp[u] += 32;                                             \
    }                                                          \
  }
#define BAR __builtin_amdgcn_s_barrier()

  f32x4 acc[4][4];
#pragma unroll
  for (int m = 0; m < 4; ++m)
#pragma unroll
    for (int n = 0; n < 4; ++n) acc[m][n] = f32x4{0.f, 0.f, 0.f, 0.f};

  STG(0);

  for (int kt = 0; kt < nt; ++kt) {
    const int cur = kt & 1;
    const bool more = (kt + 1 < nt);

    if (more) {
      STG(cur ^ 1);
      asm volatile("s_waitcnt vmcnt(4)" ::: "memory");
    } else {
      asm volatile("s_waitcnt vmcnt(0)" ::: "memory");
    }
    BAR;

    const char* bb = (const char*)&lds[cur][0][0];
    bf16x8 a[4], b[4];
#pragma unroll
    for (int m = 0; m < 4; ++m)
      a[m] = *(const bf16x8*)(bb + (AR + m * 16) * 64 + rdOff);
#pragma unroll
    for (int n = 0; n < 4; ++n)
      b[n] = *(const bf16x8*)(bb + 8192 + (BR + n * 16) * 64 + rdOff);
    __builtin_amdgcn_s_setprio(1);
#pragma unroll
    for (int m = 0; m < 4; ++m)
#pragma unroll
      for (int n = 0; n < 4; ++n)
        acc[m][n] = MFMA_BF16(a[m], b[n], acc[m][n], 0, 0, 0);
    __builtin_amdgcn_s_setprio(0);
    BAR;
  }

  const int cr = (lane >> 4) << 2;
  const int cc = lane & 15;
#pragma unroll
  for (int m = 0; m < 4; ++m)
#pragma unroll
    for (int n = 0; n < 4; ++n)
#pragma unroll
      for (int r = 0; r < 4; ++r) {
        const long long row = (long long)by * 128 + AR + m * 16 + cr + r;
        const long long col = (long long)bx * 128 + BR + n * 16 + cc;
        C[(long long)bz * Ss * Dd + row * Dd + col] = acc[m][n][r];
      }
#undef STG
#undef BAR
}

// ---- causal+pad masked row softmax, vectorized, 2 rows per block --------
// blockIdx.x in [0,1024): rows q = 2*bx, 2*bx+1.  Mask row loaded once.
// redm/reds reuse across iterations is barrier-safe (writes of iter i+1
// occur only after all threads passed iter i's second __syncthreads()).
__global__ __launch_bounds__(256) void k_softmax(float* __restrict__ attn,
                                                 u16* __restrict__ attn_bf,
                                                 const int* __restrict__ mask,
                                                 float inv_scale) {
  const int b = blockIdx.y;
  const int tid = threadIdx.x;
  const int k0 = tid * 8;
  const int* mrow = mask + b * Ss;
  const int4 mm0 = *(const int4*)(mrow + k0);
  const int4 mm1 = *(const int4*)(mrow + k0 + 4);
  const int ms[8] = {mm0.x, mm0.y, mm0.z, mm0.w, mm1.x, mm1.y, mm1.z, mm1.w};
  __shared__ float redm[4], reds[4];
  const int w = tid >> 6;

  for (int rr = 0; rr < 2; ++rr) {
    const int q = blockIdx.x * 2 + rr;
    float* row = attn + ((long long)b * Ss + q) * Ss;
    u16* rowb = attn_bf + ((long long)b * Ss + q) * Ss;
    const int qup = ((q >> 7) + 1) << 7;  // PV reads bf16 cols < 128-bound

    float x[8];
    float m = -3.0e38f;
    if (k0 <= q) {
      const float4 v0 = *(const float4*)(row + k0);
      const float4 v1 = *(const float4*)(row + k0 + 4);
      const float vs[8] = {v0.x, v0.y, v0.z, v0.w, v1.x, v1.y, v1.z, v1.w};
#pragma unroll
      for (int j = 0; j < 8; ++j) {
        const int k = k0 + j;
        float v = -3.0e38f;
        if (k <= q) v = ((ms[j] != 0) ? vs[j] : -1e20f) * inv_scale;
        x[j] = v;
        m = fmaxf(m, v);
      }
    } else {
#pragma unroll
      for (int j = 0; j < 8; ++j) x[j] = -3.0e38f;
    }

#pragma unroll
    for (int o = 32; o > 0; o >>= 1) m = fmaxf(m, __shfl_xor(m, o));
    if ((tid & 63) == 0) redm[w] = m;
    __syncthreads();
    m = fmaxf(fmaxf(redm[0], redm[1]), fmaxf(redm[2], redm[3]));
    float s = 0.f;
#pragma unroll
    for (int j = 0; j < 8; ++j) {
      x[j] = __expf(x[j] - m);
      s += x[j];
    }
#pragma unroll
    for (int o = 32; o > 0; o >>= 1) s += __shfl_xor(s, o);
    if ((tid & 63) == 0) reds[w] = s;
    __syncthreads();
    s = reds[0] + reds[1] + reds[2] + reds[3];
    const float inv = 1.0f / s;

    float o8[8];
    u16 ob[8];
#pragma unroll
    for (int j = 0; j < 8; ++j) {
      const int k = k0 + j;
      const float a = (k <= q) ? x[j] * inv : 0.0f;
      o8[j] = a;
      ob[j] = f2bf(a);
    }
    float4 w0, w1;
    w0.x = o8[0]; w0.y = o8[1]; w0.z = o8[2]; w0.w = o8[3];
    w1.x = o8[4]; w1.y = o8[5]; w1.z = o8[6]; w1.w = o8[7];
    *(float4*)(row + k0) = w0;
    *(float4*)(row + k0 + 4) = w1;
    if (k0 < qup) {
      ushort4 b0, b1;
      b0.x = ob[0]; b0.y = ob[1]; b0.z = ob[2]; b0.w = ob[3];
      b1.x = ob[4]; b1.y = ob[5]; b1.z = ob[6]; b1.w = ob[7];
      *(ushort4*)(rowb + k0) = b0;
      *(ushort4*)(rowb + k0 + 4) = b1;
    }
  }
}

extern "C" void kernel_launch(void* const* d_in, const int* in_sizes, int n_in,
                              void* d_out, int out_size, void* d_ws, size_t ws_size,
                              hipStream_t stream) {
  const float* emb = (const float*)d_in[0];
  const int* mask = (const int*)d_in[1];
  const float* Wq = (const float*)d_in[2];
  const float* Wk = (const float*)d_in[3];
  const float* Wv = (const float*)d_in[4];

  float* out = (float*)d_out;                   // [8,2048,1024] fp32
  float* attn = out + (long long)Bb * Ss * Dd;  // [8,2048,2048] fp32

  char* p = (char*)d_ws;
  u16* emb_hi = (u16*)p;                    // alive through energy
  u16* emb_lo = emb_hi + 16777216LL;
  u16* R_hi = (u16*)(p + 67108864LL);       // R = emb @ (Wq Wk^T)
  u16* R_lo = R_hi + 16777216LL;
  u16* v_t = R_lo + 16777216LL;             // [b][D][S] bf16
  u16* attn_bf = v_t + 16777216LL;
  u16* Wqr_hi = attn_bf + 16777216LL;       // raw Wq split [E,D]
  u16* Wqr_lo = Wqr_hi + 1048576LL;
  u16* Wkr_hi = Wqr_lo + 1048576LL;
  u16* Wkr_lo = Wkr_hi + 1048576LL;
  u16* M_hi = Wkr_lo + 1048576LL;           // M'' = Wk Wq^T
  u16* M_lo = M_hi + 1048576LL;
  u16* WvT_hi = M_lo + 1048576LL;           // Wv^T [D,E]

  const float inv_scale = 1.0f / (32.0f + 1.1920929e-07f);

  // fused preprocessing: emb/Wq/Wk splits + Wv^T
  k_pre<<<19456, 256, 0, stream>>>(emb, Wq, Wk, Wv, emb_hi, emb_lo,
                                   Wqr_hi, Wqr_lo, Wkr_hi, Wkr_lo, WvT_hi);

  // M'' = Wk @ Wq^T (split 3-pass): 8x8 128-tiles = 64 blocks
  k_t128<3, 1, false><<<64, 512, 0, stream>>>(
      Wkr_hi, Wkr_lo, Wqr_hi, Wqr_lo, nullptr, M_hi, M_lo,
      8, 1024, 1024, 0, 0, 0);
  // R = emb @ M''^T (single-buffer 256x128 TLP, r10-proven)
  k_s256<1><<<512, 512, 0, stream>>>(
      emb_hi, emb_lo, M_hi, M_lo, nullptr, R_hi, R_lo, 8, 1024, 1024);
  // v^T per batch: [D,S] = Wv^T x emb_b (BT), 1-pass bf16
  k_t256<2><<<dim3(64, 8), 512, 0, stream>>>(
      WvT_hi, emb_hi, nullptr, v_t,
      16, Ss, Ee, 0, (long long)Ss * Ee, (long long)Dd * Ss);
  // energy per batch: [S,S] = R_b emb_b^T (r8-proven 128^2 causal)
  k_t128<3, 0, true><<<1088, 512, 0, stream>>>(
      R_hi, R_lo, emb_hi, emb_lo, attn, nullptr, nullptr,
      0, Ss, Dd, (long long)Ss * Dd, (long long)Ss * Dd, (long long)Ss * Ss);
  // softmax rows in-place + bf16 copy (vectorized, 2 rows/block)
  k_softmax<<<dim3(1024, Bb), 256, 0, stream>>>(attn, attn_bf, mask, inv_scale);
  // out per batch: PV 128^2 tall-first flow-balanced
  k_pv128<<<1024, 256, 0, stream>>>(attn_bf, v_t, out);
}